// Round 10
// baseline (433.569 us; speedup 1.0000x reference)
//
#include <hip/hip_runtime.h>
#include <stdint.h>

typedef __attribute__((ext_vector_type(8))) short short8;
typedef __attribute__((ext_vector_type(8))) _Float16 half8;
typedef __attribute__((ext_vector_type(4))) float f32x4;

__device__ __forceinline__ unsigned short f2h(float x) {
  _Float16 h = (_Float16)x;
  return __builtin_bit_cast(unsigned short, h);
}
__device__ __forceinline__ float h2f(unsigned short u) {
  return (float)__builtin_bit_cast(_Float16, u);
}

#define GLOAD16(gsrc, ldst)                                              \
  __builtin_amdgcn_global_load_lds(                                      \
      (const __attribute__((address_space(1))) void*)(gsrc),             \
      (__attribute__((address_space(3))) void*)(ldst), 16, 0, 0)

#define VM(N) asm volatile("s_waitcnt vmcnt(" #N ")" ::: "memory")
#define BARSYNC __builtin_amdgcn_s_barrier()

// ---------- split fp32 -> (hi, lo) f16, 8 elems/thread ----------
__global__ __launch_bounds__(256) void split_pair_f16_kernel(
    const float* __restrict__ in, unsigned short* __restrict__ h,
    unsigned short* __restrict__ l) {
  size_t i = (size_t)blockIdx.x * 256 + threadIdx.x;
  float4 a = ((const float4*)in)[2 * i];
  float4 b = ((const float4*)in)[2 * i + 1];
  ushort4 h0 = make_ushort4(f2h(a.x), f2h(a.y), f2h(a.z), f2h(a.w));
  ushort4 h1 = make_ushort4(f2h(b.x), f2h(b.y), f2h(b.z), f2h(b.w));
  ((ushort4*)h)[2 * i] = h0;
  ((ushort4*)h)[2 * i + 1] = h1;
  ((ushort4*)l)[2 * i] = make_ushort4(
      f2h(a.x - h2f(h0.x)), f2h(a.y - h2f(h0.y)),
      f2h(a.z - h2f(h0.z)), f2h(a.w - h2f(h0.w)));
  ((ushort4*)l)[2 * i + 1] = make_ushort4(
      f2h(b.x - h2f(h1.x)), f2h(b.y - h2f(h1.y)),
      f2h(b.z - h2f(h1.z)), f2h(b.w - h2f(h1.w)));
}

// ---------- transpose W [K][N] fp32 -> f16 [N][K] ----------
__global__ __launch_bounds__(256) void transpose_f16_kernel(
    const float* __restrict__ W, unsigned short* __restrict__ hT,
    int Kd, int Nd) {
  __shared__ float tile[32][33];
  int r = threadIdx.x >> 3;
  int c = (threadIdx.x & 7) * 4;
  int k0 = blockIdx.y * 32, n0 = blockIdx.x * 32;
  float4 v = *(const float4*)&W[(size_t)(k0 + r) * Nd + n0 + c];
  tile[r][c] = v.x; tile[r][c + 1] = v.y; tile[r][c + 2] = v.z; tile[r][c + 3] = v.w;
  __syncthreads();
  size_t o = (size_t)(n0 + r) * Kd + k0 + c;
  *(ushort4*)&hT[o] = make_ushort4(f2h(tile[c + 0][r]), f2h(tile[c + 1][r]),
                                   f2h(tile[c + 2][r]), f2h(tile[c + 3][r]));
}

// =====================================================================
// qkv_kernel: fused QKV projection, 2-term f16 NT GEMM, 256x128 tile,
// BK=32, tri-buffer 120KB, 5 slots/wave, VM(5) -- R6-proven g2 structure.
// N=3072 = [q | k | v]; grid (24,32) = 768 blocks = exactly 3/CU.
// Epilogue per n0-slab: q,k f16 [row][col]; v f16 transposed into vT.
// =====================================================================
__global__ __launch_bounds__(512, 2) void qkv_kernel(
    const unsigned short* __restrict__ Ah, const unsigned short* __restrict__ Al,
    const unsigned short* __restrict__ WT, const float* __restrict__ bq,
    const float* __restrict__ bk, const float* __restrict__ bv,
    unsigned short* __restrict__ qh, unsigned short* __restrict__ kh,
    unsigned short* __restrict__ vT) {
  __shared__ __align__(16) char smem[3 * 40 * 1024];
  constexpr int lda = 1024, ldb = 1024, K = 1024;
  const int t = threadIdx.x, wid = t >> 6, lane = t & 63;
  const int waveM = wid >> 2, waveN = wid & 3;
  const int lr0 = lane & 15, lk0 = (lane >> 4) * 8;
  const int m0 = blockIdx.y * 256, n0 = blockIdx.x * 128;

  const unsigned short* slot_src[5];
#pragma unroll
  for (int s = 0; s < 5; ++s) {
    int si = 5 * wid + s;
    const unsigned short* p;
    if (si < 16)      p = Ah + (size_t)(m0 + si * 16 + lr0) * lda + lk0;
    else if (si < 32) p = Al + (size_t)(m0 + (si - 16) * 16 + lr0) * lda + lk0;
    else              p = WT + (size_t)(n0 + (si - 32) * 16 + lr0) * ldb + lk0;
    slot_src[s] = p;
  }

  const int NTILES = K >> 5;
  f32x4 acc[8][2] = {};

#pragma unroll
  for (int tt = 0; tt < 2; ++tt)
#pragma unroll
    for (int s = 0; s < 5; ++s)
      GLOAD16(slot_src[s] + (size_t)tt * 32,
              smem + tt * 40960 + (5 * wid + s) * 1024);
  VM(5);
  BARSYNC;
  __builtin_amdgcn_sched_barrier(0);

  for (int tile = 0; tile < NTILES; ++tile) {
    const int cur = tile % 3, nxt = (tile + 2) % 3;
    const bool do_stage = (tile + 2) < NTILES;
    const char* cb = smem + cur * 40960;
    char* nb = smem + nxt * 40960;
    half8 bf[2];
#pragma unroll
    for (int p = 0; p < 4; ++p) {
      half8 ahf[2], alf[2];
#pragma unroll
      for (int i = 0; i < 2; ++i) {
        int mg = waveM * 8 + 2 * p + i;
        ahf[i] = *(const half8*)(cb + mg * 1024 + lane * 16);
        alf[i] = *(const half8*)(cb + (16 + mg) * 1024 + lane * 16);
      }
      if (p == 0) {
#pragma unroll
        for (int j = 0; j < 2; ++j) {
          int ng = waveN * 2 + j;
          bf[j] = *(const half8*)(cb + (32 + ng) * 1024 + lane * 16);
        }
      }
      if (do_stage) {
        if (p == 0) {
          GLOAD16(slot_src[0] + (size_t)(tile + 2) * 32, nb + (5 * wid + 0) * 1024);
          GLOAD16(slot_src[1] + (size_t)(tile + 2) * 32, nb + (5 * wid + 1) * 1024);
        } else {
          const int slot = p + 1;
          GLOAD16(slot_src[slot] + (size_t)(tile + 2) * 32,
                  nb + (5 * wid + slot) * 1024);
        }
      }
      __builtin_amdgcn_s_setprio(1);
#pragma unroll
      for (int i = 0; i < 2; ++i)
#pragma unroll
        for (int j = 0; j < 2; ++j) {
          f32x4 c = acc[2 * p + i][j];
          c = __builtin_amdgcn_mfma_f32_16x16x32_f16(ahf[i], bf[j], c, 0, 0, 0);
          c = __builtin_amdgcn_mfma_f32_16x16x32_f16(alf[i], bf[j], c, 0, 0, 0);
          acc[2 * p + i][j] = c;
        }
      __builtin_amdgcn_s_setprio(0);
      if (p < 3) __builtin_amdgcn_s_barrier();
    }
    if (tile + 1 < NTILES) {
      if (do_stage) VM(5); else VM(0);
      BARSYNC;
      __builtin_amdgcn_sched_barrier(0);
    }
  }

  const int or0 = (lane >> 4) * 4;
  const int slab = n0 >> 10;  // 0=q, 1=k, 2=v
#pragma unroll
  for (int mm = 0; mm < 8; ++mm)
#pragma unroll
    for (int j = 0; j < 2; ++j)
#pragma unroll
      for (int r = 0; r < 4; ++r) {
        int row = m0 + waveM * 128 + mm * 16 + or0 + r;
        int col = (n0 & 1023) + waveN * 32 + j * 16 + lr0;
        float x = acc[mm][j][r];
        if (slab == 0) {
          qh[(size_t)row * 1024 + col] = f2h(x + bq[col]);
        } else if (slab == 1) {
          kh[(size_t)row * 1024 + col] = f2h(x + bk[col]);
        } else {
          vT[(size_t)col * 8192 + row] = f2h(x + bv[col]);
        }
      }
}

// =====================================================================
// g1q: 1-term f16 NT GEMM (QK^T), 256x256 tile, BK=32, tri-buffer 96KB,
// 4 slots/wave, stage 1/phase, VM(4). fp32 out. (R7-proven.)
// =====================================================================
__global__ __launch_bounds__(512, 2) void g1q_kernel(
    const unsigned short* __restrict__ Abase, size_t Astr, int lda,
    const unsigned short* __restrict__ Bbase, size_t Bstr, int ldb,
    float* __restrict__ outF, size_t Ostr, int ldo, int K) {
  __shared__ __align__(16) char smem[3 * 32 * 1024];
  const int t = threadIdx.x, wid = t >> 6, lane = t & 63;
  const int waveM = wid >> 2, waveN = wid & 3;
  const int lr0 = lane & 15, lk0 = (lane >> 4) * 8;
  const int m0 = blockIdx.y * 256, n0 = blockIdx.x * 256;
  const unsigned short* A = Abase + (size_t)blockIdx.z * Astr;
  const unsigned short* B = Bbase + (size_t)blockIdx.z * Bstr;
  float* out = outF + (size_t)blockIdx.z * Ostr;

  const unsigned short* slot_src[4];
#pragma unroll
  for (int s = 0; s < 4; ++s) {
    int si = 4 * wid + s;
    const unsigned short* p;
    if (si < 16) p = A + (size_t)(m0 + si * 16 + lr0) * lda + lk0;
    else         p = B + (size_t)(n0 + (si - 16) * 16 + lr0) * ldb + lk0;
    slot_src[s] = p;
  }

  const int NTILES = K >> 5;
  f32x4 acc[8][4] = {};

#pragma unroll
  for (int tt = 0; tt < 2; ++tt)
#pragma unroll
    for (int s = 0; s < 4; ++s)
      GLOAD16(slot_src[s] + (size_t)tt * 32,
              smem + tt * 32768 + (4 * wid + s) * 1024);
  VM(4);
  BARSYNC;
  __builtin_amdgcn_sched_barrier(0);

  for (int tile = 0; tile < NTILES; ++tile) {
    const int cur = tile % 3, nxt = (tile + 2) % 3;
    const bool do_stage = (tile + 2) < NTILES;
    const char* cb = smem + cur * 32768;
    char* nb = smem + nxt * 32768;
    half8 bf[4];
#pragma unroll
    for (int p = 0; p < 4; ++p) {
      half8 af[2];
#pragma unroll
      for (int i = 0; i < 2; ++i) {
        int mg = waveM * 8 + 2 * p + i;
        af[i] = *(const half8*)(cb + mg * 1024 + lane * 16);
      }
      if (p == 0) {
#pragma unroll
        for (int j = 0; j < 4; ++j) {
          int ng = waveN * 4 + j;
          bf[j] = *(const half8*)(cb + 16384 + ng * 1024 + lane * 16);
        }
      }
      if (do_stage)
        GLOAD16(slot_src[p] + (size_t)(tile + 2) * 32,
                nb + (4 * wid + p) * 1024);
      __builtin_amdgcn_s_setprio(1);
#pragma unroll
      for (int i = 0; i < 2; ++i)
#pragma unroll
        for (int j = 0; j < 4; ++j)
          acc[2 * p + i][j] = __builtin_amdgcn_mfma_f32_16x16x32_f16(
              af[i], bf[j], acc[2 * p + i][j], 0, 0, 0);
      __builtin_amdgcn_s_setprio(0);
      if (p < 3) __builtin_amdgcn_s_barrier();
    }
    if (tile + 1 < NTILES) {
      if (do_stage) VM(4); else VM(0);
      BARSYNC;
      __builtin_amdgcn_sched_barrier(0);
    }
  }

  const int or0 = (lane >> 4) * 4;
#pragma unroll
  for (int mm = 0; mm < 8; ++mm)
#pragma unroll
    for (int j = 0; j < 4; ++j)
#pragma unroll
      for (int r = 0; r < 4; ++r)
        out[(size_t)(m0 + waveM * 128 + mm * 16 + or0 + r) * ldo +
            (n0 + waveN * 64 + j * 16 + lr0)] = acc[mm][j][r];
}

// =====================================================================
// g1: 1-term f16 NT GEMM (PV), 256x128 tile, BK=64, tri-buffer 144KB,
// 6 slots/wave, VM(6) -- R6-proven, unchanged. fp32 out.
// =====================================================================
__global__ __launch_bounds__(512, 2) void g1_kernel(
    const unsigned short* __restrict__ Abase, size_t Astr, int lda,
    const unsigned short* __restrict__ Bbase, size_t Bstr, int ldb,
    float* __restrict__ outF, size_t Ostr, int ldo, int K) {
  __shared__ __align__(16) char smem[3 * 48 * 1024];
  const int t = threadIdx.x, wid = t >> 6, lane = t & 63;
  const int waveM = wid >> 2, waveN = wid & 3;
  const int lr0 = lane & 15, lk0 = (lane >> 4) * 8;
  const int m0 = blockIdx.y * 256, n0 = blockIdx.x * 128;
  const unsigned short* A = Abase + (size_t)blockIdx.z * Astr;
  const unsigned short* B = Bbase + (size_t)blockIdx.z * Bstr;
  float* out = outF + (size_t)blockIdx.z * Ostr;

  const unsigned short* slot_src[6];
#pragma unroll
  for (int s = 0; s < 6; ++s) {
    int si = 6 * wid + s;
    const unsigned short* p;
    if (si < 16)      p = A + (size_t)(m0 + si * 16 + lr0) * lda + lk0;
    else if (si < 32) p = A + (size_t)(m0 + (si - 16) * 16 + lr0) * lda + 32 + lk0;
    else if (si < 40) p = B + (size_t)(n0 + (si - 32) * 16 + lr0) * ldb + lk0;
    else              p = B + (size_t)(n0 + (si - 40) * 16 + lr0) * ldb + 32 + lk0;
    slot_src[s] = p;
  }

  const int NTILES = K >> 6;
  f32x4 acc[8][2] = {};

#pragma unroll
  for (int tt = 0; tt < 2; ++tt)
#pragma unroll
    for (int s = 0; s < 6; ++s)
      GLOAD16(slot_src[s] + (size_t)tt * 64,
              smem + tt * 49152 + (6 * wid + s) * 1024);
  VM(6);
  BARSYNC;
  __builtin_amdgcn_sched_barrier(0);

  for (int tile = 0; tile < NTILES; ++tile) {
    const int cur = tile % 3, nxt = (tile + 2) % 3;
    const bool do_stage = (tile + 2) < NTILES;
    const char* cb = smem + cur * 49152;
    char* nb = smem + nxt * 49152;
    half8 blo[2], bhi[2];
#pragma unroll
    for (int p = 0; p < 4; ++p) {
      half8 alo[2], ahi[2];
#pragma unroll
      for (int i = 0; i < 2; ++i) {
        int mg = waveM * 8 + 2 * p + i;
        alo[i] = *(const half8*)(cb + mg * 1024 + lane * 16);
        ahi[i] = *(const half8*)(cb + (16 + mg) * 1024 + lane * 16);
      }
      if (p == 0) {
#pragma unroll
        for (int j = 0; j < 2; ++j) {
          int ng = waveN * 2 + j;
          blo[j] = *(const half8*)(cb + (32 + ng) * 1024 + lane * 16);
          bhi[j] = *(const half8*)(cb + (40 + ng) * 1024 + lane * 16);
        }
      }
      if (do_stage && p < 3) {
#pragma unroll
        for (int s = 0; s < 2; ++s) {
          int slot = 2 * p + s;
          GLOAD16(slot_src[slot] + (size_t)(tile + 2) * 64,
                  nb + (6 * wid + slot) * 1024);
        }
      }
      __builtin_amdgcn_s_setprio(1);
#pragma unroll
      for (int i = 0; i < 2; ++i)
#pragma unroll
        for (int j = 0; j < 2; ++j) {
          f32x4 c = acc[2 * p + i][j];
          c = __builtin_amdgcn_mfma_f32_16x16x32_f16(alo[i], blo[j], c, 0, 0, 0);
          c = __builtin_amdgcn_mfma_f32_16x16x32_f16(ahi[i], bhi[j], c, 0, 0, 0);
          acc[2 * p + i][j] = c;
        }
      __builtin_amdgcn_s_setprio(0);
      if (p < 3) __builtin_amdgcn_s_barrier();
    }
    if (tile + 1 < NTILES) {
      if (do_stage) VM(6); else VM(0);
      BARSYNC;
      __builtin_amdgcn_sched_barrier(0);
    }
  }

  const int or0 = (lane >> 4) * 4;
#pragma unroll
  for (int mm = 0; mm < 8; ++mm)
#pragma unroll
    for (int j = 0; j < 2; ++j)
#pragma unroll
      for (int r = 0; r < 4; ++r)
        out[(size_t)(m0 + waveM * 128 + mm * 16 + or0 + r) * ldo +
            (n0 + waveN * 32 + j * 16 + lr0)] = acc[mm][j][r];
}

// ---------- row softmax: fp32 [4096] -> f16 probs (in-place, pld stride) ----
__global__ __launch_bounds__(256) void softmax_rows_kernel(
    const float* Sm, unsigned short* P, int ncol, int pld) {
  const int t = threadIdx.x;
  const float* srow = Sm + (size_t)blockIdx.x * ncol;
  float4 v[4];
  float m = -3.4e38f;
#pragma unroll
  for (int i = 0; i < 4; ++i) {
    v[i] = ((const float4*)srow)[t + 256 * i];
    m = fmaxf(m, fmaxf(fmaxf(v[i].x, v[i].y), fmaxf(v[i].z, v[i].w)));
  }
#pragma unroll
  for (int off = 32; off >= 1; off >>= 1) m = fmaxf(m, __shfl_down(m, off));
  __shared__ float redm[4];
  if ((t & 63) == 0) redm[t >> 6] = m;
  __syncthreads();
  m = fmaxf(fmaxf(redm[0], redm[1]), fmaxf(redm[2], redm[3]));
  float s = 0.f;
#pragma unroll
  for (int i = 0; i < 4; ++i) {
    v[i].x = __expf(v[i].x - m);
    v[i].y = __expf(v[i].y - m);
    v[i].z = __expf(v[i].z - m);
    v[i].w = __expf(v[i].w - m);
    s += v[i].x + v[i].y + v[i].z + v[i].w;
  }
#pragma unroll
  for (int off = 32; off >= 1; off >>= 1) s += __shfl_down(s, off);
  __shared__ float reds[4];
  if ((t & 63) == 0) reds[t >> 6] = s;
  __syncthreads();
  s = reds[0] + reds[1] + reds[2] + reds[3];
  float inv = 1.f / s;
  unsigned short* prow = P + (size_t)blockIdx.x * pld;
#pragma unroll
  for (int i = 0; i < 4; ++i) {
    ushort4 o = make_ushort4(f2h(v[i].x * inv), f2h(v[i].y * inv),
                             f2h(v[i].z * inv), f2h(v[i].w * inv));
    ((ushort4*)prow)[t + 256 * i] = o;
  }
}

extern "C" void kernel_launch(void* const* d_in, const int* in_sizes, int n_in,
                              void* d_out, int out_size, void* d_ws, size_t ws_size,
                              hipStream_t stream) {
  const float* hs = (const float*)d_in[0];
  const float* Wq = (const float*)d_in[1];
  const float* bq = (const float*)d_in[2];
  const float* Wk = (const float*)d_in[3];
  const float* bk = (const float*)d_in[4];
  const float* Wv = (const float*)d_in[5];
  const float* bv = (const float*)d_in[6];
  float* out = (float*)d_out;

  constexpr int Ss = 4096, Hh = 1024;
  constexpr int Mm = 8192;
  constexpr size_t TOK = (size_t)Ss * Hh;
  char* ws = (char*)d_ws;
  const size_t MB = 1024 * 1024;

  // live region [0,48MB): qh, kh (f16 [8192][1024]); vT (f16 [1024][8192])
  unsigned short* qh = (unsigned short*)(ws + 0 * MB);
  unsigned short* kh = (unsigned short*)(ws + 16 * MB);
  unsigned short* vT = (unsigned short*)(ws + 32 * MB);
  // region at +48MB: early = hs f16 splits (32MB) + WT (6MB);
  // late = S fp32 slabs (big: 2x64MB, P f16 in-place strided)
  char* rb = ws + 48 * MB;
  unsigned short* hs_h = (unsigned short*)(rb + 0 * MB);
  unsigned short* hs_l = (unsigned short*)(rb + 16 * MB);
  unsigned short* WT = (unsigned short*)(rb + 32 * MB);  // [3072][1024]
  float* Sf = (float*)rb;

  const bool big = ws_size >= (size_t)176 * MB;

  // 1) splits; W -> [3072][1024] f16 (q | k | v)
  split_pair_f16_kernel<<<dim3(Mm * Hh / 2048), 256, 0, stream>>>(hs, hs_h, hs_l);
  transpose_f16_kernel<<<dim3(32, 32), 256, 0, stream>>>(Wq, WT, Hh, Hh);
  transpose_f16_kernel<<<dim3(32, 32), 256, 0, stream>>>(
      Wk, WT + (size_t)1024 * 1024, Hh, Hh);
  transpose_f16_kernel<<<dim3(32, 32), 256, 0, stream>>>(
      Wv, WT + (size_t)2048 * 1024, Hh, Hh);

  // 2) fused QKV projection (256x128 2-term, grid 768 = 3/CU exact)
  qkv_kernel<<<dim3(24, 32), 512, 0, stream>>>(
      hs_h, hs_l, WT, bq, bk, bv, qh, kh, vT);

  if (big) {
    // 3) QK^T both batches (256x256 1-term) -> S fp32 slabs
    g1q_kernel<<<dim3(16, 16, 2), 512, 0, stream>>>(
        qh, TOK, Hh, kh, TOK, Hh, Sf, (size_t)Ss * Ss, Ss, Hh);
    // 4) softmax all 8192 rows, fp32 -> f16 in-place strided (pld 8192)
    softmax_rows_kernel<<<dim3(2 * Ss), 256, 0, stream>>>(
        Sf, (unsigned short*)Sf, Ss, 2 * Ss);
    // 5) PV both batches (256x128 1-term, grid 256 = 1/CU exact)
    g1_kernel<<<dim3(8, 16, 2), 512, 0, stream>>>(
        (const unsigned short*)Sf, (size_t)Ss * 2 * Ss, 2 * Ss,
        vT, (size_t)Ss, Mm, out, TOK, Hh, Ss);
  } else {
    float* Sb = (float*)rb;                                // 64MB S
    unsigned short* Pb = (unsigned short*)(rb + 64 * MB);  // 32MB P f16
    for (int b = 0; b < 2; ++b) {
      g1q_kernel<<<dim3(16, 16, 1), 512, 0, stream>>>(
          qh + b * TOK, 0, Hh, kh + b * TOK, 0, Hh, Sb, 0, Ss, Hh);
      softmax_rows_kernel<<<dim3(Ss), 256, 0, stream>>>(Sb, Pb, Ss, Ss);
      g1_kernel<<<dim3(8, 16, 1), 512, 0, stream>>>(
          Pb, 0, Ss, vT + (size_t)b * Ss, 0, Mm, out + b * TOK, 0, Hh, Ss);
    }
  }
}

// Round 11
// 418.542 us; speedup vs baseline: 1.0359x; 1.0359x over previous
//
#include <hip/hip_runtime.h>
#include <stdint.h>

typedef __attribute__((ext_vector_type(8))) short short8;
typedef __attribute__((ext_vector_type(8))) _Float16 half8;
typedef __attribute__((ext_vector_type(4))) float f32x4;

__device__ __forceinline__ unsigned short f2h(float x) {
  _Float16 h = (_Float16)x;
  return __builtin_bit_cast(unsigned short, h);
}
__device__ __forceinline__ float h2f(unsigned short u) {
  return (float)__builtin_bit_cast(_Float16, u);
}

#define GLOAD16(gsrc, ldst)                                              \
  __builtin_amdgcn_global_load_lds(                                      \
      (const __attribute__((address_space(1))) void*)(gsrc),             \
      (__attribute__((address_space(3))) void*)(ldst), 16, 0, 0)

#define VM(N) asm volatile("s_waitcnt vmcnt(" #N ")" ::: "memory")
#define BARSYNC __builtin_amdgcn_s_barrier()
#define LGKM0                                                \
  do {                                                       \
    asm volatile("s_waitcnt lgkmcnt(0)" ::: "memory");       \
    __builtin_amdgcn_sched_barrier(0);                       \
  } while (0)

// ---------- split fp32 -> (hi, lo) f16, 8 elems/thread ----------
__global__ __launch_bounds__(256) void split_pair_f16_kernel(
    const float* __restrict__ in, unsigned short* __restrict__ h,
    unsigned short* __restrict__ l) {
  size_t i = (size_t)blockIdx.x * 256 + threadIdx.x;
  float4 a = ((const float4*)in)[2 * i];
  float4 b = ((const float4*)in)[2 * i + 1];
  ushort4 h0 = make_ushort4(f2h(a.x), f2h(a.y), f2h(a.z), f2h(a.w));
  ushort4 h1 = make_ushort4(f2h(b.x), f2h(b.y), f2h(b.z), f2h(b.w));
  ((ushort4*)h)[2 * i] = h0;
  ((ushort4*)h)[2 * i + 1] = h1;
  ((ushort4*)l)[2 * i] = make_ushort4(
      f2h(a.x - h2f(h0.x)), f2h(a.y - h2f(h0.y)),
      f2h(a.z - h2f(h0.z)), f2h(a.w - h2f(h0.w)));
  ((ushort4*)l)[2 * i + 1] = make_ushort4(
      f2h(b.x - h2f(h1.x)), f2h(b.y - h2f(h1.y)),
      f2h(b.z - h2f(h1.z)), f2h(b.w - h2f(h1.w)));
}

// ---------- transpose W [K][N] fp32 -> f16 [N][K] ----------
__global__ __launch_bounds__(256) void transpose_f16_kernel(
    const float* __restrict__ W, unsigned short* __restrict__ hT,
    int Kd, int Nd) {
  __shared__ float tile[32][33];
  int r = threadIdx.x >> 3;
  int c = (threadIdx.x & 7) * 4;
  int k0 = blockIdx.y * 32, n0 = blockIdx.x * 32;
  float4 v = *(const float4*)&W[(size_t)(k0 + r) * Nd + n0 + c];
  tile[r][c] = v.x; tile[r][c + 1] = v.y; tile[r][c + 2] = v.z; tile[r][c + 3] = v.w;
  __syncthreads();
  size_t o = (size_t)(n0 + r) * Kd + k0 + c;
  *(ushort4*)&hT[o] = make_ushort4(f2h(tile[c + 0][r]), f2h(tile[c + 1][r]),
                                   f2h(tile[c + 2][r]), f2h(tile[c + 3][r]));
}

// =====================================================================
// qkv_kernel: fused QKV projection, 2-term f16 NT GEMM, 256x256 tile,
// BK=32, tri-buffer 144KB, 6 slots/wave, stage 2@p<3, VM(6).
// NO intra-tile barriers: within a tile, reads hit buf t%3 and stages
// hit buf (t+2)%3 (disjoint) -> only boundary sync needed (lgkm0 + VM + bar).
// N=3072 = [q | k | v]; epilogue per slab: q,k f16; v f16 transposed.
// =====================================================================
__global__ __launch_bounds__(512, 2) void qkv_kernel(
    const unsigned short* __restrict__ Ah, const unsigned short* __restrict__ Al,
    const unsigned short* __restrict__ WT, const float* __restrict__ bq,
    const float* __restrict__ bk, const float* __restrict__ bv,
    unsigned short* __restrict__ qh, unsigned short* __restrict__ kh,
    unsigned short* __restrict__ vT) {
  __shared__ __align__(16) char smem[3 * 48 * 1024];
  constexpr int lda = 1024, ldb = 1024, K = 1024;
  const int t = threadIdx.x, wid = t >> 6, lane = t & 63;
  const int waveM = wid >> 2, waveN = wid & 3;
  const int lr0 = lane & 15, lk0 = (lane >> 4) * 8;
  const int m0 = blockIdx.y * 256, n0 = blockIdx.x * 256;

  const unsigned short* slot_src[6];
#pragma unroll
  for (int s = 0; s < 6; ++s) {
    int si = 6 * wid + s;
    const unsigned short* p;
    if (si < 16)      p = Ah + (size_t)(m0 + si * 16 + lr0) * lda + lk0;
    else if (si < 32) p = Al + (size_t)(m0 + (si - 16) * 16 + lr0) * lda + lk0;
    else              p = WT + (size_t)(n0 + (si - 32) * 16 + lr0) * ldb + lk0;
    slot_src[s] = p;
  }

  const int NTILES = K >> 5;  // 32
  f32x4 acc[8][4] = {};

#pragma unroll
  for (int tt = 0; tt < 2; ++tt)
#pragma unroll
    for (int s = 0; s < 6; ++s)
      GLOAD16(slot_src[s] + (size_t)tt * 32,
              smem + tt * 49152 + (6 * wid + s) * 1024);
  VM(6);
  BARSYNC;
  __builtin_amdgcn_sched_barrier(0);

  for (int tile = 0; tile < NTILES; ++tile) {
    const int cur = tile % 3, nxt = (tile + 2) % 3;
    const bool do_stage = (tile + 2) < NTILES;
    const char* cb = smem + cur * 49152;
    char* nb = smem + nxt * 49152;
    half8 bf[4];
#pragma unroll
    for (int p = 0; p < 4; ++p) {
      half8 ahf[2], alf[2];
#pragma unroll
      for (int i = 0; i < 2; ++i) {
        int mg = waveM * 8 + 2 * p + i;
        ahf[i] = *(const half8*)(cb + mg * 1024 + lane * 16);
        alf[i] = *(const half8*)(cb + 16384 + mg * 1024 + lane * 16);
      }
      if (p == 0) {
#pragma unroll
        for (int j = 0; j < 4; ++j) {
          int ng = waveN * 4 + j;
          bf[j] = *(const half8*)(cb + 32768 + ng * 1024 + lane * 16);
        }
      }
      if (do_stage && p < 3) {
#pragma unroll
        for (int s = 0; s < 2; ++s) {
          int slot = 2 * p + s;
          GLOAD16(slot_src[slot] + (size_t)(tile + 2) * 32,
                  nb + (6 * wid + slot) * 1024);
        }
      }
      __builtin_amdgcn_s_setprio(1);
#pragma unroll
      for (int i = 0; i < 2; ++i)
#pragma unroll
        for (int j = 0; j < 4; ++j) {
          f32x4 c = acc[2 * p + i][j];
          c = __builtin_amdgcn_mfma_f32_16x16x32_f16(ahf[i], bf[j], c, 0, 0, 0);
          c = __builtin_amdgcn_mfma_f32_16x16x32_f16(alf[i], bf[j], c, 0, 0, 0);
          acc[2 * p + i][j] = c;
        }
      __builtin_amdgcn_s_setprio(0);
    }
    if (tile + 1 < NTILES) {
      LGKM0;                      // own ds_reads retired before crossing
      if (do_stage) VM(6); else VM(0);
      BARSYNC;
      __builtin_amdgcn_sched_barrier(0);
    }
  }

  const int or0 = (lane >> 4) * 4;
  const int slab = n0 >> 10;  // 0=q, 1=k, 2=v
#pragma unroll
  for (int mm = 0; mm < 8; ++mm)
#pragma unroll
    for (int j = 0; j < 4; ++j)
#pragma unroll
      for (int r = 0; r < 4; ++r) {
        int row = m0 + waveM * 128 + mm * 16 + or0 + r;
        int col = (n0 & 1023) + waveN * 64 + j * 16 + lr0;
        float x = acc[mm][j][r];
        if (slab == 0) {
          qh[(size_t)row * 1024 + col] = f2h(x + bq[col]);
        } else if (slab == 1) {
          kh[(size_t)row * 1024 + col] = f2h(x + bk[col]);
        } else {
          vT[(size_t)col * 8192 + row] = f2h(x + bv[col]);
        }
      }
}

// =====================================================================
// g1q: 1-term f16 NT GEMM (QK^T), 256x256, BK=32, tri-96KB, 4 slots/wave,
// stage 1/phase, VM(4). fp32 out. No intra-tile barriers (see qkv note).
// =====================================================================
__global__ __launch_bounds__(512, 2) void g1q_kernel(
    const unsigned short* __restrict__ Abase, size_t Astr, int lda,
    const unsigned short* __restrict__ Bbase, size_t Bstr, int ldb,
    float* __restrict__ outF, size_t Ostr, int ldo, int K) {
  __shared__ __align__(16) char smem[3 * 32 * 1024];
  const int t = threadIdx.x, wid = t >> 6, lane = t & 63;
  const int waveM = wid >> 2, waveN = wid & 3;
  const int lr0 = lane & 15, lk0 = (lane >> 4) * 8;
  const int m0 = blockIdx.y * 256, n0 = blockIdx.x * 256;
  const unsigned short* A = Abase + (size_t)blockIdx.z * Astr;
  const unsigned short* B = Bbase + (size_t)blockIdx.z * Bstr;
  float* out = outF + (size_t)blockIdx.z * Ostr;

  const unsigned short* slot_src[4];
#pragma unroll
  for (int s = 0; s < 4; ++s) {
    int si = 4 * wid + s;
    const unsigned short* p;
    if (si < 16) p = A + (size_t)(m0 + si * 16 + lr0) * lda + lk0;
    else         p = B + (size_t)(n0 + (si - 16) * 16 + lr0) * ldb + lk0;
    slot_src[s] = p;
  }

  const int NTILES = K >> 5;
  f32x4 acc[8][4] = {};

#pragma unroll
  for (int tt = 0; tt < 2; ++tt)
#pragma unroll
    for (int s = 0; s < 4; ++s)
      GLOAD16(slot_src[s] + (size_t)tt * 32,
              smem + tt * 32768 + (4 * wid + s) * 1024);
  VM(4);
  BARSYNC;
  __builtin_amdgcn_sched_barrier(0);

  for (int tile = 0; tile < NTILES; ++tile) {
    const int cur = tile % 3, nxt = (tile + 2) % 3;
    const bool do_stage = (tile + 2) < NTILES;
    const char* cb = smem + cur * 32768;
    char* nb = smem + nxt * 32768;
    half8 bf[4];
#pragma unroll
    for (int p = 0; p < 4; ++p) {
      half8 af[2];
#pragma unroll
      for (int i = 0; i < 2; ++i) {
        int mg = waveM * 8 + 2 * p + i;
        af[i] = *(const half8*)(cb + mg * 1024 + lane * 16);
      }
      if (p == 0) {
#pragma unroll
        for (int j = 0; j < 4; ++j) {
          int ng = waveN * 4 + j;
          bf[j] = *(const half8*)(cb + 16384 + ng * 1024 + lane * 16);
        }
      }
      if (do_stage)
        GLOAD16(slot_src[p] + (size_t)(tile + 2) * 32,
                nb + (4 * wid + p) * 1024);
      __builtin_amdgcn_s_setprio(1);
#pragma unroll
      for (int i = 0; i < 2; ++i)
#pragma unroll
        for (int j = 0; j < 4; ++j)
          acc[2 * p + i][j] = __builtin_amdgcn_mfma_f32_16x16x32_f16(
              af[i], bf[j], acc[2 * p + i][j], 0, 0, 0);
      __builtin_amdgcn_s_setprio(0);
    }
    if (tile + 1 < NTILES) {
      LGKM0;
      if (do_stage) VM(4); else VM(0);
      BARSYNC;
      __builtin_amdgcn_sched_barrier(0);
    }
  }

  const int or0 = (lane >> 4) * 4;
#pragma unroll
  for (int mm = 0; mm < 8; ++mm)
#pragma unroll
    for (int j = 0; j < 4; ++j)
#pragma unroll
      for (int r = 0; r < 4; ++r)
        out[(size_t)(m0 + waveM * 128 + mm * 16 + or0 + r) * ldo +
            (n0 + waveN * 64 + j * 16 + lr0)] = acc[mm][j][r];
}

// =====================================================================
// g1: 1-term f16 NT GEMM (PV), 256x128, BK=64, tri-144KB, 6 slots/wave,
// VM(6). fp32 out. No intra-tile barriers (see qkv note).
// =====================================================================
__global__ __launch_bounds__(512, 2) void g1_kernel(
    const unsigned short* __restrict__ Abase, size_t Astr, int lda,
    const unsigned short* __restrict__ Bbase, size_t Bstr, int ldb,
    float* __restrict__ outF, size_t Ostr, int ldo, int K) {
  __shared__ __align__(16) char smem[3 * 48 * 1024];
  const int t = threadIdx.x, wid = t >> 6, lane = t & 63;
  const int waveM = wid >> 2, waveN = wid & 3;
  const int lr0 = lane & 15, lk0 = (lane >> 4) * 8;
  const int m0 = blockIdx.y * 256, n0 = blockIdx.x * 128;
  const unsigned short* A = Abase + (size_t)blockIdx.z * Astr;
  const unsigned short* B = Bbase + (size_t)blockIdx.z * Bstr;
  float* out = outF + (size_t)blockIdx.z * Ostr;

  const unsigned short* slot_src[6];
#pragma unroll
  for (int s = 0; s < 6; ++s) {
    int si = 6 * wid + s;
    const unsigned short* p;
    if (si < 16)      p = A + (size_t)(m0 + si * 16 + lr0) * lda + lk0;
    else if (si < 32) p = A + (size_t)(m0 + (si - 16) * 16 + lr0) * lda + 32 + lk0;
    else if (si < 40) p = B + (size_t)(n0 + (si - 32) * 16 + lr0) * ldb + lk0;
    else              p = B + (size_t)(n0 + (si - 40) * 16 + lr0) * ldb + 32 + lk0;
    slot_src[s] = p;
  }

  const int NTILES = K >> 6;
  f32x4 acc[8][2] = {};

#pragma unroll
  for (int tt = 0; tt < 2; ++tt)
#pragma unroll
    for (int s = 0; s < 6; ++s)
      GLOAD16(slot_src[s] + (size_t)tt * 64,
              smem + tt * 49152 + (6 * wid + s) * 1024);
  VM(6);
  BARSYNC;
  __builtin_amdgcn_sched_barrier(0);

  for (int tile = 0; tile < NTILES; ++tile) {
    const int cur = tile % 3, nxt = (tile + 2) % 3;
    const bool do_stage = (tile + 2) < NTILES;
    const char* cb = smem + cur * 49152;
    char* nb = smem + nxt * 49152;
    half8 blo[2], bhi[2];
#pragma unroll
    for (int p = 0; p < 4; ++p) {
      half8 alo[2], ahi[2];
#pragma unroll
      for (int i = 0; i < 2; ++i) {
        int mg = waveM * 8 + 2 * p + i;
        alo[i] = *(const half8*)(cb + mg * 1024 + lane * 16);
        ahi[i] = *(const half8*)(cb + (16 + mg) * 1024 + lane * 16);
      }
      if (p == 0) {
#pragma unroll
        for (int j = 0; j < 2; ++j) {
          int ng = waveN * 2 + j;
          blo[j] = *(const half8*)(cb + (32 + ng) * 1024 + lane * 16);
          bhi[j] = *(const half8*)(cb + (40 + ng) * 1024 + lane * 16);
        }
      }
      if (do_stage && p < 3) {
#pragma unroll
        for (int s = 0; s < 2; ++s) {
          int slot = 2 * p + s;
          GLOAD16(slot_src[slot] + (size_t)(tile + 2) * 64,
                  nb + (6 * wid + slot) * 1024);
        }
      }
      __builtin_amdgcn_s_setprio(1);
#pragma unroll
      for (int i = 0; i < 2; ++i)
#pragma unroll
        for (int j = 0; j < 2; ++j) {
          f32x4 c = acc[2 * p + i][j];
          c = __builtin_amdgcn_mfma_f32_16x16x32_f16(alo[i], blo[j], c, 0, 0, 0);
          c = __builtin_amdgcn_mfma_f32_16x16x32_f16(ahi[i], bhi[j], c, 0, 0, 0);
          acc[2 * p + i][j] = c;
        }
      __builtin_amdgcn_s_setprio(0);
    }
    if (tile + 1 < NTILES) {
      LGKM0;
      if (do_stage) VM(6); else VM(0);
      BARSYNC;
      __builtin_amdgcn_sched_barrier(0);
    }
  }

  const int or0 = (lane >> 4) * 4;
#pragma unroll
  for (int mm = 0; mm < 8; ++mm)
#pragma unroll
    for (int j = 0; j < 2; ++j)
#pragma unroll
      for (int r = 0; r < 4; ++r)
        out[(size_t)(m0 + waveM * 128 + mm * 16 + or0 + r) * ldo +
            (n0 + waveN * 32 + j * 16 + lr0)] = acc[mm][j][r];
}

// ---------- row softmax: fp32 [4096] -> f16 probs (in-place, pld stride) ----
__global__ __launch_bounds__(256) void softmax_rows_kernel(
    const float* Sm, unsigned short* P, int ncol, int pld) {
  const int t = threadIdx.x;
  const float* srow = Sm + (size_t)blockIdx.x * ncol;
  float4 v[4];
  float m = -3.4e38f;
#pragma unroll
  for (int i = 0; i < 4; ++i) {
    v[i] = ((const float4*)srow)[t + 256 * i];
    m = fmaxf(m, fmaxf(fmaxf(v[i].x, v[i].y), fmaxf(v[i].z, v[i].w)));
  }
#pragma unroll
  for (int off = 32; off >= 1; off >>= 1) m = fmaxf(m, __shfl_down(m, off));
  __shared__ float redm[4];
  if ((t & 63) == 0) redm[t >> 6] = m;
  __syncthreads();
  m = fmaxf(fmaxf(redm[0], redm[1]), fmaxf(redm[2], redm[3]));
  float s = 0.f;
#pragma unroll
  for (int i = 0; i < 4; ++i) {
    v[i].x = __expf(v[i].x - m);
    v[i].y = __expf(v[i].y - m);
    v[i].z = __expf(v[i].z - m);
    v[i].w = __expf(v[i].w - m);
    s += v[i].x + v[i].y + v[i].z + v[i].w;
  }
#pragma unroll
  for (int off = 32; off >= 1; off >>= 1) s += __shfl_down(s, off);
  __shared__ float reds[4];
  if ((t & 63) == 0) reds[t >> 6] = s;
  __syncthreads();
  s = reds[0] + reds[1] + reds[2] + reds[3];
  float inv = 1.f / s;
  unsigned short* prow = P + (size_t)blockIdx.x * pld;
#pragma unroll
  for (int i = 0; i < 4; ++i) {
    ushort4 o = make_ushort4(f2h(v[i].x * inv), f2h(v[i].y * inv),
                             f2h(v[i].z * inv), f2h(v[i].w * inv));
    ((ushort4*)prow)[t + 256 * i] = o;
  }
}

extern "C" void kernel_launch(void* const* d_in, const int* in_sizes, int n_in,
                              void* d_out, int out_size, void* d_ws, size_t ws_size,
                              hipStream_t stream) {
  const float* hs = (const float*)d_in[0];
  const float* Wq = (const float*)d_in[1];
  const float* bq = (const float*)d_in[2];
  const float* Wk = (const float*)d_in[3];
  const float* bk = (const float*)d_in[4];
  const float* Wv = (const float*)d_in[5];
  const float* bv = (const float*)d_in[6];
  float* out = (float*)d_out;

  constexpr int Ss = 4096, Hh = 1024;
  constexpr int Mm = 8192;
  constexpr size_t TOK = (size_t)Ss * Hh;
  char* ws = (char*)d_ws;
  const size_t MB = 1024 * 1024;

  unsigned short* qh = (unsigned short*)(ws + 0 * MB);
  unsigned short* kh = (unsigned short*)(ws + 16 * MB);
  unsigned short* vT = (unsigned short*)(ws + 32 * MB);
  char* rb = ws + 48 * MB;
  unsigned short* hs_h = (unsigned short*)(rb + 0 * MB);
  unsigned short* hs_l = (unsigned short*)(rb + 16 * MB);
  unsigned short* WT = (unsigned short*)(rb + 32 * MB);  // [3072][1024]
  float* Sf = (float*)rb;

  const bool big = ws_size >= (size_t)176 * MB;

  // 1) splits; W -> [3072][1024] f16 (q | k | v)
  split_pair_f16_kernel<<<dim3(Mm * Hh / 2048), 256, 0, stream>>>(hs, hs_h, hs_l);
  transpose_f16_kernel<<<dim3(32, 32), 256, 0, stream>>>(Wq, WT, Hh, Hh);
  transpose_f16_kernel<<<dim3(32, 32), 256, 0, stream>>>(
      Wk, WT + (size_t)1024 * 1024, Hh, Hh);
  transpose_f16_kernel<<<dim3(32, 32), 256, 0, stream>>>(
      Wv, WT + (size_t)2048 * 1024, Hh, Hh);

  // 2) fused QKV projection (256x256 2-term)
  qkv_kernel<<<dim3(12, 32), 512, 0, stream>>>(
      hs_h, hs_l, WT, bq, bk, bv, qh, kh, vT);

  if (big) {
    // 3) QK^T both batches (256x256 1-term) -> S fp32 slabs
    g1q_kernel<<<dim3(16, 16, 2), 512, 0, stream>>>(
        qh, TOK, Hh, kh, TOK, Hh, Sf, (size_t)Ss * Ss, Ss, Hh);
    // 4) softmax 8192 rows, fp32 -> f16 in-place strided (pld 8192)
    softmax_rows_kernel<<<dim3(2 * Ss), 256, 0, stream>>>(
        Sf, (unsigned short*)Sf, Ss, 2 * Ss);
    // 5) PV both batches (256x128 1-term, grid 256)
    g1_kernel<<<dim3(8, 16, 2), 512, 0, stream>>>(
        (const unsigned short*)Sf, (size_t)Ss * 2 * Ss, 2 * Ss,
        vT, (size_t)Ss, Mm, out, TOK, Hh, Ss);
  } else {
    float* Sb = (float*)rb;
    unsigned short* Pb = (unsigned short*)(rb + 64 * MB);
    for (int b = 0; b < 2; ++b) {
      g1q_kernel<<<dim3(16, 16, 1), 512, 0, stream>>>(
          qh + b * TOK, 0, Hh, kh + b * TOK, 0, Hh, Sb, 0, Ss, Hh);
      softmax_rows_kernel<<<dim3(Ss), 256, 0, stream>>>(Sb, Pb, Ss, Ss);
      g1_kernel<<<dim3(8, 16, 1), 512, 0, stream>>>(
          Pb, 0, Ss, vT + (size_t)b * Ss, 0, Mm, out + b * TOK, 0, Hh, Ss);
    }
  }
}

// Round 12
// 403.125 us; speedup vs baseline: 1.0755x; 1.0382x over previous
//
#include <hip/hip_runtime.h>
#include <stdint.h>

typedef __attribute__((ext_vector_type(8))) short short8;
typedef __attribute__((ext_vector_type(8))) _Float16 half8;
typedef __attribute__((ext_vector_type(4))) float f32x4;

__device__ __forceinline__ unsigned short f2h(float x) {
  _Float16 h = (_Float16)x;
  return __builtin_bit_cast(unsigned short, h);
}
__device__ __forceinline__ float h2f(unsigned short u) {
  return (float)__builtin_bit_cast(_Float16, u);
}

#define GLOAD16(gsrc, ldst)                                              \
  __builtin_amdgcn_global_load_lds(                                      \
      (const __attribute__((address_space(1))) void*)(gsrc),             \
      (__attribute__((address_space(3))) void*)(ldst), 16, 0, 0)

#define VM(N) asm volatile("s_waitcnt vmcnt(" #N ")" ::: "memory")
#define BARSYNC __builtin_amdgcn_s_barrier()
#define LGKM0                                                \
  do {                                                       \
    asm volatile("s_waitcnt lgkmcnt(0)" ::: "memory");       \
    __builtin_amdgcn_sched_barrier(0);                       \
  } while (0)

// ---------- split fp32 -> (hi, lo) f16, 8 elems/thread ----------
__global__ __launch_bounds__(256) void split_pair_f16_kernel(
    const float* __restrict__ in, unsigned short* __restrict__ h,
    unsigned short* __restrict__ l) {
  size_t i = (size_t)blockIdx.x * 256 + threadIdx.x;
  float4 a = ((const float4*)in)[2 * i];
  float4 b = ((const float4*)in)[2 * i + 1];
  ushort4 h0 = make_ushort4(f2h(a.x), f2h(a.y), f2h(a.z), f2h(a.w));
  ushort4 h1 = make_ushort4(f2h(b.x), f2h(b.y), f2h(b.z), f2h(b.w));
  ((ushort4*)h)[2 * i] = h0;
  ((ushort4*)h)[2 * i + 1] = h1;
  ((ushort4*)l)[2 * i] = make_ushort4(
      f2h(a.x - h2f(h0.x)), f2h(a.y - h2f(h0.y)),
      f2h(a.z - h2f(h0.z)), f2h(a.w - h2f(h0.w)));
  ((ushort4*)l)[2 * i + 1] = make_ushort4(
      f2h(b.x - h2f(h1.x)), f2h(b.y - h2f(h1.y)),
      f2h(b.z - h2f(h1.z)), f2h(b.w - h2f(h1.w)));
}

// ---------- transpose W [K][N] fp32 -> f16 [N][K] ----------
__global__ __launch_bounds__(256) void transpose_f16_kernel(
    const float* __restrict__ W, unsigned short* __restrict__ hT,
    int Kd, int Nd) {
  __shared__ float tile[32][33];
  int r = threadIdx.x >> 3;
  int c = (threadIdx.x & 7) * 4;
  int k0 = blockIdx.y * 32, n0 = blockIdx.x * 32;
  float4 v = *(const float4*)&W[(size_t)(k0 + r) * Nd + n0 + c];
  tile[r][c] = v.x; tile[r][c + 1] = v.y; tile[r][c + 2] = v.z; tile[r][c + 3] = v.w;
  __syncthreads();
  size_t o = (size_t)(n0 + r) * Kd + k0 + c;
  *(ushort4*)&hT[o] = make_ushort4(f2h(tile[c + 0][r]), f2h(tile[c + 1][r]),
                                   f2h(tile[c + 2][r]), f2h(tile[c + 3][r]));
}

// =====================================================================
// qkv_kernel: fused QKV projection, 2-term f16 NT GEMM, 256x128 tile,
// BK=32, DOUBLE-buffer 80KB -> 2 blocks/CU (the m97 occupancy regime).
// Depth-1: stage all 5 slots at tile start into nbuf, compute tile from
// buf (no intra-tile barriers), then LGKM0 + VM(0) + barrier. The full
// drain is covered by the co-resident block (m114 co-scheduling).
// N=3072 = [q | k | v]; grid (24,32) = 768 blocks.
// =====================================================================
__global__ __launch_bounds__(512, 4) void qkv_kernel(
    const unsigned short* __restrict__ Ah, const unsigned short* __restrict__ Al,
    const unsigned short* __restrict__ WT, const float* __restrict__ bq,
    const float* __restrict__ bk, const float* __restrict__ bv,
    unsigned short* __restrict__ qh, unsigned short* __restrict__ kh,
    unsigned short* __restrict__ vT) {
  __shared__ __align__(16) char smem[2 * 40 * 1024];
  constexpr int lda = 1024, ldb = 1024, K = 1024;
  const int t = threadIdx.x, wid = t >> 6, lane = t & 63;
  const int waveM = wid >> 2, waveN = wid & 3;
  const int lr0 = lane & 15, lk0 = (lane >> 4) * 8;
  const int m0 = blockIdx.y * 256, n0 = blockIdx.x * 128;

  const unsigned short* slot_src[5];
#pragma unroll
  for (int s = 0; s < 5; ++s) {
    int si = 5 * wid + s;
    const unsigned short* p;
    if (si < 16)      p = Ah + (size_t)(m0 + si * 16 + lr0) * lda + lk0;
    else if (si < 32) p = Al + (size_t)(m0 + (si - 16) * 16 + lr0) * lda + lk0;
    else              p = WT + (size_t)(n0 + (si - 32) * 16 + lr0) * ldb + lk0;
    slot_src[s] = p;
  }

  const int NTILES = K >> 5;  // 32
  f32x4 acc[8][2] = {};

  // prologue: stage tile 0, drain, cross
#pragma unroll
  for (int s = 0; s < 5; ++s)
    GLOAD16(slot_src[s], smem + (5 * wid + s) * 1024);
  VM(0);
  BARSYNC;
  __builtin_amdgcn_sched_barrier(0);

  for (int tile = 0; tile < NTILES; ++tile) {
    const char* cb = smem + (tile & 1) * 40960;
    char* nb = smem + ((tile + 1) & 1) * 40960;
    if (tile + 1 < NTILES) {
#pragma unroll
      for (int s = 0; s < 5; ++s)
        GLOAD16(slot_src[s] + (size_t)(tile + 1) * 32,
                nb + (5 * wid + s) * 1024);
    }
    half8 bf[2];
#pragma unroll
    for (int p = 0; p < 4; ++p) {
      half8 ahf[2], alf[2];
#pragma unroll
      for (int i = 0; i < 2; ++i) {
        int mg = waveM * 8 + 2 * p + i;
        ahf[i] = *(const half8*)(cb + mg * 1024 + lane * 16);
        alf[i] = *(const half8*)(cb + (16 + mg) * 1024 + lane * 16);
      }
      if (p == 0) {
#pragma unroll
        for (int j = 0; j < 2; ++j) {
          int ng = waveN * 2 + j;
          bf[j] = *(const half8*)(cb + (32 + ng) * 1024 + lane * 16);
        }
      }
      __builtin_amdgcn_s_setprio(1);
#pragma unroll
      for (int i = 0; i < 2; ++i)
#pragma unroll
        for (int j = 0; j < 2; ++j) {
          f32x4 c = acc[2 * p + i][j];
          c = __builtin_amdgcn_mfma_f32_16x16x32_f16(ahf[i], bf[j], c, 0, 0, 0);
          c = __builtin_amdgcn_mfma_f32_16x16x32_f16(alf[i], bf[j], c, 0, 0, 0);
          acc[2 * p + i][j] = c;
        }
      __builtin_amdgcn_s_setprio(0);
    }
    if (tile + 1 < NTILES) {
      LGKM0;    // own ds_reads retired before others overwrite cb next round
      VM(0);    // next tile fully landed (drain covered by sibling block)
      BARSYNC;
      __builtin_amdgcn_sched_barrier(0);
    }
  }

  const int or0 = (lane >> 4) * 4;
  const int slab = n0 >> 10;  // 0=q, 1=k, 2=v
#pragma unroll
  for (int mm = 0; mm < 8; ++mm)
#pragma unroll
    for (int j = 0; j < 2; ++j)
#pragma unroll
      for (int r = 0; r < 4; ++r) {
        int row = m0 + waveM * 128 + mm * 16 + or0 + r;
        int col = (n0 & 1023) + waveN * 32 + j * 16 + lr0;
        float x = acc[mm][j][r];
        if (slab == 0) {
          qh[(size_t)row * 1024 + col] = f2h(x + bq[col]);
        } else if (slab == 1) {
          kh[(size_t)row * 1024 + col] = f2h(x + bk[col]);
        } else {
          vT[(size_t)col * 8192 + row] = f2h(x + bv[col]);
        }
      }
}

// =====================================================================
// g1q: 1-term f16 NT GEMM (QK^T), 256x256, BK=32, tri-96KB, 4 slots/wave,
// stage 1/phase, VM(4). fp32 out. (R7/R10-proven, unchanged.)
// =====================================================================
__global__ __launch_bounds__(512, 2) void g1q_kernel(
    const unsigned short* __restrict__ Abase, size_t Astr, int lda,
    const unsigned short* __restrict__ Bbase, size_t Bstr, int ldb,
    float* __restrict__ outF, size_t Ostr, int ldo, int K) {
  __shared__ __align__(16) char smem[3 * 32 * 1024];
  const int t = threadIdx.x, wid = t >> 6, lane = t & 63;
  const int waveM = wid >> 2, waveN = wid & 3;
  const int lr0 = lane & 15, lk0 = (lane >> 4) * 8;
  const int m0 = blockIdx.y * 256, n0 = blockIdx.x * 256;
  const unsigned short* A = Abase + (size_t)blockIdx.z * Astr;
  const unsigned short* B = Bbase + (size_t)blockIdx.z * Bstr;
  float* out = outF + (size_t)blockIdx.z * Ostr;

  const unsigned short* slot_src[4];
#pragma unroll
  for (int s = 0; s < 4; ++s) {
    int si = 4 * wid + s;
    const unsigned short* p;
    if (si < 16) p = A + (size_t)(m0 + si * 16 + lr0) * lda + lk0;
    else         p = B + (size_t)(n0 + (si - 16) * 16 + lr0) * ldb + lk0;
    slot_src[s] = p;
  }

  const int NTILES = K >> 5;
  f32x4 acc[8][4] = {};

#pragma unroll
  for (int tt = 0; tt < 2; ++tt)
#pragma unroll
    for (int s = 0; s < 4; ++s)
      GLOAD16(slot_src[s] + (size_t)tt * 32,
              smem + tt * 32768 + (4 * wid + s) * 1024);
  VM(4);
  BARSYNC;
  __builtin_amdgcn_sched_barrier(0);

  for (int tile = 0; tile < NTILES; ++tile) {
    const int cur = tile % 3, nxt = (tile + 2) % 3;
    const bool do_stage = (tile + 2) < NTILES;
    const char* cb = smem + cur * 32768;
    char* nb = smem + nxt * 32768;
    half8 bf[4];
#pragma unroll
    for (int p = 0; p < 4; ++p) {
      half8 af[2];
#pragma unroll
      for (int i = 0; i < 2; ++i) {
        int mg = waveM * 8 + 2 * p + i;
        af[i] = *(const half8*)(cb + mg * 1024 + lane * 16);
      }
      if (p == 0) {
#pragma unroll
        for (int j = 0; j < 4; ++j) {
          int ng = waveN * 4 + j;
          bf[j] = *(const half8*)(cb + 16384 + ng * 1024 + lane * 16);
        }
      }
      if (do_stage)
        GLOAD16(slot_src[p] + (size_t)(tile + 2) * 32,
                nb + (4 * wid + p) * 1024);
      __builtin_amdgcn_s_setprio(1);
#pragma unroll
      for (int i = 0; i < 2; ++i)
#pragma unroll
        for (int j = 0; j < 4; ++j)
          acc[2 * p + i][j] = __builtin_amdgcn_mfma_f32_16x16x32_f16(
              af[i], bf[j], acc[2 * p + i][j], 0, 0, 0);
      __builtin_amdgcn_s_setprio(0);
    }
    if (tile + 1 < NTILES) {
      LGKM0;
      if (do_stage) VM(4); else VM(0);
      BARSYNC;
      __builtin_amdgcn_sched_barrier(0);
    }
  }

  const int or0 = (lane >> 4) * 4;
#pragma unroll
  for (int mm = 0; mm < 8; ++mm)
#pragma unroll
    for (int j = 0; j < 4; ++j)
#pragma unroll
      for (int r = 0; r < 4; ++r)
        out[(size_t)(m0 + waveM * 128 + mm * 16 + or0 + r) * ldo +
            (n0 + waveN * 64 + j * 16 + lr0)] = acc[mm][j][r];
}

// =====================================================================
// g1: 1-term f16 NT GEMM (PV), 256x128, BK=64, tri-144KB, 6 slots/wave,
// VM(6). fp32 out. (R6/R10-proven, unchanged.)
// =====================================================================
__global__ __launch_bounds__(512, 2) void g1_kernel(
    const unsigned short* __restrict__ Abase, size_t Astr, int lda,
    const unsigned short* __restrict__ Bbase, size_t Bstr, int ldb,
    float* __restrict__ outF, size_t Ostr, int ldo, int K) {
  __shared__ __align__(16) char smem[3 * 48 * 1024];
  const int t = threadIdx.x, wid = t >> 6, lane = t & 63;
  const int waveM = wid >> 2, waveN = wid & 3;
  const int lr0 = lane & 15, lk0 = (lane >> 4) * 8;
  const int m0 = blockIdx.y * 256, n0 = blockIdx.x * 128;
  const unsigned short* A = Abase + (size_t)blockIdx.z * Astr;
  const unsigned short* B = Bbase + (size_t)blockIdx.z * Bstr;
  float* out = outF + (size_t)blockIdx.z * Ostr;

  const unsigned short* slot_src[6];
#pragma unroll
  for (int s = 0; s < 6; ++s) {
    int si = 6 * wid + s;
    const unsigned short* p;
    if (si < 16)      p = A + (size_t)(m0 + si * 16 + lr0) * lda + lk0;
    else if (si < 32) p = A + (size_t)(m0 + (si - 16) * 16 + lr0) * lda + 32 + lk0;
    else if (si < 40) p = B + (size_t)(n0 + (si - 32) * 16 + lr0) * ldb + lk0;
    else              p = B + (size_t)(n0 + (si - 40) * 16 + lr0) * ldb + 32 + lk0;
    slot_src[s] = p;
  }

  const int NTILES = K >> 6;
  f32x4 acc[8][2] = {};

#pragma unroll
  for (int tt = 0; tt < 2; ++tt)
#pragma unroll
    for (int s = 0; s < 6; ++s)
      GLOAD16(slot_src[s] + (size_t)tt * 64,
              smem + tt * 49152 + (6 * wid + s) * 1024);
  VM(6);
  BARSYNC;
  __builtin_amdgcn_sched_barrier(0);

  for (int tile = 0; tile < NTILES; ++tile) {
    const int cur = tile % 3, nxt = (tile + 2) % 3;
    const bool do_stage = (tile + 2) < NTILES;
    const char* cb = smem + cur * 49152;
    char* nb = smem + nxt * 49152;
    half8 blo[2], bhi[2];
#pragma unroll
    for (int p = 0; p < 4; ++p) {
      half8 alo[2], ahi[2];
#pragma unroll
      for (int i = 0; i < 2; ++i) {
        int mg = waveM * 8 + 2 * p + i;
        alo[i] = *(const half8*)(cb + mg * 1024 + lane * 16);
        ahi[i] = *(const half8*)(cb + (16 + mg) * 1024 + lane * 16);
      }
      if (p == 0) {
#pragma unroll
        for (int j = 0; j < 2; ++j) {
          int ng = waveN * 2 + j;
          blo[j] = *(const half8*)(cb + (32 + ng) * 1024 + lane * 16);
          bhi[j] = *(const half8*)(cb + (40 + ng) * 1024 + lane * 16);
        }
      }
      if (do_stage && p < 3) {
#pragma unroll
        for (int s = 0; s < 2; ++s) {
          int slot = 2 * p + s;
          GLOAD16(slot_src[slot] + (size_t)(tile + 2) * 64,
                  nb + (6 * wid + slot) * 1024);
        }
      }
      __builtin_amdgcn_s_setprio(1);
#pragma unroll
      for (int i = 0; i < 2; ++i)
#pragma unroll
        for (int j = 0; j < 2; ++j) {
          f32x4 c = acc[2 * p + i][j];
          c = __builtin_amdgcn_mfma_f32_16x16x32_f16(alo[i], blo[j], c, 0, 0, 0);
          c = __builtin_amdgcn_mfma_f32_16x16x32_f16(ahi[i], bhi[j], c, 0, 0, 0);
          acc[2 * p + i][j] = c;
        }
      __builtin_amdgcn_s_setprio(0);
    }
    if (tile + 1 < NTILES) {
      LGKM0;
      if (do_stage) VM(6); else VM(0);
      BARSYNC;
      __builtin_amdgcn_sched_barrier(0);
    }
  }

  const int or0 = (lane >> 4) * 4;
#pragma unroll
  for (int mm = 0; mm < 8; ++mm)
#pragma unroll
    for (int j = 0; j < 2; ++j)
#pragma unroll
      for (int r = 0; r < 4; ++r)
        out[(size_t)(m0 + waveM * 128 + mm * 16 + or0 + r) * ldo +
            (n0 + waveN * 32 + j * 16 + lr0)] = acc[mm][j][r];
}

// ---------- row softmax: fp32 [4096] -> f16 probs (in-place, pld stride) ----
__global__ __launch_bounds__(256) void softmax_rows_kernel(
    const float* Sm, unsigned short* P, int ncol, int pld) {
  const int t = threadIdx.x;
  const float* srow = Sm + (size_t)blockIdx.x * ncol;
  float4 v[4];
  float m = -3.4e38f;
#pragma unroll
  for (int i = 0; i < 4; ++i) {
    v[i] = ((const float4*)srow)[t + 256 * i];
    m = fmaxf(m, fmaxf(fmaxf(v[i].x, v[i].y), fmaxf(v[i].z, v[i].w)));
  }
#pragma unroll
  for (int off = 32; off >= 1; off >>= 1) m = fmaxf(m, __shfl_down(m, off));
  __shared__ float redm[4];
  if ((t & 63) == 0) redm[t >> 6] = m;
  __syncthreads();
  m = fmaxf(fmaxf(redm[0], redm[1]), fmaxf(redm[2], redm[3]));
  float s = 0.f;
#pragma unroll
  for (int i = 0; i < 4; ++i) {
    v[i].x = __expf(v[i].x - m);
    v[i].y = __expf(v[i].y - m);
    v[i].z = __expf(v[i].z - m);
    v[i].w = __expf(v[i].w - m);
    s += v[i].x + v[i].y + v[i].z + v[i].w;
  }
#pragma unroll
  for (int off = 32; off >= 1; off >>= 1) s += __shfl_down(s, off);
  __shared__ float reds[4];
  if ((t & 63) == 0) reds[t >> 6] = s;
  __syncthreads();
  s = reds[0] + reds[1] + reds[2] + reds[3];
  float inv = 1.f / s;
  unsigned short* prow = P + (size_t)blockIdx.x * pld;
#pragma unroll
  for (int i = 0; i < 4; ++i) {
    ushort4 o = make_ushort4(f2h(v[i].x * inv), f2h(v[i].y * inv),
                             f2h(v[i].z * inv), f2h(v[i].w * inv));
    ((ushort4*)prow)[t + 256 * i] = o;
  }
}

extern "C" void kernel_launch(void* const* d_in, const int* in_sizes, int n_in,
                              void* d_out, int out_size, void* d_ws, size_t ws_size,
                              hipStream_t stream) {
  const float* hs = (const float*)d_in[0];
  const float* Wq = (const float*)d_in[1];
  const float* bq = (const float*)d_in[2];
  const float* Wk = (const float*)d_in[3];
  const float* bk = (const float*)d_in[4];
  const float* Wv = (const float*)d_in[5];
  const float* bv = (const float*)d_in[6];
  float* out = (float*)d_out;

  constexpr int Ss = 4096, Hh = 1024;
  constexpr int Mm = 8192;
  constexpr size_t TOK = (size_t)Ss * Hh;
  char* ws = (char*)d_ws;
  const size_t MB = 1024 * 1024;

  unsigned short* qh = (unsigned short*)(ws + 0 * MB);
  unsigned short* kh = (unsigned short*)(ws + 16 * MB);
  unsigned short* vT = (unsigned short*)(ws + 32 * MB);
  char* rb = ws + 48 * MB;
  unsigned short* hs_h = (unsigned short*)(rb + 0 * MB);
  unsigned short* hs_l = (unsigned short*)(rb + 16 * MB);
  unsigned short* WT = (unsigned short*)(rb + 32 * MB);  // [3072][1024]
  float* Sf = (float*)rb;

  const bool big = ws_size >= (size_t)176 * MB;

  // 1) splits; W -> [3072][1024] f16 (q | k | v)
  split_pair_f16_kernel<<<dim3(Mm * Hh / 2048), 256, 0, stream>>>(hs, hs_h, hs_l);
  transpose_f16_kernel<<<dim3(32, 32), 256, 0, stream>>>(Wq, WT, Hh, Hh);
  transpose_f16_kernel<<<dim3(32, 32), 256, 0, stream>>>(
      Wk, WT + (size_t)1024 * 1024, Hh, Hh);
  transpose_f16_kernel<<<dim3(32, 32), 256, 0, stream>>>(
      Wv, WT + (size_t)2048 * 1024, Hh, Hh);

  // 2) fused QKV projection (256x128 2-term, double-buffer, 2 blocks/CU)
  qkv_kernel<<<dim3(24, 32), 512, 0, stream>>>(
      hs_h, hs_l, WT, bq, bk, bv, qh, kh, vT);

  if (big) {
    // 3) QK^T both batches (256x256 1-term) -> S fp32 slabs
    g1q_kernel<<<dim3(16, 16, 2), 512, 0, stream>>>(
        qh, TOK, Hh, kh, TOK, Hh, Sf, (size_t)Ss * Ss, Ss, Hh);
    // 4) softmax 8192 rows, fp32 -> f16 in-place strided (pld 8192)
    softmax_rows_kernel<<<dim3(2 * Ss), 256, 0, stream>>>(
        Sf, (unsigned short*)Sf, Ss, 2 * Ss);
    // 5) PV both batches (256x128 1-term, grid 256)
    g1_kernel<<<dim3(8, 16, 2), 512, 0, stream>>>(
        (const unsigned short*)Sf, (size_t)Ss * 2 * Ss, 2 * Ss,
        vT, (size_t)Ss, Mm, out, TOK, Hh, Ss);
  } else {
    float* Sb = (float*)rb;
    unsigned short* Pb = (unsigned short*)(rb + 64 * MB);
    for (int b = 0; b < 2; ++b) {
      g1q_kernel<<<dim3(16, 16, 1), 512, 0, stream>>>(
          qh + b * TOK, 0, Hh, kh + b * TOK, 0, Hh, Sb, 0, Ss, Hh);
      softmax_rows_kernel<<<dim3(Ss), 256, 0, stream>>>(Sb, Pb, Ss, Ss);
      g1_kernel<<<dim3(8, 16, 1), 512, 0, stream>>>(
          Pb, 0, Ss, vT + (size_t)b * Ss, 0, Mm, out + b * TOK, 0, Hh, Ss);
    }
  }
}

// Round 13
// 392.149 us; speedup vs baseline: 1.1056x; 1.0280x over previous
//
#include <hip/hip_runtime.h>
#include <stdint.h>

typedef __attribute__((ext_vector_type(8))) short short8;
typedef __attribute__((ext_vector_type(8))) _Float16 half8;
typedef __attribute__((ext_vector_type(4))) float f32x4;

__device__ __forceinline__ unsigned short f2h(float x) {
  _Float16 h = (_Float16)x;
  return __builtin_bit_cast(unsigned short, h);
}
__device__ __forceinline__ float h2f(unsigned short u) {
  return (float)__builtin_bit_cast(_Float16, u);
}

#define GLOAD16(gsrc, ldst)                                              \
  __builtin_amdgcn_global_load_lds(                                      \
      (const __attribute__((address_space(1))) void*)(gsrc),             \
      (__attribute__((address_space(3))) void*)(ldst), 16, 0, 0)

#define VM(N) asm volatile("s_waitcnt vmcnt(" #N ")" ::: "memory")
#define BARSYNC __builtin_amdgcn_s_barrier()
#define LGKM0                                                \
  do {                                                       \
    asm volatile("s_waitcnt lgkmcnt(0)" ::: "memory");       \
    __builtin_amdgcn_sched_barrier(0);                       \
  } while (0)

// ---------- split fp32 -> (hi, lo) f16, 8 elems/thread ----------
__global__ __launch_bounds__(256) void split_pair_f16_kernel(
    const float* __restrict__ in, unsigned short* __restrict__ h,
    unsigned short* __restrict__ l) {
  size_t i = (size_t)blockIdx.x * 256 + threadIdx.x;
  float4 a = ((const float4*)in)[2 * i];
  float4 b = ((const float4*)in)[2 * i + 1];
  ushort4 h0 = make_ushort4(f2h(a.x), f2h(a.y), f2h(a.z), f2h(a.w));
  ushort4 h1 = make_ushort4(f2h(b.x), f2h(b.y), f2h(b.z), f2h(b.w));
  ((ushort4*)h)[2 * i] = h0;
  ((ushort4*)h)[2 * i + 1] = h1;
  ((ushort4*)l)[2 * i] = make_ushort4(
      f2h(a.x - h2f(h0.x)), f2h(a.y - h2f(h0.y)),
      f2h(a.z - h2f(h0.z)), f2h(a.w - h2f(h0.w)));
  ((ushort4*)l)[2 * i + 1] = make_ushort4(
      f2h(b.x - h2f(h1.x)), f2h(b.y - h2f(h1.y)),
      f2h(b.z - h2f(h1.z)), f2h(b.w - h2f(h1.w)));
}

// ---------- transpose W [K][N] fp32 -> f16 [N][K] ----------
__global__ __launch_bounds__(256) void transpose_f16_kernel(
    const float* __restrict__ W, unsigned short* __restrict__ hT,
    int Kd, int Nd) {
  __shared__ float tile[32][33];
  int r = threadIdx.x >> 3;
  int c = (threadIdx.x & 7) * 4;
  int k0 = blockIdx.y * 32, n0 = blockIdx.x * 32;
  float4 v = *(const float4*)&W[(size_t)(k0 + r) * Nd + n0 + c];
  tile[r][c] = v.x; tile[r][c + 1] = v.y; tile[r][c + 2] = v.z; tile[r][c + 3] = v.w;
  __syncthreads();
  size_t o = (size_t)(n0 + r) * Kd + k0 + c;
  *(ushort4*)&hT[o] = make_ushort4(f2h(tile[c + 0][r]), f2h(tile[c + 1][r]),
                                   f2h(tile[c + 2][r]), f2h(tile[c + 3][r]));
}

// ---------- transpose V [8192][1024] f16 -> vT [1024][8192] f16 ----------
__global__ __launch_bounds__(256) void transpose_v_kernel(
    const unsigned short* __restrict__ Vs, unsigned short* __restrict__ vT) {
  __shared__ unsigned short tile[32][36];
  int r = threadIdx.x >> 3;        // 0..31
  int c = (threadIdx.x & 7) * 4;   // 0,4,..,28
  int col0 = blockIdx.x * 32;      // over H = 1024
  int row0 = blockIdx.y * 32;      // over tokens = 8192
  ushort4 v = *(const ushort4*)&Vs[(size_t)(row0 + r) * 1024 + col0 + c];
  tile[r][c] = v.x; tile[r][c + 1] = v.y; tile[r][c + 2] = v.z; tile[r][c + 3] = v.w;
  __syncthreads();
  ushort4 o = make_ushort4(tile[c + 0][r], tile[c + 1][r],
                           tile[c + 2][r], tile[c + 3][r]);
  *(ushort4*)&vT[(size_t)(col0 + r) * 8192 + row0 + c] = o;
}

// =====================================================================
// qkv_kernel: fused QKV projection, 2-term f16 NT GEMM, 256x128 tile,
// BK=32, double-buffer 80KB (2 blocks/CU). ALL epilogue writes coalesced:
// q,k f16 [row][col]; v f16 [row][col] into vS (transposed separately).
// N=3072 = [q | k | v]; grid (24,32) = 768 blocks.
// =====================================================================
__global__ __launch_bounds__(512, 4) void qkv_kernel(
    const unsigned short* __restrict__ Ah, const unsigned short* __restrict__ Al,
    const unsigned short* __restrict__ WT, const float* __restrict__ bq,
    const float* __restrict__ bk, const float* __restrict__ bv,
    unsigned short* __restrict__ qh, unsigned short* __restrict__ kh,
    unsigned short* __restrict__ vS) {
  __shared__ __align__(16) char smem[2 * 40 * 1024];
  constexpr int lda = 1024, ldb = 1024, K = 1024;
  const int t = threadIdx.x, wid = t >> 6, lane = t & 63;
  const int waveM = wid >> 2, waveN = wid & 3;
  const int lr0 = lane & 15, lk0 = (lane >> 4) * 8;
  const int m0 = blockIdx.y * 256, n0 = blockIdx.x * 128;

  const unsigned short* slot_src[5];
#pragma unroll
  for (int s = 0; s < 5; ++s) {
    int si = 5 * wid + s;
    const unsigned short* p;
    if (si < 16)      p = Ah + (size_t)(m0 + si * 16 + lr0) * lda + lk0;
    else if (si < 32) p = Al + (size_t)(m0 + (si - 16) * 16 + lr0) * lda + lk0;
    else              p = WT + (size_t)(n0 + (si - 32) * 16 + lr0) * ldb + lk0;
    slot_src[s] = p;
  }

  const int NTILES = K >> 5;  // 32
  f32x4 acc[8][2] = {};

#pragma unroll
  for (int s = 0; s < 5; ++s)
    GLOAD16(slot_src[s], smem + (5 * wid + s) * 1024);
  VM(0);
  BARSYNC;
  __builtin_amdgcn_sched_barrier(0);

  for (int tile = 0; tile < NTILES; ++tile) {
    const char* cb = smem + (tile & 1) * 40960;
    char* nb = smem + ((tile + 1) & 1) * 40960;
    if (tile + 1 < NTILES) {
#pragma unroll
      for (int s = 0; s < 5; ++s)
        GLOAD16(slot_src[s] + (size_t)(tile + 1) * 32,
                nb + (5 * wid + s) * 1024);
    }
    half8 bf[2];
#pragma unroll
    for (int p = 0; p < 4; ++p) {
      half8 ahf[2], alf[2];
#pragma unroll
      for (int i = 0; i < 2; ++i) {
        int mg = waveM * 8 + 2 * p + i;
        ahf[i] = *(const half8*)(cb + mg * 1024 + lane * 16);
        alf[i] = *(const half8*)(cb + (16 + mg) * 1024 + lane * 16);
      }
      if (p == 0) {
#pragma unroll
        for (int j = 0; j < 2; ++j) {
          int ng = waveN * 2 + j;
          bf[j] = *(const half8*)(cb + (32 + ng) * 1024 + lane * 16);
        }
      }
      __builtin_amdgcn_s_setprio(1);
#pragma unroll
      for (int i = 0; i < 2; ++i)
#pragma unroll
        for (int j = 0; j < 2; ++j) {
          f32x4 c = acc[2 * p + i][j];
          c = __builtin_amdgcn_mfma_f32_16x16x32_f16(ahf[i], bf[j], c, 0, 0, 0);
          c = __builtin_amdgcn_mfma_f32_16x16x32_f16(alf[i], bf[j], c, 0, 0, 0);
          acc[2 * p + i][j] = c;
        }
      __builtin_amdgcn_s_setprio(0);
    }
    if (tile + 1 < NTILES) {
      LGKM0;
      VM(0);
      BARSYNC;
      __builtin_amdgcn_sched_barrier(0);
    }
  }

  const int or0 = (lane >> 4) * 4;
  const int slab = n0 >> 10;  // 0=q, 1=k, 2=v
#pragma unroll
  for (int mm = 0; mm < 8; ++mm)
#pragma unroll
    for (int j = 0; j < 2; ++j)
#pragma unroll
      for (int r = 0; r < 4; ++r) {
        int row = m0 + waveM * 128 + mm * 16 + or0 + r;
        int col = (n0 & 1023) + waveN * 32 + j * 16 + lr0;
        float x = acc[mm][j][r];
        if (slab == 0) {
          qh[(size_t)row * 1024 + col] = f2h(x + bq[col]);
        } else if (slab == 1) {
          kh[(size_t)row * 1024 + col] = f2h(x + bk[col]);
        } else {
          vS[(size_t)row * 1024 + col] = f2h(x + bv[col]);  // coalesced
        }
      }
}

// =====================================================================
// g1q: 1-term f16 NT GEMM (QK^T), 256x256, BK=32, tri-96KB, 4 slots/wave,
// stage 1/phase, VM(4). fp32 out. (R7/R10-proven, unchanged.)
// =====================================================================
__global__ __launch_bounds__(512, 2) void g1q_kernel(
    const unsigned short* __restrict__ Abase, size_t Astr, int lda,
    const unsigned short* __restrict__ Bbase, size_t Bstr, int ldb,
    float* __restrict__ outF, size_t Ostr, int ldo, int K) {
  __shared__ __align__(16) char smem[3 * 32 * 1024];
  const int t = threadIdx.x, wid = t >> 6, lane = t & 63;
  const int waveM = wid >> 2, waveN = wid & 3;
  const int lr0 = lane & 15, lk0 = (lane >> 4) * 8;
  const int m0 = blockIdx.y * 256, n0 = blockIdx.x * 256;
  const unsigned short* A = Abase + (size_t)blockIdx.z * Astr;
  const unsigned short* B = Bbase + (size_t)blockIdx.z * Bstr;
  float* out = outF + (size_t)blockIdx.z * Ostr;

  const unsigned short* slot_src[4];
#pragma unroll
  for (int s = 0; s < 4; ++s) {
    int si = 4 * wid + s;
    const unsigned short* p;
    if (si < 16) p = A + (size_t)(m0 + si * 16 + lr0) * lda + lk0;
    else         p = B + (size_t)(n0 + (si - 16) * 16 + lr0) * ldb + lk0;
    slot_src[s] = p;
  }

  const int NTILES = K >> 5;
  f32x4 acc[8][4] = {};

#pragma unroll
  for (int tt = 0; tt < 2; ++tt)
#pragma unroll
    for (int s = 0; s < 4; ++s)
      GLOAD16(slot_src[s] + (size_t)tt * 32,
              smem + tt * 32768 + (4 * wid + s) * 1024);
  VM(4);
  BARSYNC;
  __builtin_amdgcn_sched_barrier(0);

  for (int tile = 0; tile < NTILES; ++tile) {
    const int cur = tile % 3, nxt = (tile + 2) % 3;
    const bool do_stage = (tile + 2) < NTILES;
    const char* cb = smem + cur * 32768;
    char* nb = smem + nxt * 32768;
    half8 bf[4];
#pragma unroll
    for (int p = 0; p < 4; ++p) {
      half8 af[2];
#pragma unroll
      for (int i = 0; i < 2; ++i) {
        int mg = waveM * 8 + 2 * p + i;
        af[i] = *(const half8*)(cb + mg * 1024 + lane * 16);
      }
      if (p == 0) {
#pragma unroll
        for (int j = 0; j < 4; ++j) {
          int ng = waveN * 4 + j;
          bf[j] = *(const half8*)(cb + 16384 + ng * 1024 + lane * 16);
        }
      }
      if (do_stage)
        GLOAD16(slot_src[p] + (size_t)(tile + 2) * 32,
                nb + (4 * wid + p) * 1024);
      __builtin_amdgcn_s_setprio(1);
#pragma unroll
      for (int i = 0; i < 2; ++i)
#pragma unroll
        for (int j = 0; j < 4; ++j)
          acc[2 * p + i][j] = __builtin_amdgcn_mfma_f32_16x16x32_f16(
              af[i], bf[j], acc[2 * p + i][j], 0, 0, 0);
      __builtin_amdgcn_s_setprio(0);
    }
    if (tile + 1 < NTILES) {
      LGKM0;
      if (do_stage) VM(4); else VM(0);
      BARSYNC;
      __builtin_amdgcn_sched_barrier(0);
    }
  }

  const int or0 = (lane >> 4) * 4;
#pragma unroll
  for (int mm = 0; mm < 8; ++mm)
#pragma unroll
    for (int j = 0; j < 4; ++j)
#pragma unroll
      for (int r = 0; r < 4; ++r)
        out[(size_t)(m0 + waveM * 128 + mm * 16 + or0 + r) * ldo +
            (n0 + waveN * 64 + j * 16 + lr0)] = acc[mm][j][r];
}

// =====================================================================
// g1: 1-term f16 NT GEMM (PV), 256x128, BK=64, tri-144KB, 6 slots/wave,
// VM(6). fp32 out. (R6/R10-proven, unchanged.)
// =====================================================================
__global__ __launch_bounds__(512, 2) void g1_kernel(
    const unsigned short* __restrict__ Abase, size_t Astr, int lda,
    const unsigned short* __restrict__ Bbase, size_t Bstr, int ldb,
    float* __restrict__ outF, size_t Ostr, int ldo, int K) {
  __shared__ __align__(16) char smem[3 * 48 * 1024];
  const int t = threadIdx.x, wid = t >> 6, lane = t & 63;
  const int waveM = wid >> 2, waveN = wid & 3;
  const int lr0 = lane & 15, lk0 = (lane >> 4) * 8;
  const int m0 = blockIdx.y * 256, n0 = blockIdx.x * 128;
  const unsigned short* A = Abase + (size_t)blockIdx.z * Astr;
  const unsigned short* B = Bbase + (size_t)blockIdx.z * Bstr;
  float* out = outF + (size_t)blockIdx.z * Ostr;

  const unsigned short* slot_src[6];
#pragma unroll
  for (int s = 0; s < 6; ++s) {
    int si = 6 * wid + s;
    const unsigned short* p;
    if (si < 16)      p = A + (size_t)(m0 + si * 16 + lr0) * lda + lk0;
    else if (si < 32) p = A + (size_t)(m0 + (si - 16) * 16 + lr0) * lda + 32 + lk0;
    else if (si < 40) p = B + (size_t)(n0 + (si - 32) * 16 + lr0) * ldb + lk0;
    else              p = B + (size_t)(n0 + (si - 40) * 16 + lr0) * ldb + 32 + lk0;
    slot_src[s] = p;
  }

  const int NTILES = K >> 6;
  f32x4 acc[8][2] = {};

#pragma unroll
  for (int tt = 0; tt < 2; ++tt)
#pragma unroll
    for (int s = 0; s < 6; ++s)
      GLOAD16(slot_src[s] + (size_t)tt * 64,
              smem + tt * 49152 + (6 * wid + s) * 1024);
  VM(6);
  BARSYNC;
  __builtin_amdgcn_sched_barrier(0);

  for (int tile = 0; tile < NTILES; ++tile) {
    const int cur = tile % 3, nxt = (tile + 2) % 3;
    const bool do_stage = (tile + 2) < NTILES;
    const char* cb = smem + cur * 49152;
    char* nb = smem + nxt * 49152;
    half8 blo[2], bhi[2];
#pragma unroll
    for (int p = 0; p < 4; ++p) {
      half8 alo[2], ahi[2];
#pragma unroll
      for (int i = 0; i < 2; ++i) {
        int mg = waveM * 8 + 2 * p + i;
        alo[i] = *(const half8*)(cb + mg * 1024 + lane * 16);
        ahi[i] = *(const half8*)(cb + (16 + mg) * 1024 + lane * 16);
      }
      if (p == 0) {
#pragma unroll
        for (int j = 0; j < 2; ++j) {
          int ng = waveN * 2 + j;
          blo[j] = *(const half8*)(cb + (32 + ng) * 1024 + lane * 16);
          bhi[j] = *(const half8*)(cb + (40 + ng) * 1024 + lane * 16);
        }
      }
      if (do_stage && p < 3) {
#pragma unroll
        for (int s = 0; s < 2; ++s) {
          int slot = 2 * p + s;
          GLOAD16(slot_src[slot] + (size_t)(tile + 2) * 64,
                  nb + (6 * wid + slot) * 1024);
        }
      }
      __builtin_amdgcn_s_setprio(1);
#pragma unroll
      for (int i = 0; i < 2; ++i)
#pragma unroll
        for (int j = 0; j < 2; ++j) {
          f32x4 c = acc[2 * p + i][j];
          c = __builtin_amdgcn_mfma_f32_16x16x32_f16(alo[i], blo[j], c, 0, 0, 0);
          c = __builtin_amdgcn_mfma_f32_16x16x32_f16(ahi[i], bhi[j], c, 0, 0, 0);
          acc[2 * p + i][j] = c;
        }
      __builtin_amdgcn_s_setprio(0);
    }
    if (tile + 1 < NTILES) {
      LGKM0;
      if (do_stage) VM(6); else VM(0);
      BARSYNC;
      __builtin_amdgcn_sched_barrier(0);
    }
  }

  const int or0 = (lane >> 4) * 4;
#pragma unroll
  for (int mm = 0; mm < 8; ++mm)
#pragma unroll
    for (int j = 0; j < 2; ++j)
#pragma unroll
      for (int r = 0; r < 4; ++r)
        out[(size_t)(m0 + waveM * 128 + mm * 16 + or0 + r) * ldo +
            (n0 + waveN * 32 + j * 16 + lr0)] = acc[mm][j][r];
}

// ---------- row softmax: fp32 [4096] -> f16 probs (in-place, pld stride) ----
__global__ __launch_bounds__(256) void softmax_rows_kernel(
    const float* Sm, unsigned short* P, int ncol, int pld) {
  const int t = threadIdx.x;
  const float* srow = Sm + (size_t)blockIdx.x * ncol;
  float4 v[4];
  float m = -3.4e38f;
#pragma unroll
  for (int i = 0; i < 4; ++i) {
    v[i] = ((const float4*)srow)[t + 256 * i];
    m = fmaxf(m, fmaxf(fmaxf(v[i].x, v[i].y), fmaxf(v[i].z, v[i].w)));
  }
#pragma unroll
  for (int off = 32; off >= 1; off >>= 1) m = fmaxf(m, __shfl_down(m, off));
  __shared__ float redm[4];
  if ((t & 63) == 0) redm[t >> 6] = m;
  __syncthreads();
  m = fmaxf(fmaxf(redm[0], redm[1]), fmaxf(redm[2], redm[3]));
  float s = 0.f;
#pragma unroll
  for (int i = 0; i < 4; ++i) {
    v[i].x = __expf(v[i].x - m);
    v[i].y = __expf(v[i].y - m);
    v[i].z = __expf(v[i].z - m);
    v[i].w = __expf(v[i].w - m);
    s += v[i].x + v[i].y + v[i].z + v[i].w;
  }
#pragma unroll
  for (int off = 32; off >= 1; off >>= 1) s += __shfl_down(s, off);
  __shared__ float reds[4];
  if ((t & 63) == 0) reds[t >> 6] = s;
  __syncthreads();
  s = reds[0] + reds[1] + reds[2] + reds[3];
  float inv = 1.f / s;
  unsigned short* prow = P + (size_t)blockIdx.x * pld;
#pragma unroll
  for (int i = 0; i < 4; ++i) {
    ushort4 o = make_ushort4(f2h(v[i].x * inv), f2h(v[i].y * inv),
                             f2h(v[i].z * inv), f2h(v[i].w * inv));
    ((ushort4*)prow)[t + 256 * i] = o;
  }
}

extern "C" void kernel_launch(void* const* d_in, const int* in_sizes, int n_in,
                              void* d_out, int out_size, void* d_ws, size_t ws_size,
                              hipStream_t stream) {
  const float* hs = (const float*)d_in[0];
  const float* Wq = (const float*)d_in[1];
  const float* bq = (const float*)d_in[2];
  const float* Wk = (const float*)d_in[3];
  const float* bk = (const float*)d_in[4];
  const float* Wv = (const float*)d_in[5];
  const float* bv = (const float*)d_in[6];
  float* out = (float*)d_out;

  constexpr int Ss = 4096, Hh = 1024;
  constexpr int Mm = 8192;
  constexpr size_t TOK = (size_t)Ss * Hh;
  char* ws = (char*)d_ws;
  const size_t MB = 1024 * 1024;

  unsigned short* qh = (unsigned short*)(ws + 0 * MB);
  unsigned short* kh = (unsigned short*)(ws + 16 * MB);
  unsigned short* vT = (unsigned short*)(ws + 32 * MB);  // [1024][8192]
  char* rb = ws + 48 * MB;
  unsigned short* hs_h = (unsigned short*)(rb + 0 * MB);
  unsigned short* hs_l = (unsigned short*)(rb + 16 * MB);
  unsigned short* WT = (unsigned short*)(rb + 32 * MB);   // [3072][1024]
  unsigned short* vS = (unsigned short*)(rb + 38 * MB);   // [8192][1024] staging
  float* Sf = (float*)rb;

  const bool big = ws_size >= (size_t)176 * MB;

  // 1) splits; W -> [3072][1024] f16 (q | k | v)
  split_pair_f16_kernel<<<dim3(Mm * Hh / 2048), 256, 0, stream>>>(hs, hs_h, hs_l);
  transpose_f16_kernel<<<dim3(32, 32), 256, 0, stream>>>(Wq, WT, Hh, Hh);
  transpose_f16_kernel<<<dim3(32, 32), 256, 0, stream>>>(
      Wk, WT + (size_t)1024 * 1024, Hh, Hh);
  transpose_f16_kernel<<<dim3(32, 32), 256, 0, stream>>>(
      Wv, WT + (size_t)2048 * 1024, Hh, Hh);

  // 2) fused QKV projection (256x128 2-term, dbuf, coalesced epilogue)
  qkv_kernel<<<dim3(24, 32), 512, 0, stream>>>(
      hs_h, hs_l, WT, bq, bk, bv, qh, kh, vS);

  // 2b) transpose V staging [8192][1024] -> vT [1024][8192]
  transpose_v_kernel<<<dim3(32, 256), 256, 0, stream>>>(vS, vT);

  if (big) {
    // 3) QK^T both batches (256x256 1-term) -> S fp32 slabs
    g1q_kernel<<<dim3(16, 16, 2), 512, 0, stream>>>(
        qh, TOK, Hh, kh, TOK, Hh, Sf, (size_t)Ss * Ss, Ss, Hh);
    // 4) softmax 8192 rows, fp32 -> f16 in-place strided (pld 8192)
    softmax_rows_kernel<<<dim3(2 * Ss), 256, 0, stream>>>(
        Sf, (unsigned short*)Sf, Ss, 2 * Ss);
    // 5) PV both batches (256x128 1-term, grid 256)
    g1_kernel<<<dim3(8, 16, 2), 512, 0, stream>>>(
        (const unsigned short*)Sf, (size_t)Ss * 2 * Ss, 2 * Ss,
        vT, (size_t)Ss, Mm, out, TOK, Hh, Ss);
  } else {
    float* Sb = (float*)rb;
    unsigned short* Pb = (unsigned short*)(rb + 64 * MB);
    for (int b = 0; b < 2; ++b) {
      g1q_kernel<<<dim3(16, 16, 1), 512, 0, stream>>>(
          qh + b * TOK, 0, Hh, kh + b * TOK, 0, Hh, Sb, 0, Ss, Hh);
      softmax_rows_kernel<<<dim3(Ss), 256, 0, stream>>>(Sb, Pb, Ss, Ss);
      g1_kernel<<<dim3(8, 16, 1), 512, 0, stream>>>(
          Pb, 0, Ss, vT + (size_t)b * Ss, 0, Mm, out + b * TOK, 0, Hh, Ss);
    }
  }
}

// Round 15
// 383.123 us; speedup vs baseline: 1.1317x; 1.0236x over previous
//
#include <hip/hip_runtime.h>
#include <stdint.h>

typedef __attribute__((ext_vector_type(8))) short short8;
typedef __attribute__((ext_vector_type(8))) _Float16 half8;
typedef __attribute__((ext_vector_type(4))) float f32x4;

__device__ __forceinline__ unsigned short f2h(float x) {
  _Float16 h = (_Float16)x;
  return __builtin_bit_cast(unsigned short, h);
}
__device__ __forceinline__ float h2f(unsigned short u) {
  return (float)__builtin_bit_cast(_Float16, u);
}

#define GLOAD16(gsrc, ldst)                                              \
  __builtin_amdgcn_global_load_lds(                                      \
      (const __attribute__((address_space(1))) void*)(gsrc),             \
      (__attribute__((address_space(3))) void*)(ldst), 16, 0, 0)

#define VM(N) asm volatile("s_waitcnt vmcnt(" #N ")" ::: "memory")
#define BARSYNC __builtin_amdgcn_s_barrier()
#define LGKM0                                                \
  do {                                                       \
    asm volatile("s_waitcnt lgkmcnt(0)" ::: "memory");       \
    __builtin_amdgcn_sched_barrier(0);                       \
  } while (0)

// ---------- split fp32 -> (hi, lo) f16, 8 elems/thread ----------
__global__ __launch_bounds__(256) void split_pair_f16_kernel(
    const float* __restrict__ in, unsigned short* __restrict__ h,
    unsigned short* __restrict__ l) {
  size_t i = (size_t)blockIdx.x * 256 + threadIdx.x;
  float4 a = ((const float4*)in)[2 * i];
  float4 b = ((const float4*)in)[2 * i + 1];
  ushort4 h0 = make_ushort4(f2h(a.x), f2h(a.y), f2h(a.z), f2h(a.w));
  ushort4 h1 = make_ushort4(f2h(b.x), f2h(b.y), f2h(b.z), f2h(b.w));
  ((ushort4*)h)[2 * i] = h0;
  ((ushort4*)h)[2 * i + 1] = h1;
  ((ushort4*)l)[2 * i] = make_ushort4(
      f2h(a.x - h2f(h0.x)), f2h(a.y - h2f(h0.y)),
      f2h(a.z - h2f(h0.z)), f2h(a.w - h2f(h0.w)));
  ((ushort4*)l)[2 * i + 1] = make_ushort4(
      f2h(b.x - h2f(h1.x)), f2h(b.y - h2f(h1.y)),
      f2h(b.z - h2f(h1.z)), f2h(b.w - h2f(h1.w)));
}

// ---------- transpose W [K][N] fp32 -> f16 [N][K] ----------
__global__ __launch_bounds__(256) void transpose_f16_kernel(
    const float* __restrict__ W, unsigned short* __restrict__ hT,
    int Kd, int Nd) {
  __shared__ float tile[32][33];
  int r = threadIdx.x >> 3;
  int c = (threadIdx.x & 7) * 4;
  int k0 = blockIdx.y * 32, n0 = blockIdx.x * 32;
  float4 v = *(const float4*)&W[(size_t)(k0 + r) * Nd + n0 + c];
  tile[r][c] = v.x; tile[r][c + 1] = v.y; tile[r][c + 2] = v.z; tile[r][c + 3] = v.w;
  __syncthreads();
  size_t o = (size_t)(n0 + r) * Kd + k0 + c;
  *(ushort4*)&hT[o] = make_ushort4(f2h(tile[c + 0][r]), f2h(tile[c + 1][r]),
                                   f2h(tile[c + 2][r]), f2h(tile[c + 3][r]));
}

// ---------- transpose V [8192][1024] f16 -> vT [1024][8192] f16 ----------
__global__ __launch_bounds__(256) void transpose_v_kernel(
    const unsigned short* __restrict__ Vs, unsigned short* __restrict__ vT) {
  __shared__ unsigned short tile[32][36];
  int r = threadIdx.x >> 3;
  int c = (threadIdx.x & 7) * 4;
  int col0 = blockIdx.x * 32;
  int row0 = blockIdx.y * 32;
  ushort4 v = *(const ushort4*)&Vs[(size_t)(row0 + r) * 1024 + col0 + c];
  tile[r][c] = v.x; tile[r][c + 1] = v.y; tile[r][c + 2] = v.z; tile[r][c + 3] = v.w;
  __syncthreads();
  ushort4 o = make_ushort4(tile[c + 0][r], tile[c + 1][r],
                           tile[c + 2][r], tile[c + 3][r]);
  *(ushort4*)&vT[(size_t)(col0 + r) * 8192 + row0 + c] = o;
}

// =====================================================================
// qkv_kernel: fused QKV projection, 2-term f16 NT GEMM, 256x128 tile,
// BK=32, double-buffer 80KB (2 blocks/CU), coalesced epilogue.
// (R12-proven, unchanged.)
// =====================================================================
__global__ __launch_bounds__(512, 4) void qkv_kernel(
    const unsigned short* __restrict__ Ah, const unsigned short* __restrict__ Al,
    const unsigned short* __restrict__ WT, const float* __restrict__ bq,
    const float* __restrict__ bk, const float* __restrict__ bv,
    unsigned short* __restrict__ qh, unsigned short* __restrict__ kh,
    unsigned short* __restrict__ vS) {
  __shared__ __align__(16) char smem[2 * 40 * 1024];
  constexpr int lda = 1024, ldb = 1024, K = 1024;
  const int t = threadIdx.x, wid = t >> 6, lane = t & 63;
  const int waveM = wid >> 2, waveN = wid & 3;
  const int lr0 = lane & 15, lk0 = (lane >> 4) * 8;
  const int m0 = blockIdx.y * 256, n0 = blockIdx.x * 128;

  const unsigned short* slot_src[5];
#pragma unroll
  for (int s = 0; s < 5; ++s) {
    int si = 5 * wid + s;
    const unsigned short* p;
    if (si < 16)      p = Ah + (size_t)(m0 + si * 16 + lr0) * lda + lk0;
    else if (si < 32) p = Al + (size_t)(m0 + (si - 16) * 16 + lr0) * lda + lk0;
    else              p = WT + (size_t)(n0 + (si - 32) * 16 + lr0) * ldb + lk0;
    slot_src[s] = p;
  }

  const int NTILES = K >> 5;
  f32x4 acc[8][2] = {};

#pragma unroll
  for (int s = 0; s < 5; ++s)
    GLOAD16(slot_src[s], smem + (5 * wid + s) * 1024);
  VM(0);
  BARSYNC;
  __builtin_amdgcn_sched_barrier(0);

  for (int tile = 0; tile < NTILES; ++tile) {
    const char* cb = smem + (tile & 1) * 40960;
    char* nb = smem + ((tile + 1) & 1) * 40960;
    if (tile + 1 < NTILES) {
#pragma unroll
      for (int s = 0; s < 5; ++s)
        GLOAD16(slot_src[s] + (size_t)(tile + 1) * 32,
                nb + (5 * wid + s) * 1024);
    }
    half8 bf[2];
#pragma unroll
    for (int p = 0; p < 4; ++p) {
      half8 ahf[2], alf[2];
#pragma unroll
      for (int i = 0; i < 2; ++i) {
        int mg = waveM * 8 + 2 * p + i;
        ahf[i] = *(const half8*)(cb + mg * 1024 + lane * 16);
        alf[i] = *(const half8*)(cb + (16 + mg) * 1024 + lane * 16);
      }
      if (p == 0) {
#pragma unroll
        for (int j = 0; j < 2; ++j) {
          int ng = waveN * 2 + j;
          bf[j] = *(const half8*)(cb + (32 + ng) * 1024 + lane * 16);
        }
      }
      __builtin_amdgcn_s_setprio(1);
#pragma unroll
      for (int i = 0; i < 2; ++i)
#pragma unroll
        for (int j = 0; j < 2; ++j) {
          f32x4 c = acc[2 * p + i][j];
          c = __builtin_amdgcn_mfma_f32_16x16x32_f16(ahf[i], bf[j], c, 0, 0, 0);
          c = __builtin_amdgcn_mfma_f32_16x16x32_f16(alf[i], bf[j], c, 0, 0, 0);
          acc[2 * p + i][j] = c;
        }
      __builtin_amdgcn_s_setprio(0);
    }
    if (tile + 1 < NTILES) {
      LGKM0;
      VM(0);
      BARSYNC;
      __builtin_amdgcn_sched_barrier(0);
    }
  }

  const int or0 = (lane >> 4) * 4;
  const int slab = n0 >> 10;
#pragma unroll
  for (int mm = 0; mm < 8; ++mm)
#pragma unroll
    for (int j = 0; j < 2; ++j)
#pragma unroll
      for (int r = 0; r < 4; ++r) {
        int row = m0 + waveM * 128 + mm * 16 + or0 + r;
        int col = (n0 & 1023) + waveN * 32 + j * 16 + lr0;
        float x = acc[mm][j][r];
        if (slab == 0) {
          qh[(size_t)row * 1024 + col] = f2h(x + bq[col]);
        } else if (slab == 1) {
          kh[(size_t)row * 1024 + col] = f2h(x + bk[col]);
        } else {
          vS[(size_t)row * 1024 + col] = f2h(x + bv[col]);
        }
      }
}

// =====================================================================
// g8q: 8-phase 256x256 BK=64 1-term f16 NT GEMM (QK^T), m201 ledger.
// Quad order (0,0),(1,0),(1,1),(0,1); B regs persist; A0 re-read ph3.
// Half-tiles grouped by QUADRANT USAGE (R13 bug fix):
//   HA0 = rowgroups {0-3,8-11} (qr=0), HA1 = {4-7,12-15} (qr=1)
//   HB0 = colgroups {0,1,4,5,8,9,12,13} (qc=0), HB1 = +2 (qc=1)
// Each wave stages 1 rowgroup/half (2 gloads). Stage map: ph0->HA0(t+1)
// buf^1, ph1->HB0(t+2) buf, ph2->HA1(t+2) buf, ph3->HB1(t+2) buf,
// ph4->HA0(t+2) buf, ph5..7 -> HB0/HA1/HB1(t+3) buf^1.
// vmcnt(6) ONLY at ph3/ph7 (3 half-tiles in flight). WAR: every staged
// region's last reader is the immediately-preceding phase (drained by
// its LGKM0 before the inter-phase barrier). LDS dest is wave-uniform
// base (HW adds lane*16). Prologue 7 halves + VM(6); tail: VM(0) at ph3.
// =====================================================================
#define ST8(h, T, bufb)                                                   \
  do {                                                                    \
    const unsigned short* _s = ssrc[h] + (size_t)(T) * 64;                \
    char* _d = smem + (bufb) * 65536 + sdst[h];                           \
    GLOAD16(_s, _d);                                                      \
    GLOAD16(_s + 32, _d + 1024);                                          \
  } while (0)

#define RDA(bufb, qr)                                                     \
  _Pragma("unroll") for (int _i = 0; _i < 4; ++_i)                        \
  _Pragma("unroll") for (int _kk = 0; _kk < 2; ++_kk)                     \
      areg[_i][_kk] = *(const half8*)(smem + (bufb) * 65536 +             \
          ((waveM * 8 + (qr) * 4 + _i) * 2 + _kk) * 1024 + lane * 16);

#define RDB(bufb, qc)                                                     \
  _Pragma("unroll") for (int _j = 0; _j < 2; ++_j)                        \
  _Pragma("unroll") for (int _kk = 0; _kk < 2; ++_kk)                     \
      breg[_j][_kk] = *(const half8*)(smem + (bufb) * 65536 + 32768 +     \
          ((waveN * 4 + (qc) * 2 + _j) * 2 + _kk) * 1024 + lane * 16);

#define MM16(qr, qc)                                                      \
  __builtin_amdgcn_s_setprio(1);                                          \
  _Pragma("unroll") for (int _i = 0; _i < 4; ++_i)                        \
  _Pragma("unroll") for (int _j = 0; _j < 2; ++_j)                        \
  _Pragma("unroll") for (int _kk = 0; _kk < 2; ++_kk)                     \
      acc[(qr) * 4 + _i][(qc) * 2 + _j] =                                 \
          __builtin_amdgcn_mfma_f32_16x16x32_f16(                         \
              areg[_i][_kk], breg[_j][_kk],                               \
              acc[(qr) * 4 + _i][(qc) * 2 + _j], 0, 0, 0);                \
  __builtin_amdgcn_s_setprio(0);

__global__ __launch_bounds__(512, 2) void g8q_kernel(
    const unsigned short* __restrict__ Abase, size_t Astr, int lda,
    const unsigned short* __restrict__ Bbase, size_t Bstr, int ldb,
    float* __restrict__ outF, size_t Ostr, int ldo, int K) {
  __shared__ __align__(16) char smem[131072];
  const int t = threadIdx.x, wid = t >> 6, lane = t & 63;
  const int waveM = wid >> 2, waveN = wid & 3;
  const int lr0 = lane & 15, lk0 = (lane >> 4) * 8;
  const int m0 = blockIdx.y * 256, n0 = blockIdx.x * 256;
  const unsigned short* A = Abase + (size_t)blockIdx.z * Astr;
  const unsigned short* B = Bbase + (size_t)blockIdx.z * Bstr;
  float* out = outF + (size_t)blockIdx.z * Ostr;

  // usage-aligned staging rowgroups (one per wave per half)
  const int rgA0 = (wid & 3) + ((wid >> 2) << 3);   // {0-3,8-11}
  const int rgA1 = rgA0 + 4;                        // {4-7,12-15}
  const int cgB0 = (wid & 1) + ((wid >> 1) << 2);   // {0,1,4,5,8,9,12,13}
  const int cgB1 = cgB0 + 2;                        // {2,3,6,7,10,11,14,15}
  const unsigned short* ssrc[4];
  int sdst[4];
  ssrc[0] = A + (size_t)(m0 + rgA0 * 16 + lr0) * lda + lk0;
  ssrc[1] = A + (size_t)(m0 + rgA1 * 16 + lr0) * lda + lk0;
  ssrc[2] = B + (size_t)(n0 + cgB0 * 16 + lr0) * ldb + lk0;
  ssrc[3] = B + (size_t)(n0 + cgB1 * 16 + lr0) * ldb + lk0;
  sdst[0] = (rgA0 * 2) * 1024;
  sdst[1] = (rgA1 * 2) * 1024;
  sdst[2] = 32768 + (cgB0 * 2) * 1024;
  sdst[3] = 32768 + (cgB1 * 2) * 1024;

  const int NT = K >> 6, NT2 = NT >> 1;
  f32x4 acc[8][4] = {};
  half8 areg[4][2], breg[2][2];

  // prologue: tile0 {HA0,HB0,HA1,HB1} + tile1 {HB0,HA1,HB1}; land tile0.
  ST8(0, 0, 0); ST8(2, 0, 0); ST8(1, 0, 0); ST8(3, 0, 0);
  ST8(2, 1, 1); ST8(1, 1, 1); ST8(3, 1, 1);
  VM(6);
  BARSYNC;
  __builtin_amdgcn_sched_barrier(0);

#pragma unroll 1
  for (int it = 0; it < NT2; ++it) {
    const int tt = 2 * it;
    const bool s2 = (tt + 2) < NT;
    const bool s3 = (tt + 3) < NT;
    // ph0: buf0 quad(0,0); stage HA0(tt+1)->buf1
    RDA(0, 0) RDB(0, 0)
    ST8(0, tt + 1, 1);
    BARSYNC; LGKM0; MM16(0, 0) BARSYNC;
    // ph1: quad(1,0) [B0 in regs]; stage HB0(tt+2)->buf0
    RDA(0, 1)
    if (s2) ST8(2, tt + 2, 0);
    BARSYNC; LGKM0; MM16(1, 0) BARSYNC;
    // ph2: quad(1,1) [A1 in regs]; stage HA1(tt+2)->buf0
    RDB(0, 1)
    if (s2) ST8(1, tt + 2, 0);
    BARSYNC; LGKM0; MM16(1, 1) BARSYNC;
    // ph3: quad(0,1), re-read HA0; stage HB1(tt+2)->buf0; vmcnt
    RDA(0, 0)
    if (s2) ST8(3, tt + 2, 0);
    BARSYNC; LGKM0; MM16(0, 1)
    if (s2) { VM(6); } else { VM(0); }
    BARSYNC;
    // ph4: buf1 quad(0,0); stage HA0(tt+2)->buf0
    RDA(1, 0) RDB(1, 0)
    if (s2) ST8(0, tt + 2, 0);
    BARSYNC; LGKM0; MM16(0, 0) BARSYNC;
    // ph5: quad(1,0); stage HB0(tt+3)->buf1
    RDA(1, 1)
    if (s3) ST8(2, tt + 3, 1);
    BARSYNC; LGKM0; MM16(1, 0) BARSYNC;
    // ph6: quad(1,1); stage HA1(tt+3)->buf1
    RDB(1, 1)
    if (s3) ST8(1, tt + 3, 1);
    BARSYNC; LGKM0; MM16(1, 1) BARSYNC;
    // ph7: quad(0,1), re-read HA0; stage HB1(tt+3)->buf1; vmcnt
    RDA(1, 0)
    if (s3) ST8(3, tt + 3, 1);
    BARSYNC; LGKM0; MM16(0, 1)
    if (s3) { VM(6); }
    BARSYNC;
  }

  const int or0 = (lane >> 4) * 4;
#pragma unroll
  for (int mm = 0; mm < 8; ++mm)
#pragma unroll
    for (int cg = 0; cg < 4; ++cg)
#pragma unroll
      for (int r = 0; r < 4; ++r)
        out[(size_t)(m0 + waveM * 128 + mm * 16 + or0 + r) * ldo +
            (n0 + waveN * 64 + cg * 16 + lr0)] = acc[mm][cg][r];
}

// =====================================================================
// g1: 1-term f16 NT GEMM (PV), 256x128, BK=64, tri-144KB, 6 slots/wave,
// VM(6). fp32 out. (R6/R10-proven, unchanged.)
// =====================================================================
__global__ __launch_bounds__(512, 2) void g1_kernel(
    const unsigned short* __restrict__ Abase, size_t Astr, int lda,
    const unsigned short* __restrict__ Bbase, size_t Bstr, int ldb,
    float* __restrict__ outF, size_t Ostr, int ldo, int K) {
  __shared__ __align__(16) char smem[3 * 48 * 1024];
  const int t = threadIdx.x, wid = t >> 6, lane = t & 63;
  const int waveM = wid >> 2, waveN = wid & 3;
  const int lr0 = lane & 15, lk0 = (lane >> 4) * 8;
  const int m0 = blockIdx.y * 256, n0 = blockIdx.x * 128;
  const unsigned short* A = Abase + (size_t)blockIdx.z * Astr;
  const unsigned short* B = Bbase + (size_t)blockIdx.z * Bstr;
  float* out = outF + (size_t)blockIdx.z * Ostr;

  const unsigned short* slot_src[6];
#pragma unroll
  for (int s = 0; s < 6; ++s) {
    int si = 6 * wid + s;
    const unsigned short* p;
    if (si < 16)      p = A + (size_t)(m0 + si * 16 + lr0) * lda + lk0;
    else if (si < 32) p = A + (size_t)(m0 + (si - 16) * 16 + lr0) * lda + 32 + lk0;
    else if (si < 40) p = B + (size_t)(n0 + (si - 32) * 16 + lr0) * ldb + lk0;
    else              p = B + (size_t)(n0 + (si - 40) * 16 + lr0) * ldb + 32 + lk0;
    slot_src[s] = p;
  }

  const int NTILES = K >> 6;
  f32x4 acc[8][2] = {};

#pragma unroll
  for (int tt = 0; tt < 2; ++tt)
#pragma unroll
    for (int s = 0; s < 6; ++s)
      GLOAD16(slot_src[s] + (size_t)tt * 64,
              smem + tt * 49152 + (6 * wid + s) * 1024);
  VM(6);
  BARSYNC;
  __builtin_amdgcn_sched_barrier(0);

  for (int tile = 0; tile < NTILES; ++tile) {
    const int cur = tile % 3, nxt = (tile + 2) % 3;
    const bool do_stage = (tile + 2) < NTILES;
    const char* cb = smem + cur * 49152;
    char* nb = smem + nxt * 49152;
    half8 blo[2], bhi[2];
#pragma unroll
    for (int p = 0; p < 4; ++p) {
      half8 alo[2], ahi[2];
#pragma unroll
      for (int i = 0; i < 2; ++i) {
        int mg = waveM * 8 + 2 * p + i;
        alo[i] = *(const half8*)(cb + mg * 1024 + lane * 16);
        ahi[i] = *(const half8*)(cb + (16 + mg) * 1024 + lane * 16);
      }
      if (p == 0) {
#pragma unroll
        for (int j = 0; j < 2; ++j) {
          int ng = waveN * 2 + j;
          blo[j] = *(const half8*)(cb + (32 + ng) * 1024 + lane * 16);
          bhi[j] = *(const half8*)(cb + (40 + ng) * 1024 + lane * 16);
        }
      }
      if (do_stage && p < 3) {
#pragma unroll
        for (int s = 0; s < 2; ++s) {
          int slot = 2 * p + s;
          GLOAD16(slot_src[slot] + (size_t)(tile + 2) * 64,
                  nb + (6 * wid + slot) * 1024);
        }
      }
      __builtin_amdgcn_s_setprio(1);
#pragma unroll
      for (int i = 0; i < 2; ++i)
#pragma unroll
        for (int j = 0; j < 2; ++j) {
          f32x4 c = acc[2 * p + i][j];
          c = __builtin_amdgcn_mfma_f32_16x16x32_f16(alo[i], blo[j], c, 0, 0, 0);
          c = __builtin_amdgcn_mfma_f32_16x16x32_f16(ahi[i], bhi[j], c, 0, 0, 0);
          acc[2 * p + i][j] = c;
        }
      __builtin_amdgcn_s_setprio(0);
    }
    if (tile + 1 < NTILES) {
      LGKM0;
      if (do_stage) VM(6); else VM(0);
      BARSYNC;
      __builtin_amdgcn_sched_barrier(0);
    }
  }

  const int or0 = (lane >> 4) * 4;
#pragma unroll
  for (int mm = 0; mm < 8; ++mm)
#pragma unroll
    for (int j = 0; j < 2; ++j)
#pragma unroll
      for (int r = 0; r < 4; ++r)
        out[(size_t)(m0 + waveM * 128 + mm * 16 + or0 + r) * ldo +
            (n0 + waveN * 32 + j * 16 + lr0)] = acc[mm][j][r];
}

// ---------- row softmax: fp32 [4096] -> f16 probs (in-place, pld stride) ----
__global__ __launch_bounds__(256) void softmax_rows_kernel(
    const float* Sm, unsigned short* P, int ncol, int pld) {
  const int t = threadIdx.x;
  const float* srow = Sm + (size_t)blockIdx.x * ncol;
  float4 v[4];
  float m = -3.4e38f;
#pragma unroll
  for (int i = 0; i < 4; ++i) {
    v[i] = ((const float4*)srow)[t + 256 * i];
    m = fmaxf(m, fmaxf(fmaxf(v[i].x, v[i].y), fmaxf(v[i].z, v[i].w)));
  }
#pragma unroll
  for (int off = 32; off >= 1; off >>= 1) m = fmaxf(m, __shfl_down(m, off));
  __shared__ float redm[4];
  if ((t & 63) == 0) redm[t >> 6] = m;
  __syncthreads();
  m = fmaxf(fmaxf(redm[0], redm[1]), fmaxf(redm[2], redm[3]));
  float s = 0.f;
#pragma unroll
  for (int i = 0; i < 4; ++i) {
    v[i].x = __expf(v[i].x - m);
    v[i].y = __expf(v[i].y - m);
    v[i].z = __expf(v[i].z - m);
    v[i].w = __expf(v[i].w - m);
    s += v[i].x + v[i].y + v[i].z + v[i].w;
  }
#pragma unroll
  for (int off = 32; off >= 1; off >>= 1) s += __shfl_down(s, off);
  __shared__ float reds[4];
  if ((t & 63) == 0) reds[t >> 6] = s;
  __syncthreads();
  s = reds[0] + reds[1] + reds[2] + reds[3];
  float inv = 1.f / s;
  unsigned short* prow = P + (size_t)blockIdx.x * pld;
#pragma unroll
  for (int i = 0; i < 4; ++i) {
    ushort4 o = make_ushort4(f2h(v[i].x * inv), f2h(v[i].y * inv),
                             f2h(v[i].z * inv), f2h(v[i].w * inv));
    ((ushort4*)prow)[t + 256 * i] = o;
  }
}

extern "C" void kernel_launch(void* const* d_in, const int* in_sizes, int n_in,
                              void* d_out, int out_size, void* d_ws, size_t ws_size,
                              hipStream_t stream) {
  const float* hs = (const float*)d_in[0];
  const float* Wq = (const float*)d_in[1];
  const float* bq = (const float*)d_in[2];
  const float* Wk = (const float*)d_in[3];
  const float* bk = (const float*)d_in[4];
  const float* Wv = (const float*)d_in[5];
  const float* bv = (const float*)d_in[6];
  float* out = (float*)d_out;

  constexpr int Ss = 4096, Hh = 1024;
  constexpr int Mm = 8192;
  constexpr size_t TOK = (size_t)Ss * Hh;
  char* ws = (char*)d_ws;
  const size_t MB = 1024 * 1024;

  unsigned short* qh = (unsigned short*)(ws + 0 * MB);
  unsigned short* kh = (unsigned short*)(ws + 16 * MB);
  unsigned short* vT = (unsigned short*)(ws + 32 * MB);  // [1024][8192]
  char* rb = ws + 48 * MB;
  unsigned short* hs_h = (unsigned short*)(rb + 0 * MB);
  unsigned short* hs_l = (unsigned short*)(rb + 16 * MB);
  unsigned short* WT = (unsigned short*)(rb + 32 * MB);   // [3072][1024]
  unsigned short* vS = (unsigned short*)(rb + 38 * MB);   // [8192][1024] staging
  float* Sf = (float*)rb;

  const bool big = ws_size >= (size_t)176 * MB;

  // 1) splits; W -> [3072][1024] f16 (q | k | v)
  split_pair_f16_kernel<<<dim3(Mm * Hh / 2048), 256, 0, stream>>>(hs, hs_h, hs_l);
  transpose_f16_kernel<<<dim3(32, 32), 256, 0, stream>>>(Wq, WT, Hh, Hh);
  transpose_f16_kernel<<<dim3(32, 32), 256, 0, stream>>>(
      Wk, WT + (size_t)1024 * 1024, Hh, Hh);
  transpose_f16_kernel<<<dim3(32, 32), 256, 0, stream>>>(
      Wv, WT + (size_t)2048 * 1024, Hh, Hh);

  // 2) fused QKV projection (256x128 2-term, dbuf, coalesced epilogue)
  qkv_kernel<<<dim3(24, 32), 512, 0, stream>>>(
      hs_h, hs_l, WT, bq, bk, bv, qh, kh, vS);

  // 2b) transpose V staging [8192][1024] -> vT [1024][8192]
  transpose_v_kernel<<<dim3(32, 256), 256, 0, stream>>>(vS, vT);

  if (big) {
    // 3) QK^T both batches (8-phase 256x256 BK=64) -> S fp32 slabs
    g8q_kernel<<<dim3(16, 16, 2), 512, 0, stream>>>(
        qh, TOK, Hh, kh, TOK, Hh, Sf, (size_t)Ss * Ss, Ss, Hh);
    // 4) softmax 8192 rows, fp32 -> f16 in-place strided (pld 8192)
    softmax_rows_kernel<<<dim3(2 * Ss), 256, 0, stream>>>(
        Sf, (unsigned short*)Sf, Ss, 2 * Ss);
    // 5) PV both batches (256x128 1-term, grid 256)
    g1_kernel<<<dim3(8, 16, 2), 512, 0, stream>>>(
        (const unsigned short*)Sf, (size_t)Ss * 2 * Ss, 2 * Ss,
        vT, (size_t)Ss, Mm, out, TOK, Hh, Ss);
  } else {
    float* Sb = (float*)rb;
    unsigned short* Pb = (unsigned short*)(rb + 64 * MB);
    for (int b = 0; b < 2; ++b) {
      g8q_kernel<<<dim3(16, 16, 1), 512, 0, stream>>>(
          qh + b * TOK, 0, Hh, kh + b * TOK, 0, Hh, Sb, 0, Ss, Hh);
      softmax_rows_kernel<<<dim3(Ss), 256, 0, stream>>>(Sb, Pb, Ss, Ss);
      g1_kernel<<<dim3(8, 16, 1), 512, 0, stream>>>(
          Pb, 0, Ss, vT + (size_t)b * Ss, 0, Mm, out + b * TOK, 0, Hh, Ss);
    }
  }
}

// Round 16
// 370.739 us; speedup vs baseline: 1.1695x; 1.0334x over previous
//
#include <hip/hip_runtime.h>
#include <stdint.h>

typedef __attribute__((ext_vector_type(8))) short short8;
typedef __attribute__((ext_vector_type(8))) _Float16 half8;
typedef __attribute__((ext_vector_type(4))) float f32x4;

__device__ __forceinline__ unsigned short f2h(float x) {
  _Float16 h = (_Float16)x;
  return __builtin_bit_cast(unsigned short, h);
}
__device__ __forceinline__ float h2f(unsigned short u) {
  return (float)__builtin_bit_cast(_Float16, u);
}

#define GLOAD16(gsrc, ldst)                                              \
  __builtin_amdgcn_global_load_lds(                                      \
      (const __attribute__((address_space(1))) void*)(gsrc),             \
      (__attribute__((address_space(3))) void*)(ldst), 16, 0, 0)

#define VM(N) asm volatile("s_waitcnt vmcnt(" #N ")" ::: "memory")
#define BARSYNC __builtin_amdgcn_s_barrier()
#define LGKM0                                                \
  do {                                                       \
    asm volatile("s_waitcnt lgkmcnt(0)" ::: "memory");       \
    __builtin_amdgcn_sched_barrier(0);                       \
  } while (0)

// ---------- split fp32 -> (hi, lo) f16, 8 elems/thread ----------
__global__ __launch_bounds__(256) void split_pair_f16_kernel(
    const float* __restrict__ in, unsigned short* __restrict__ h,
    unsigned short* __restrict__ l) {
  size_t i = (size_t)blockIdx.x * 256 + threadIdx.x;
  float4 a = ((const float4*)in)[2 * i];
  float4 b = ((const float4*)in)[2 * i + 1];
  ushort4 h0 = make_ushort4(f2h(a.x), f2h(a.y), f2h(a.z), f2h(a.w));
  ushort4 h1 = make_ushort4(f2h(b.x), f2h(b.y), f2h(b.z), f2h(b.w));
  ((ushort4*)h)[2 * i] = h0;
  ((ushort4*)h)[2 * i + 1] = h1;
  ((ushort4*)l)[2 * i] = make_ushort4(
      f2h(a.x - h2f(h0.x)), f2h(a.y - h2f(h0.y)),
      f2h(a.z - h2f(h0.z)), f2h(a.w - h2f(h0.w)));
  ((ushort4*)l)[2 * i + 1] = make_ushort4(
      f2h(b.x - h2f(h1.x)), f2h(b.y - h2f(h1.y)),
      f2h(b.z - h2f(h1.z)), f2h(b.w - h2f(h1.w)));
}

// ---------- transpose W [K][N] fp32 -> f16 [N][K] ----------
__global__ __launch_bounds__(256) void transpose_f16_kernel(
    const float* __restrict__ W, unsigned short* __restrict__ hT,
    int Kd, int Nd) {
  __shared__ float tile[32][33];
  int r = threadIdx.x >> 3;
  int c = (threadIdx.x & 7) * 4;
  int k0 = blockIdx.y * 32, n0 = blockIdx.x * 32;
  float4 v = *(const float4*)&W[(size_t)(k0 + r) * Nd + n0 + c];
  tile[r][c] = v.x; tile[r][c + 1] = v.y; tile[r][c + 2] = v.z; tile[r][c + 3] = v.w;
  __syncthreads();
  size_t o = (size_t)(n0 + r) * Kd + k0 + c;
  *(ushort4*)&hT[o] = make_ushort4(f2h(tile[c + 0][r]), f2h(tile[c + 1][r]),
                                   f2h(tile[c + 2][r]), f2h(tile[c + 3][r]));
}

// ---------- transpose V [8192][1024] f16 -> vT [1024][8192] f16 ----------
__global__ __launch_bounds__(256) void transpose_v_kernel(
    const unsigned short* __restrict__ Vs, unsigned short* __restrict__ vT) {
  __shared__ unsigned short tile[32][36];
  int r = threadIdx.x >> 3;
  int c = (threadIdx.x & 7) * 4;
  int col0 = blockIdx.x * 32;
  int row0 = blockIdx.y * 32;
  ushort4 v = *(const ushort4*)&Vs[(size_t)(row0 + r) * 1024 + col0 + c];
  tile[r][c] = v.x; tile[r][c + 1] = v.y; tile[r][c + 2] = v.z; tile[r][c + 3] = v.w;
  __syncthreads();
  ushort4 o = make_ushort4(tile[c + 0][r], tile[c + 1][r],
                           tile[c + 2][r], tile[c + 3][r]);
  *(ushort4*)&vT[(size_t)(col0 + r) * 8192 + row0 + c] = o;
}

// =====================================================================
// qkv_kernel: fused QKV projection, 2-term f16 NT GEMM, 128x384 tile,
// BK=32, double-buffer 80KB, grid (8,64)=512 (2 balanced rounds).
// Staged bytes = 8 colblocks x 32MB (A) + 64 Mblocks x 6MB (B) = 640MB
// (vs 983MB at 256x128) -- staging-rate-bound, so ~1.5x faster.
// 40 subtiles/K-step: Ah rg0-7 (si 0-7), Al rg0-7 (si 8-15), B cg0-23
// (si 16-39); 5 slots/wave, same R12-proven loop. acc[4][6]; per phase:
// 1 a-frag pair + 12 MFMA; B frags (6) loaded at p==0.
// Epilogue: per-element slab = globalcol>>10 (tile spans q/k/v bounds).
// =====================================================================
__global__ __launch_bounds__(512, 2) void qkv_kernel(
    const unsigned short* __restrict__ Ah, const unsigned short* __restrict__ Al,
    const unsigned short* __restrict__ WT, const float* __restrict__ bq,
    const float* __restrict__ bk, const float* __restrict__ bv,
    unsigned short* __restrict__ qh, unsigned short* __restrict__ kh,
    unsigned short* __restrict__ vS) {
  __shared__ __align__(16) char smem[2 * 40 * 1024];
  constexpr int lda = 1024, ldb = 1024, K = 1024;
  const int t = threadIdx.x, wid = t >> 6, lane = t & 63;
  const int waveM = wid >> 2, waveN = wid & 3;
  const int lr0 = lane & 15, lk0 = (lane >> 4) * 8;
  const int m0 = blockIdx.y * 128, n0 = blockIdx.x * 384;

  const unsigned short* slot_src[5];
#pragma unroll
  for (int s = 0; s < 5; ++s) {
    int si = 5 * wid + s;
    const unsigned short* p;
    if (si < 8)       p = Ah + (size_t)(m0 + si * 16 + lr0) * lda + lk0;
    else if (si < 16) p = Al + (size_t)(m0 + (si - 8) * 16 + lr0) * lda + lk0;
    else              p = WT + (size_t)(n0 + (si - 16) * 16 + lr0) * ldb + lk0;
    slot_src[s] = p;
  }

  const int NTILES = K >> 5;  // 32
  f32x4 acc[4][6] = {};

#pragma unroll
  for (int s = 0; s < 5; ++s)
    GLOAD16(slot_src[s], smem + (5 * wid + s) * 1024);
  VM(0);
  BARSYNC;
  __builtin_amdgcn_sched_barrier(0);

  for (int tile = 0; tile < NTILES; ++tile) {
    const char* cb = smem + (tile & 1) * 40960;
    char* nb = smem + ((tile + 1) & 1) * 40960;
    if (tile + 1 < NTILES) {
#pragma unroll
      for (int s = 0; s < 5; ++s)
        GLOAD16(slot_src[s] + (size_t)(tile + 1) * 32,
                nb + (5 * wid + s) * 1024);
    }
    half8 bf[6];
#pragma unroll
    for (int p = 0; p < 4; ++p) {
      const int mg = waveM * 4 + p;
      half8 ahf = *(const half8*)(cb + mg * 1024 + lane * 16);
      half8 alf = *(const half8*)(cb + (8 + mg) * 1024 + lane * 16);
      if (p == 0) {
#pragma unroll
        for (int j = 0; j < 6; ++j) {
          int ng = waveN * 6 + j;
          bf[j] = *(const half8*)(cb + (16 + ng) * 1024 + lane * 16);
        }
      }
      __builtin_amdgcn_s_setprio(1);
#pragma unroll
      for (int j = 0; j < 6; ++j) {
        f32x4 c = acc[p][j];
        c = __builtin_amdgcn_mfma_f32_16x16x32_f16(ahf, bf[j], c, 0, 0, 0);
        c = __builtin_amdgcn_mfma_f32_16x16x32_f16(alf, bf[j], c, 0, 0, 0);
        acc[p][j] = c;
      }
      __builtin_amdgcn_s_setprio(0);
    }
    if (tile + 1 < NTILES) {
      LGKM0;
      VM(0);
      BARSYNC;
      __builtin_amdgcn_sched_barrier(0);
    }
  }

  const int or0 = (lane >> 4) * 4;
#pragma unroll
  for (int mm = 0; mm < 4; ++mm)
#pragma unroll
    for (int j = 0; j < 6; ++j)
#pragma unroll
      for (int r = 0; r < 4; ++r) {
        int row = m0 + waveM * 64 + mm * 16 + or0 + r;
        int gc = n0 + waveN * 96 + j * 16 + lr0;
        int slab = gc >> 10;
        int col = gc & 1023;
        float x = acc[mm][j][r];
        if (slab == 0) {
          qh[(size_t)row * 1024 + col] = f2h(x + bq[col]);
        } else if (slab == 1) {
          kh[(size_t)row * 1024 + col] = f2h(x + bk[col]);
        } else {
          vS[(size_t)row * 1024 + col] = f2h(x + bv[col]);
        }
      }
}

// =====================================================================
// g8q: 8-phase 256x256 BK=64 1-term f16 NT GEMM (QK^T), m201 ledger.
// (R14-proven, unchanged.)
// =====================================================================
#define ST8(h, T, bufb)                                                   \
  do {                                                                    \
    const unsigned short* _s = ssrc[h] + (size_t)(T) * 64;                \
    char* _d = smem + (bufb) * 65536 + sdst[h];                           \
    GLOAD16(_s, _d);                                                      \
    GLOAD16(_s + 32, _d + 1024);                                          \
  } while (0)

#define RDA(bufb, qr)                                                     \
  _Pragma("unroll") for (int _i = 0; _i < 4; ++_i)                        \
  _Pragma("unroll") for (int _kk = 0; _kk < 2; ++_kk)                     \
      areg[_i][_kk] = *(const half8*)(smem + (bufb) * 65536 +             \
          ((waveM * 8 + (qr) * 4 + _i) * 2 + _kk) * 1024 + lane * 16);

#define RDB(bufb, qc)                                                     \
  _Pragma("unroll") for (int _j = 0; _j < 2; ++_j)                        \
  _Pragma("unroll") for (int _kk = 0; _kk < 2; ++_kk)                     \
      breg[_j][_kk] = *(const half8*)(smem + (bufb) * 65536 + 32768 +     \
          ((waveN * 4 + (qc) * 2 + _j) * 2 + _kk) * 1024 + lane * 16);

#define MM16(qr, qc)                                                      \
  __builtin_amdgcn_s_setprio(1);                                          \
  _Pragma("unroll") for (int _i = 0; _i < 4; ++_i)                        \
  _Pragma("unroll") for (int _j = 0; _j < 2; ++_j)                        \
  _Pragma("unroll") for (int _kk = 0; _kk < 2; ++_kk)                     \
      acc[(qr) * 4 + _i][(qc) * 2 + _j] =                                 \
          __builtin_amdgcn_mfma_f32_16x16x32_f16(                         \
              areg[_i][_kk], breg[_j][_kk],                               \
              acc[(qr) * 4 + _i][(qc) * 2 + _j], 0, 0, 0);                \
  __builtin_amdgcn_s_setprio(0);

__global__ __launch_bounds__(512, 2) void g8q_kernel(
    const unsigned short* __restrict__ Abase, size_t Astr, int lda,
    const unsigned short* __restrict__ Bbase, size_t Bstr, int ldb,
    float* __restrict__ outF, size_t Ostr, int ldo, int K) {
  __shared__ __align__(16) char smem[131072];
  const int t = threadIdx.x, wid = t >> 6, lane = t & 63;
  const int waveM = wid >> 2, waveN = wid & 3;
  const int lr0 = lane & 15, lk0 = (lane >> 4) * 8;
  const int m0 = blockIdx.y * 256, n0 = blockIdx.x * 256;
  const unsigned short* A = Abase + (size_t)blockIdx.z * Astr;
  const unsigned short* B = Bbase + (size_t)blockIdx.z * Bstr;
  float* out = outF + (size_t)blockIdx.z * Ostr;

  const int rgA0 = (wid & 3) + ((wid >> 2) << 3);   // {0-3,8-11}
  const int rgA1 = rgA0 + 4;                        // {4-7,12-15}
  const int cgB0 = (wid & 1) + ((wid >> 1) << 2);   // {0,1,4,5,8,9,12,13}
  const int cgB1 = cgB0 + 2;                        // {2,3,6,7,10,11,14,15}
  const unsigned short* ssrc[4];
  int sdst[4];
  ssrc[0] = A + (size_t)(m0 + rgA0 * 16 + lr0) * lda + lk0;
  ssrc[1] = A + (size_t)(m0 + rgA1 * 16 + lr0) * lda + lk0;
  ssrc[2] = B + (size_t)(n0 + cgB0 * 16 + lr0) * ldb + lk0;
  ssrc[3] = B + (size_t)(n0 + cgB1 * 16 + lr0) * ldb + lk0;
  sdst[0] = (rgA0 * 2) * 1024;
  sdst[1] = (rgA1 * 2) * 1024;
  sdst[2] = 32768 + (cgB0 * 2) * 1024;
  sdst[3] = 32768 + (cgB1 * 2) * 1024;

  const int NT = K >> 6, NT2 = NT >> 1;
  f32x4 acc[8][4] = {};
  half8 areg[4][2], breg[2][2];

  ST8(0, 0, 0); ST8(2, 0, 0); ST8(1, 0, 0); ST8(3, 0, 0);
  ST8(2, 1, 1); ST8(1, 1, 1); ST8(3, 1, 1);
  VM(6);
  BARSYNC;
  __builtin_amdgcn_sched_barrier(0);

#pragma unroll 1
  for (int it = 0; it < NT2; ++it) {
    const int tt = 2 * it;
    const bool s2 = (tt + 2) < NT;
    const bool s3 = (tt + 3) < NT;
    RDA(0, 0) RDB(0, 0)
    ST8(0, tt + 1, 1);
    BARSYNC; LGKM0; MM16(0, 0) BARSYNC;
    RDA(0, 1)
    if (s2) ST8(2, tt + 2, 0);
    BARSYNC; LGKM0; MM16(1, 0) BARSYNC;
    RDB(0, 1)
    if (s2) ST8(1, tt + 2, 0);
    BARSYNC; LGKM0; MM16(1, 1) BARSYNC;
    RDA(0, 0)
    if (s2) ST8(3, tt + 2, 0);
    BARSYNC; LGKM0; MM16(0, 1)
    if (s2) { VM(6); } else { VM(0); }
    BARSYNC;
    RDA(1, 0) RDB(1, 0)
    if (s2) ST8(0, tt + 2, 0);
    BARSYNC; LGKM0; MM16(0, 0) BARSYNC;
    RDA(1, 1)
    if (s3) ST8(2, tt + 3, 1);
    BARSYNC; LGKM0; MM16(1, 0) BARSYNC;
    RDB(1, 1)
    if (s3) ST8(1, tt + 3, 1);
    BARSYNC; LGKM0; MM16(1, 1) BARSYNC;
    RDA(1, 0)
    if (s3) ST8(3, tt + 3, 1);
    BARSYNC; LGKM0; MM16(0, 1)
    if (s3) { VM(6); }
    BARSYNC;
  }

  const int or0 = (lane >> 4) * 4;
#pragma unroll
  for (int mm = 0; mm < 8; ++mm)
#pragma unroll
    for (int cg = 0; cg < 4; ++cg)
#pragma unroll
      for (int r = 0; r < 4; ++r)
        out[(size_t)(m0 + waveM * 128 + mm * 16 + or0 + r) * ldo +
            (n0 + waveN * 64 + cg * 16 + lr0)] = acc[mm][cg][r];
}

// =====================================================================
// g1: 1-term f16 NT GEMM (PV), 256x128, BK=64, tri-144KB, 6 slots/wave,
// VM(6). fp32 out. (R6/R10-proven, unchanged.)
// =====================================================================
__global__ __launch_bounds__(512, 2) void g1_kernel(
    const unsigned short* __restrict__ Abase, size_t Astr, int lda,
    const unsigned short* __restrict__ Bbase, size_t Bstr, int ldb,
    float* __restrict__ outF, size_t Ostr, int ldo, int K) {
  __shared__ __align__(16) char smem[3 * 48 * 1024];
  const int t = threadIdx.x, wid = t >> 6, lane = t & 63;
  const int waveM = wid >> 2, waveN = wid & 3;
  const int lr0 = lane & 15, lk0 = (lane >> 4) * 8;
  const int m0 = blockIdx.y * 256, n0 = blockIdx.x * 128;
  const unsigned short* A = Abase + (size_t)blockIdx.z * Astr;
  const unsigned short* B = Bbase + (size_t)blockIdx.z * Bstr;
  float* out = outF + (size_t)blockIdx.z * Ostr;

  const unsigned short* slot_src[6];
#pragma unroll
  for (int s = 0; s < 6; ++s) {
    int si = 6 * wid + s;
    const unsigned short* p;
    if (si < 16)      p = A + (size_t)(m0 + si * 16 + lr0) * lda + lk0;
    else if (si < 32) p = A + (size_t)(m0 + (si - 16) * 16 + lr0) * lda + 32 + lk0;
    else if (si < 40) p = B + (size_t)(n0 + (si - 32) * 16 + lr0) * ldb + lk0;
    else              p = B + (size_t)(n0 + (si - 40) * 16 + lr0) * ldb + 32 + lk0;
    slot_src[s] = p;
  }

  const int NTILES = K >> 6;
  f32x4 acc[8][2] = {};

#pragma unroll
  for (int tt = 0; tt < 2; ++tt)
#pragma unroll
    for (int s = 0; s < 6; ++s)
      GLOAD16(slot_src[s] + (size_t)tt * 64,
              smem + tt * 49152 + (6 * wid + s) * 1024);
  VM(6);
  BARSYNC;
  __builtin_amdgcn_sched_barrier(0);

  for (int tile = 0; tile < NTILES; ++tile) {
    const int cur = tile % 3, nxt = (tile + 2) % 3;
    const bool do_stage = (tile + 2) < NTILES;
    const char* cb = smem + cur * 49152;
    char* nb = smem + nxt * 49152;
    half8 blo[2], bhi[2];
#pragma unroll
    for (int p = 0; p < 4; ++p) {
      half8 alo[2], ahi[2];
#pragma unroll
      for (int i = 0; i < 2; ++i) {
        int mg = waveM * 8 + 2 * p + i;
        alo[i] = *(const half8*)(cb + mg * 1024 + lane * 16);
        ahi[i] = *(const half8*)(cb + (16 + mg) * 1024 + lane * 16);
      }
      if (p == 0) {
#pragma unroll
        for (int j = 0; j < 2; ++j) {
          int ng = waveN * 2 + j;
          blo[j] = *(const half8*)(cb + (32 + ng) * 1024 + lane * 16);
          bhi[j] = *(const half8*)(cb + (40 + ng) * 1024 + lane * 16);
        }
      }
      if (do_stage && p < 3) {
#pragma unroll
        for (int s = 0; s < 2; ++s) {
          int slot = 2 * p + s;
          GLOAD16(slot_src[slot] + (size_t)(tile + 2) * 64,
                  nb + (6 * wid + slot) * 1024);
        }
      }
      __builtin_amdgcn_s_setprio(1);
#pragma unroll
      for (int i = 0; i < 2; ++i)
#pragma unroll
        for (int j = 0; j < 2; ++j) {
          f32x4 c = acc[2 * p + i][j];
          c = __builtin_amdgcn_mfma_f32_16x16x32_f16(alo[i], blo[j], c, 0, 0, 0);
          c = __builtin_amdgcn_mfma_f32_16x16x32_f16(ahi[i], bhi[j], c, 0, 0, 0);
          acc[2 * p + i][j] = c;
        }
      __builtin_amdgcn_s_setprio(0);
    }
    if (tile + 1 < NTILES) {
      LGKM0;
      if (do_stage) VM(6); else VM(0);
      BARSYNC;
      __builtin_amdgcn_sched_barrier(0);
    }
  }

  const int or0 = (lane >> 4) * 4;
#pragma unroll
  for (int mm = 0; mm < 8; ++mm)
#pragma unroll
    for (int j = 0; j < 2; ++j)
#pragma unroll
      for (int r = 0; r < 4; ++r)
        out[(size_t)(m0 + waveM * 128 + mm * 16 + or0 + r) * ldo +
            (n0 + waveN * 32 + j * 16 + lr0)] = acc[mm][j][r];
}

// ---------- row softmax: fp32 [4096] -> f16 probs (in-place, pld stride) ----
__global__ __launch_bounds__(256) void softmax_rows_kernel(
    const float* Sm, unsigned short* P, int ncol, int pld) {
  const int t = threadIdx.x;
  const float* srow = Sm + (size_t)blockIdx.x * ncol;
  float4 v[4];
  float m = -3.4e38f;
#pragma unroll
  for (int i = 0; i < 4; ++i) {
    v[i] = ((const float4*)srow)[t + 256 * i];
    m = fmaxf(m, fmaxf(fmaxf(v[i].x, v[i].y), fmaxf(v[i].z, v[i].w)));
  }
#pragma unroll
  for (int off = 32; off >= 1; off >>= 1) m = fmaxf(m, __shfl_down(m, off));
  __shared__ float redm[4];
  if ((t & 63) == 0) redm[t >> 6] = m;
  __syncthreads();
  m = fmaxf(fmaxf(redm[0], redm[1]), fmaxf(redm[2], redm[3]));
  float s = 0.f;
#pragma unroll
  for (int i = 0; i < 4; ++i) {
    v[i].x = __expf(v[i].x - m);
    v[i].y = __expf(v[i].y - m);
    v[i].z = __expf(v[i].z - m);
    v[i].w = __expf(v[i].w - m);
    s += v[i].x + v[i].y + v[i].z + v[i].w;
  }
#pragma unroll
  for (int off = 32; off >= 1; off >>= 1) s += __shfl_down(s, off);
  __shared__ float reds[4];
  if ((t & 63) == 0) reds[t >> 6] = s;
  __syncthreads();
  s = reds[0] + reds[1] + reds[2] + reds[3];
  float inv = 1.f / s;
  unsigned short* prow = P + (size_t)blockIdx.x * pld;
#pragma unroll
  for (int i = 0; i < 4; ++i) {
    ushort4 o = make_ushort4(f2h(v[i].x * inv), f2h(v[i].y * inv),
                             f2h(v[i].z * inv), f2h(v[i].w * inv));
    ((ushort4*)prow)[t + 256 * i] = o;
  }
}

extern "C" void kernel_launch(void* const* d_in, const int* in_sizes, int n_in,
                              void* d_out, int out_size, void* d_ws, size_t ws_size,
                              hipStream_t stream) {
  const float* hs = (const float*)d_in[0];
  const float* Wq = (const float*)d_in[1];
  const float* bq = (const float*)d_in[2];
  const float* Wk = (const float*)d_in[3];
  const float* bk = (const float*)d_in[4];
  const float* Wv = (const float*)d_in[5];
  const float* bv = (const float*)d_in[6];
  float* out = (float*)d_out;

  constexpr int Ss = 4096, Hh = 1024;
  constexpr int Mm = 8192;
  constexpr size_t TOK = (size_t)Ss * Hh;
  char* ws = (char*)d_ws;
  const size_t MB = 1024 * 1024;

  unsigned short* qh = (unsigned short*)(ws + 0 * MB);
  unsigned short* kh = (unsigned short*)(ws + 16 * MB);
  unsigned short* vT = (unsigned short*)(ws + 32 * MB);  // [1024][8192]
  char* rb = ws + 48 * MB;
  unsigned short* hs_h = (unsigned short*)(rb + 0 * MB);
  unsigned short* hs_l = (unsigned short*)(rb + 16 * MB);
  unsigned short* WT = (unsigned short*)(rb + 32 * MB);   // [3072][1024]
  unsigned short* vS = (unsigned short*)(rb + 38 * MB);   // [8192][1024] staging
  float* Sf = (float*)rb;

  const bool big = ws_size >= (size_t)176 * MB;

  // 1) splits; W -> [3072][1024] f16 (q | k | v)
  split_pair_f16_kernel<<<dim3(Mm * Hh / 2048), 256, 0, stream>>>(hs, hs_h, hs_l);
  transpose_f16_kernel<<<dim3(32, 32), 256, 0, stream>>>(Wq, WT, Hh, Hh);
  transpose_f16_kernel<<<dim3(32, 32), 256, 0, stream>>>(
      Wk, WT + (size_t)1024 * 1024, Hh, Hh);
  transpose_f16_kernel<<<dim3(32, 32), 256, 0, stream>>>(
      Wv, WT + (size_t)2048 * 1024, Hh, Hh);

  // 2) fused QKV projection (128x384 2-term, dbuf, grid 512 = 2 rounds)
  qkv_kernel<<<dim3(8, 64), 512, 0, stream>>>(
      hs_h, hs_l, WT, bq, bk, bv, qh, kh, vS);

  // 2b) transpose V staging [8192][1024] -> vT [1024][8192]
  transpose_v_kernel<<<dim3(32, 256), 256, 0, stream>>>(vS, vT);

  if (big) {
    // 3) QK^T both batches (8-phase 256x256 BK=64) -> S fp32 slabs
    g8q_kernel<<<dim3(16, 16, 2), 512, 0, stream>>>(
        qh, TOK, Hh, kh, TOK, Hh, Sf, (size_t)Ss * Ss, Ss, Hh);
    // 4) softmax 8192 rows, fp32 -> f16 in-place strided (pld 8192)
    softmax_rows_kernel<<<dim3(2 * Ss), 256, 0, stream>>>(
        Sf, (unsigned short*)Sf, Ss, 2 * Ss);
    // 5) PV both batches (256x128 1-term, grid 256)
    g1_kernel<<<dim3(8, 16, 2), 512, 0, stream>>>(
        (const unsigned short*)Sf, (size_t)Ss * 2 * Ss, 2 * Ss,
        vT, (size_t)Ss, Mm, out, TOK, Hh, Ss);
  } else {
    float* Sb = (float*)rb;
    unsigned short* Pb = (unsigned short*)(rb + 64 * MB);
    for (int b = 0; b < 2; ++b) {
      g8q_kernel<<<dim3(16, 16, 1), 512, 0, stream>>>(
          qh + b * TOK, 0, Hh, kh + b * TOK, 0, Hh, Sb, 0, Ss, Hh);
      softmax_rows_kernel<<<dim3(Ss), 256, 0, stream>>>(Sb, Pb, Ss, Ss);
      g1_kernel<<<dim3(8, 16, 1), 512, 0, stream>>>(
          Pb, 0, Ss, vT + (size_t)b * Ss, 0, Mm, out + b * TOK, 0, Hh, Ss);
    }
  }
}

// Round 17
// 369.968 us; speedup vs baseline: 1.1719x; 1.0021x over previous
//
#include <hip/hip_runtime.h>
#include <stdint.h>

typedef __attribute__((ext_vector_type(8))) short short8;
typedef __attribute__((ext_vector_type(8))) _Float16 half8;
typedef __attribute__((ext_vector_type(4))) float f32x4;

__device__ __forceinline__ unsigned short f2h(float x) {
  _Float16 h = (_Float16)x;
  return __builtin_bit_cast(unsigned short, h);
}
__device__ __forceinline__ float h2f(unsigned short u) {
  return (float)__builtin_bit_cast(_Float16, u);
}

#define GLOAD16(gsrc, ldst)                                              \
  __builtin_amdgcn_global_load_lds(                                      \
      (const __attribute__((address_space(1))) void*)(gsrc),             \
      (__attribute__((address_space(3))) void*)(ldst), 16, 0, 0)

#define VM(N) asm volatile("s_waitcnt vmcnt(" #N ")" ::: "memory")
#define BARSYNC __builtin_amdgcn_s_barrier()
#define LGKM0                                                \
  do {                                                       \
    asm volatile("s_waitcnt lgkmcnt(0)" ::: "memory");       \
    __builtin_amdgcn_sched_barrier(0);                       \
  } while (0)

// ---------- split fp32 -> (hi, lo) f16, 8 elems/thread ----------
__global__ __launch_bounds__(256) void split_pair_f16_kernel(
    const float* __restrict__ in, unsigned short* __restrict__ h,
    unsigned short* __restrict__ l) {
  size_t i = (size_t)blockIdx.x * 256 + threadIdx.x;
  float4 a = ((const float4*)in)[2 * i];
  float4 b = ((const float4*)in)[2 * i + 1];
  ushort4 h0 = make_ushort4(f2h(a.x), f2h(a.y), f2h(a.z), f2h(a.w));
  ushort4 h1 = make_ushort4(f2h(b.x), f2h(b.y), f2h(b.z), f2h(b.w));
  ((ushort4*)h)[2 * i] = h0;
  ((ushort4*)h)[2 * i + 1] = h1;
  ((ushort4*)l)[2 * i] = make_ushort4(
      f2h(a.x - h2f(h0.x)), f2h(a.y - h2f(h0.y)),
      f2h(a.z - h2f(h0.z)), f2h(a.w - h2f(h0.w)));
  ((ushort4*)l)[2 * i + 1] = make_ushort4(
      f2h(b.x - h2f(h1.x)), f2h(b.y - h2f(h1.y)),
      f2h(b.z - h2f(h1.z)), f2h(b.w - h2f(h1.w)));
}

// ---------- transpose W [K][N] fp32 -> f16 [N][K] ----------
__global__ __launch_bounds__(256) void transpose_f16_kernel(
    const float* __restrict__ W, unsigned short* __restrict__ hT,
    int Kd, int Nd) {
  __shared__ float tile[32][33];
  int r = threadIdx.x >> 3;
  int c = (threadIdx.x & 7) * 4;
  int k0 = blockIdx.y * 32, n0 = blockIdx.x * 32;
  float4 v = *(const float4*)&W[(size_t)(k0 + r) * Nd + n0 + c];
  tile[r][c] = v.x; tile[r][c + 1] = v.y; tile[r][c + 2] = v.z; tile[r][c + 3] = v.w;
  __syncthreads();
  size_t o = (size_t)(n0 + r) * Kd + k0 + c;
  *(ushort4*)&hT[o] = make_ushort4(f2h(tile[c + 0][r]), f2h(tile[c + 1][r]),
                                   f2h(tile[c + 2][r]), f2h(tile[c + 3][r]));
}

// ---------- transpose V [8192][1024] f16 -> vT [1024][8192] f16 ----------
__global__ __launch_bounds__(256) void transpose_v_kernel(
    const unsigned short* __restrict__ Vs, unsigned short* __restrict__ vT) {
  __shared__ unsigned short tile[32][36];
  int r = threadIdx.x >> 3;
  int c = (threadIdx.x & 7) * 4;
  int col0 = blockIdx.x * 32;
  int row0 = blockIdx.y * 32;
  ushort4 v = *(const ushort4*)&Vs[(size_t)(row0 + r) * 1024 + col0 + c];
  tile[r][c] = v.x; tile[r][c + 1] = v.y; tile[r][c + 2] = v.z; tile[r][c + 3] = v.w;
  __syncthreads();
  ushort4 o = make_ushort4(tile[c + 0][r], tile[c + 1][r],
                           tile[c + 2][r], tile[c + 3][r]);
  *(ushort4*)&vT[(size_t)(col0 + r) * 8192 + row0 + c] = o;
}

// =====================================================================
// qkv_kernel: fused QKV projection, 2-term f16 NT GEMM, 128x384 tile,
// BK=32, TRI-buffer 120KB, counted VM(5), stage distributed across
// phases ({0,1}@p0, {2}@p1, {3}@p2, {4}@p3 -> buf (t+2)%3) -- the
// R5/R6-proven qk2 schedule (27-29 GB/s/CU staging) on R15's geometry
// (640MB staged). Grid (8,64)=512 = 2 balanced rounds.
// 40 subtiles/K-step: Ah rg0-7, Al rg0-7, B cg0-23; 5 slots/wave.
// acc[4][6]; per phase 1 a-pair + 12 MFMA; 6 B frags at p==0.
// Epilogue: per-element slab = globalcol>>10 (R15-proven, coalesced).
// =====================================================================
__global__ __launch_bounds__(512, 2) void qkv_kernel(
    const unsigned short* __restrict__ Ah, const unsigned short* __restrict__ Al,
    const unsigned short* __restrict__ WT, const float* __restrict__ bq,
    const float* __restrict__ bk, const float* __restrict__ bv,
    unsigned short* __restrict__ qh, unsigned short* __restrict__ kh,
    unsigned short* __restrict__ vS) {
  __shared__ __align__(16) char smem[3 * 40 * 1024];
  constexpr int lda = 1024, ldb = 1024, K = 1024;
  const int t = threadIdx.x, wid = t >> 6, lane = t & 63;
  const int waveM = wid >> 2, waveN = wid & 3;
  const int lr0 = lane & 15, lk0 = (lane >> 4) * 8;
  const int m0 = blockIdx.y * 128, n0 = blockIdx.x * 384;

  const unsigned short* slot_src[5];
#pragma unroll
  for (int s = 0; s < 5; ++s) {
    int si = 5 * wid + s;
    const unsigned short* p;
    if (si < 8)       p = Ah + (size_t)(m0 + si * 16 + lr0) * lda + lk0;
    else if (si < 16) p = Al + (size_t)(m0 + (si - 8) * 16 + lr0) * lda + lk0;
    else              p = WT + (size_t)(n0 + (si - 16) * 16 + lr0) * ldb + lk0;
    slot_src[s] = p;
  }

  const int NTILES = K >> 5;  // 32
  f32x4 acc[4][6] = {};

#pragma unroll
  for (int tt = 0; tt < 2; ++tt)
#pragma unroll
    for (int s = 0; s < 5; ++s)
      GLOAD16(slot_src[s] + (size_t)tt * 32,
              smem + tt * 40960 + (5 * wid + s) * 1024);
  VM(5);
  BARSYNC;
  __builtin_amdgcn_sched_barrier(0);

  for (int tile = 0; tile < NTILES; ++tile) {
    const int cur = tile % 3, nxt = (tile + 2) % 3;
    const bool do_stage = (tile + 2) < NTILES;
    const char* cb = smem + cur * 40960;
    char* nb = smem + nxt * 40960;
    half8 bf[6];
#pragma unroll
    for (int p = 0; p < 4; ++p) {
      const int mg = waveM * 4 + p;
      half8 ahf = *(const half8*)(cb + mg * 1024 + lane * 16);
      half8 alf = *(const half8*)(cb + (8 + mg) * 1024 + lane * 16);
      if (p == 0) {
#pragma unroll
        for (int j = 0; j < 6; ++j) {
          int ng = waveN * 6 + j;
          bf[j] = *(const half8*)(cb + (16 + ng) * 1024 + lane * 16);
        }
      }
      if (do_stage) {
        if (p == 0) {
          GLOAD16(slot_src[0] + (size_t)(tile + 2) * 32, nb + (5 * wid + 0) * 1024);
          GLOAD16(slot_src[1] + (size_t)(tile + 2) * 32, nb + (5 * wid + 1) * 1024);
        } else {
          const int slot = p + 1;  // p=1->2, p=2->3, p=3->4
          GLOAD16(slot_src[slot] + (size_t)(tile + 2) * 32,
                  nb + (5 * wid + slot) * 1024);
        }
      }
      __builtin_amdgcn_s_setprio(1);
#pragma unroll
      for (int j = 0; j < 6; ++j) {
        f32x4 c = acc[p][j];
        c = __builtin_amdgcn_mfma_f32_16x16x32_f16(ahf, bf[j], c, 0, 0, 0);
        c = __builtin_amdgcn_mfma_f32_16x16x32_f16(alf, bf[j], c, 0, 0, 0);
        acc[p][j] = c;
      }
      __builtin_amdgcn_s_setprio(0);
      if (p < 3) __builtin_amdgcn_s_barrier();
    }
    if (tile + 1 < NTILES) {
      if (do_stage) VM(5); else VM(0);
      BARSYNC;
      __builtin_amdgcn_sched_barrier(0);
    }
  }

  const int or0 = (lane >> 4) * 4;
#pragma unroll
  for (int mm = 0; mm < 4; ++mm)
#pragma unroll
    for (int j = 0; j < 6; ++j)
#pragma unroll
      for (int r = 0; r < 4; ++r) {
        int row = m0 + waveM * 64 + mm * 16 + or0 + r;
        int gc = n0 + waveN * 96 + j * 16 + lr0;
        int slab = gc >> 10;
        int col = gc & 1023;
        float x = acc[mm][j][r];
        if (slab == 0) {
          qh[(size_t)row * 1024 + col] = f2h(x + bq[col]);
        } else if (slab == 1) {
          kh[(size_t)row * 1024 + col] = f2h(x + bk[col]);
        } else {
          vS[(size_t)row * 1024 + col] = f2h(x + bv[col]);
        }
      }
}

// =====================================================================
// g8q: 8-phase 256x256 BK=64 1-term f16 NT GEMM (QK^T), m201 ledger.
// (R14-proven, unchanged.)
// =====================================================================
#define ST8(h, T, bufb)                                                   \
  do {                                                                    \
    const unsigned short* _s = ssrc[h] + (size_t)(T) * 64;                \
    char* _d = smem + (bufb) * 65536 + sdst[h];                           \
    GLOAD16(_s, _d);                                                      \
    GLOAD16(_s + 32, _d + 1024);                                          \
  } while (0)

#define RDA(bufb, qr)                                                     \
  _Pragma("unroll") for (int _i = 0; _i < 4; ++_i)                        \
  _Pragma("unroll") for (int _kk = 0; _kk < 2; ++_kk)                     \
      areg[_i][_kk] = *(const half8*)(smem + (bufb) * 65536 +             \
          ((waveM * 8 + (qr) * 4 + _i) * 2 + _kk) * 1024 + lane * 16);

#define RDB(bufb, qc)                                                     \
  _Pragma("unroll") for (int _j = 0; _j < 2; ++_j)                        \
  _Pragma("unroll") for (int _kk = 0; _kk < 2; ++_kk)                     \
      breg[_j][_kk] = *(const half8*)(smem + (bufb) * 65536 + 32768 +     \
          ((waveN * 4 + (qc) * 2 + _j) * 2 + _kk) * 1024 + lane * 16);

#define MM16(qr, qc)                                                      \
  __builtin_amdgcn_s_setprio(1);                                          \
  _Pragma("unroll") for (int _i = 0; _i < 4; ++_i)                        \
  _Pragma("unroll") for (int _j = 0; _j < 2; ++_j)                        \
  _Pragma("unroll") for (int _kk = 0; _kk < 2; ++_kk)                     \
      acc[(qr) * 4 + _i][(qc) * 2 + _j] =                                 \
          __builtin_amdgcn_mfma_f32_16x16x32_f16(                         \
              areg[_i][_kk], breg[_j][_kk],                               \
              acc[(qr) * 4 + _i][(qc) * 2 + _j], 0, 0, 0);                \
  __builtin_amdgcn_s_setprio(0);

__global__ __launch_bounds__(512, 2) void g8q_kernel(
    const unsigned short* __restrict__ Abase, size_t Astr, int lda,
    const unsigned short* __restrict__ Bbase, size_t Bstr, int ldb,
    float* __restrict__ outF, size_t Ostr, int ldo, int K) {
  __shared__ __align__(16) char smem[131072];
  const int t = threadIdx.x, wid = t >> 6, lane = t & 63;
  const int waveM = wid >> 2, waveN = wid & 3;
  const int lr0 = lane & 15, lk0 = (lane >> 4) * 8;
  const int m0 = blockIdx.y * 256, n0 = blockIdx.x * 256;
  const unsigned short* A = Abase + (size_t)blockIdx.z * Astr;
  const unsigned short* B = Bbase + (size_t)blockIdx.z * Bstr;
  float* out = outF + (size_t)blockIdx.z * Ostr;

  const int rgA0 = (wid & 3) + ((wid >> 2) << 3);   // {0-3,8-11}
  const int rgA1 = rgA0 + 4;                        // {4-7,12-15}
  const int cgB0 = (wid & 1) + ((wid >> 1) << 2);   // {0,1,4,5,8,9,12,13}
  const int cgB1 = cgB0 + 2;                        // {2,3,6,7,10,11,14,15}
  const unsigned short* ssrc[4];
  int sdst[4];
  ssrc[0] = A + (size_t)(m0 + rgA0 * 16 + lr0) * lda + lk0;
  ssrc[1] = A + (size_t)(m0 + rgA1 * 16 + lr0) * lda + lk0;
  ssrc[2] = B + (size_t)(n0 + cgB0 * 16 + lr0) * ldb + lk0;
  ssrc[3] = B + (size_t)(n0 + cgB1 * 16 + lr0) * ldb + lk0;
  sdst[0] = (rgA0 * 2) * 1024;
  sdst[1] = (rgA1 * 2) * 1024;
  sdst[2] = 32768 + (cgB0 * 2) * 1024;
  sdst[3] = 32768 + (cgB1 * 2) * 1024;

  const int NT = K >> 6, NT2 = NT >> 1;
  f32x4 acc[8][4] = {};
  half8 areg[4][2], breg[2][2];

  ST8(0, 0, 0); ST8(2, 0, 0); ST8(1, 0, 0); ST8(3, 0, 0);
  ST8(2, 1, 1); ST8(1, 1, 1); ST8(3, 1, 1);
  VM(6);
  BARSYNC;
  __builtin_amdgcn_sched_barrier(0);

#pragma unroll 1
  for (int it = 0; it < NT2; ++it) {
    const int tt = 2 * it;
    const bool s2 = (tt + 2) < NT;
    const bool s3 = (tt + 3) < NT;
    RDA(0, 0) RDB(0, 0)
    ST8(0, tt + 1, 1);
    BARSYNC; LGKM0; MM16(0, 0) BARSYNC;
    RDA(0, 1)
    if (s2) ST8(2, tt + 2, 0);
    BARSYNC; LGKM0; MM16(1, 0) BARSYNC;
    RDB(0, 1)
    if (s2) ST8(1, tt + 2, 0);
    BARSYNC; LGKM0; MM16(1, 1) BARSYNC;
    RDA(0, 0)
    if (s2) ST8(3, tt + 2, 0);
    BARSYNC; LGKM0; MM16(0, 1)
    if (s2) { VM(6); } else { VM(0); }
    BARSYNC;
    RDA(1, 0) RDB(1, 0)
    if (s2) ST8(0, tt + 2, 0);
    BARSYNC; LGKM0; MM16(0, 0) BARSYNC;
    RDA(1, 1)
    if (s3) ST8(2, tt + 3, 1);
    BARSYNC; LGKM0; MM16(1, 0) BARSYNC;
    RDB(1, 1)
    if (s3) ST8(1, tt + 3, 1);
    BARSYNC; LGKM0; MM16(1, 1) BARSYNC;
    RDA(1, 0)
    if (s3) ST8(3, tt + 3, 1);
    BARSYNC; LGKM0; MM16(0, 1)
    if (s3) { VM(6); }
    BARSYNC;
  }

  const int or0 = (lane >> 4) * 4;
#pragma unroll
  for (int mm = 0; mm < 8; ++mm)
#pragma unroll
    for (int cg = 0; cg < 4; ++cg)
#pragma unroll
      for (int r = 0; r < 4; ++r)
        out[(size_t)(m0 + waveM * 128 + mm * 16 + or0 + r) * ldo +
            (n0 + waveN * 64 + cg * 16 + lr0)] = acc[mm][cg][r];
}

// =====================================================================
// g1: 1-term f16 NT GEMM (PV), 256x128, BK=64, tri-144KB, 6 slots/wave,
// VM(6). fp32 out. (R6/R10-proven, unchanged.)
// =====================================================================
__global__ __launch_bounds__(512, 2) void g1_kernel(
    const unsigned short* __restrict__ Abase, size_t Astr, int lda,
    const unsigned short* __restrict__ Bbase, size_t Bstr, int ldb,
    float* __restrict__ outF, size_t Ostr, int ldo, int K) {
  __shared__ __align__(16) char smem[3 * 48 * 1024];
  const int t = threadIdx.x, wid = t >> 6, lane = t & 63;
  const int waveM = wid >> 2, waveN = wid & 3;
  const int lr0 = lane & 15, lk0 = (lane >> 4) * 8;
  const int m0 = blockIdx.y * 256, n0 = blockIdx.x * 128;
  const unsigned short* A = Abase + (size_t)blockIdx.z * Astr;
  const unsigned short* B = Bbase + (size_t)blockIdx.z * Bstr;
  float* out = outF + (size_t)blockIdx.z * Ostr;

  const unsigned short* slot_src[6];
#pragma unroll
  for (int s = 0; s < 6; ++s) {
    int si = 6 * wid + s;
    const unsigned short* p;
    if (si < 16)      p = A + (size_t)(m0 + si * 16 + lr0) * lda + lk0;
    else if (si < 32) p = A + (size_t)(m0 + (si - 16) * 16 + lr0) * lda + 32 + lk0;
    else if (si < 40) p = B + (size_t)(n0 + (si - 32) * 16 + lr0) * ldb + lk0;
    else              p = B + (size_t)(n0 + (si - 40) * 16 + lr0) * ldb + 32 + lk0;
    slot_src[s] = p;
  }

  const int NTILES = K >> 6;
  f32x4 acc[8][2] = {};

#pragma unroll
  for (int tt = 0; tt < 2; ++tt)
#pragma unroll
    for (int s = 0; s < 6; ++s)
      GLOAD16(slot_src[s] + (size_t)tt * 64,
              smem + tt * 49152 + (6 * wid + s) * 1024);
  VM(6);
  BARSYNC;
  __builtin_amdgcn_sched_barrier(0);

  for (int tile = 0; tile < NTILES; ++tile) {
    const int cur = tile % 3, nxt = (tile + 2) % 3;
    const bool do_stage = (tile + 2) < NTILES;
    const char* cb = smem + cur * 49152;
    char* nb = smem + nxt * 49152;
    half8 blo[2], bhi[2];
#pragma unroll
    for (int p = 0; p < 4; ++p) {
      half8 alo[2], ahi[2];
#pragma unroll
      for (int i = 0; i < 2; ++i) {
        int mg = waveM * 8 + 2 * p + i;
        alo[i] = *(const half8*)(cb + mg * 1024 + lane * 16);
        ahi[i] = *(const half8*)(cb + (16 + mg) * 1024 + lane * 16);
      }
      if (p == 0) {
#pragma unroll
        for (int j = 0; j < 2; ++j) {
          int ng = waveN * 2 + j;
          blo[j] = *(const half8*)(cb + (32 + ng) * 1024 + lane * 16);
          bhi[j] = *(const half8*)(cb + (40 + ng) * 1024 + lane * 16);
        }
      }
      if (do_stage && p < 3) {
#pragma unroll
        for (int s = 0; s < 2; ++s) {
          int slot = 2 * p + s;
          GLOAD16(slot_src[slot] + (size_t)(tile + 2) * 64,
                  nb + (6 * wid + slot) * 1024);
        }
      }
      __builtin_amdgcn_s_setprio(1);
#pragma unroll
      for (int i = 0; i < 2; ++i)
#pragma unroll
        for (int j = 0; j < 2; ++j) {
          f32x4 c = acc[2 * p + i][j];
          c = __builtin_amdgcn_mfma_f32_16x16x32_f16(alo[i], blo[j], c, 0, 0, 0);
          c = __builtin_amdgcn_mfma_f32_16x16x32_f16(ahi[i], bhi[j], c, 0, 0, 0);
          acc[2 * p + i][j] = c;
        }
      __builtin_amdgcn_s_setprio(0);
    }
    if (tile + 1 < NTILES) {
      LGKM0;
      if (do_stage) VM(6); else VM(0);
      BARSYNC;
      __builtin_amdgcn_sched_barrier(0);
    }
  }

  const int or0 = (lane >> 4) * 4;
#pragma unroll
  for (int mm = 0; mm < 8; ++mm)
#pragma unroll
    for (int j = 0; j < 2; ++j)
#pragma unroll
      for (int r = 0; r < 4; ++r)
        out[(size_t)(m0 + waveM * 128 + mm * 16 + or0 + r) * ldo +
            (n0 + waveN * 32 + j * 16 + lr0)] = acc[mm][j][r];
}

// ---------- row softmax: fp32 [4096] -> f16 probs (in-place, pld stride) ----
__global__ __launch_bounds__(256) void softmax_rows_kernel(
    const float* Sm, unsigned short* P, int ncol, int pld) {
  const int t = threadIdx.x;
  const float* srow = Sm + (size_t)blockIdx.x * ncol;
  float4 v[4];
  float m = -3.4e38f;
#pragma unroll
  for (int i = 0; i < 4; ++i) {
    v[i] = ((const float4*)srow)[t + 256 * i];
    m = fmaxf(m, fmaxf(fmaxf(v[i].x, v[i].y), fmaxf(v[i].z, v[i].w)));
  }
#pragma unroll
  for (int off = 32; off >= 1; off >>= 1) m = fmaxf(m, __shfl_down(m, off));
  __shared__ float redm[4];
  if ((t & 63) == 0) redm[t >> 6] = m;
  __syncthreads();
  m = fmaxf(fmaxf(redm[0], redm[1]), fmaxf(redm[2], redm[3]));
  float s = 0.f;
#pragma unroll
  for (int i = 0; i < 4; ++i) {
    v[i].x = __expf(v[i].x - m);
    v[i].y = __expf(v[i].y - m);
    v[i].z = __expf(v[i].z - m);
    v[i].w = __expf(v[i].w - m);
    s += v[i].x + v[i].y + v[i].z + v[i].w;
  }
#pragma unroll
  for (int off = 32; off >= 1; off >>= 1) s += __shfl_down(s, off);
  __shared__ float reds[4];
  if ((t & 63) == 0) reds[t >> 6] = s;
  __syncthreads();
  s = reds[0] + reds[1] + reds[2] + reds[3];
  float inv = 1.f / s;
  unsigned short* prow = P + (size_t)blockIdx.x * pld;
#pragma unroll
  for (int i = 0; i < 4; ++i) {
    ushort4 o = make_ushort4(f2h(v[i].x * inv), f2h(v[i].y * inv),
                             f2h(v[i].z * inv), f2h(v[i].w * inv));
    ((ushort4*)prow)[t + 256 * i] = o;
  }
}

extern "C" void kernel_launch(void* const* d_in, const int* in_sizes, int n_in,
                              void* d_out, int out_size, void* d_ws, size_t ws_size,
                              hipStream_t stream) {
  const float* hs = (const float*)d_in[0];
  const float* Wq = (const float*)d_in[1];
  const float* bq = (const float*)d_in[2];
  const float* Wk = (const float*)d_in[3];
  const float* bk = (const float*)d_in[4];
  const float* Wv = (const float*)d_in[5];
  const float* bv = (const float*)d_in[6];
  float* out = (float*)d_out;

  constexpr int Ss = 4096, Hh = 1024;
  constexpr int Mm = 8192;
  constexpr size_t TOK = (size_t)Ss * Hh;
  char* ws = (char*)d_ws;
  const size_t MB = 1024 * 1024;

  unsigned short* qh = (unsigned short*)(ws + 0 * MB);
  unsigned short* kh = (unsigned short*)(ws + 16 * MB);
  unsigned short* vT = (unsigned short*)(ws + 32 * MB);  // [1024][8192]
  char* rb = ws + 48 * MB;
  unsigned short* hs_h = (unsigned short*)(rb + 0 * MB);
  unsigned short* hs_l = (unsigned short*)(rb + 16 * MB);
  unsigned short* WT = (unsigned short*)(rb + 32 * MB);   // [3072][1024]
  unsigned short* vS = (unsigned short*)(rb + 38 * MB);   // [8192][1024] staging
  float* Sf = (float*)rb;

  const bool big = ws_size >= (size_t)176 * MB;

  // 1) splits; W -> [3072][1024] f16 (q | k | v)
  split_pair_f16_kernel<<<dim3(Mm * Hh / 2048), 256, 0, stream>>>(hs, hs_h, hs_l);
  transpose_f16_kernel<<<dim3(32, 32), 256, 0, stream>>>(Wq, WT, Hh, Hh);
  transpose_f16_kernel<<<dim3(32, 32), 256, 0, stream>>>(
      Wk, WT + (size_t)1024 * 1024, Hh, Hh);
  transpose_f16_kernel<<<dim3(32, 32), 256, 0, stream>>>(
      Wv, WT + (size_t)2048 * 1024, Hh, Hh);

  // 2) fused QKV projection (128x384 2-term, tri-buffer VM(5), 2 rounds)
  qkv_kernel<<<dim3(8, 64), 512, 0, stream>>>(
      hs_h, hs_l, WT, bq, bk, bv, qh, kh, vS);

  // 2b) transpose V staging [8192][1024] -> vT [1024][8192]
  transpose_v_kernel<<<dim3(32, 256), 256, 0, stream>>>(vS, vT);

  if (big) {
    // 3) QK^T both batches (8-phase 256x256 BK=64) -> S fp32 slabs
    g8q_kernel<<<dim3(16, 16, 2), 512, 0, stream>>>(
        qh, TOK, Hh, kh, TOK, Hh, Sf, (size_t)Ss * Ss, Ss, Hh);
    // 4) softmax 8192 rows, fp32 -> f16 in-place strided (pld 8192)
    softmax_rows_kernel<<<dim3(2 * Ss), 256, 0, stream>>>(
        Sf, (unsigned short*)Sf, Ss, 2 * Ss);
    // 5) PV both batches (256x128 1-term, grid 256)
    g1_kernel<<<dim3(8, 16, 2), 512, 0, stream>>>(
        (const unsigned short*)Sf, (size_t)Ss * 2 * Ss, 2 * Ss,
        vT, (size_t)Ss, Mm, out, TOK, Hh, Ss);
  } else {
    float* Sb = (float*)rb;
    unsigned short* Pb = (unsigned short*)(rb + 64 * MB);
    for (int b = 0; b < 2; ++b) {
      g8q_kernel<<<dim3(16, 16, 1), 512, 0, stream>>>(
          qh + b * TOK, 0, Hh, kh + b * TOK, 0, Hh, Sb, 0, Ss, Hh);
      softmax_rows_kernel<<<dim3(Ss), 256, 0, stream>>>(Sb, Pb, Ss, Ss);
      g1_kernel<<<dim3(8, 16, 1), 512, 0, stream>>>(
          Pb, 0, Ss, vT + (size_t)b * Ss, 0, Mm, out + b * TOK, 0, Hh, Ss);
    }
  }
}

// Round 18
// 362.424 us; speedup vs baseline: 1.1963x; 1.0208x over previous
//
#include <hip/hip_runtime.h>
#include <stdint.h>

typedef __attribute__((ext_vector_type(8))) short short8;
typedef __attribute__((ext_vector_type(8))) _Float16 half8;
typedef __attribute__((ext_vector_type(4))) float f32x4;

__device__ __forceinline__ unsigned short f2h(float x) {
  _Float16 h = (_Float16)x;
  return __builtin_bit_cast(unsigned short, h);
}
__device__ __forceinline__ float h2f(unsigned short u) {
  return (float)__builtin_bit_cast(_Float16, u);
}

#define GLOAD16(gsrc, ldst)                                              \
  __builtin_amdgcn_global_load_lds(                                      \
      (const __attribute__((address_space(1))) void*)(gsrc),             \
      (__attribute__((address_space(3))) void*)(ldst), 16, 0, 0)

#define VM(N) asm volatile("s_waitcnt vmcnt(" #N ")" ::: "memory")
#define BARSYNC __builtin_amdgcn_s_barrier()
#define LGKM0                                                \
  do {                                                       \
    asm volatile("s_waitcnt lgkmcnt(0)" ::: "memory");       \
    __builtin_amdgcn_sched_barrier(0);                       \
  } while (0)

// ---------- split fp32 -> (hi, lo) f16, 8 elems/thread ----------
__global__ __launch_bounds__(256) void split_pair_f16_kernel(
    const float* __restrict__ in, unsigned short* __restrict__ h,
    unsigned short* __restrict__ l) {
  size_t i = (size_t)blockIdx.x * 256 + threadIdx.x;
  float4 a = ((const float4*)in)[2 * i];
  float4 b = ((const float4*)in)[2 * i + 1];
  ushort4 h0 = make_ushort4(f2h(a.x), f2h(a.y), f2h(a.z), f2h(a.w));
  ushort4 h1 = make_ushort4(f2h(b.x), f2h(b.y), f2h(b.z), f2h(b.w));
  ((ushort4*)h)[2 * i] = h0;
  ((ushort4*)h)[2 * i + 1] = h1;
  ((ushort4*)l)[2 * i] = make_ushort4(
      f2h(a.x - h2f(h0.x)), f2h(a.y - h2f(h0.y)),
      f2h(a.z - h2f(h0.z)), f2h(a.w - h2f(h0.w)));
  ((ushort4*)l)[2 * i + 1] = make_ushort4(
      f2h(b.x - h2f(h1.x)), f2h(b.y - h2f(h1.y)),
      f2h(b.z - h2f(h1.z)), f2h(b.w - h2f(h1.w)));
}

// ---------- transpose W [K][N] fp32 -> f16 [N][K] ----------
__global__ __launch_bounds__(256) void transpose_f16_kernel(
    const float* __restrict__ W, unsigned short* __restrict__ hT,
    int Kd, int Nd) {
  __shared__ float tile[32][33];
  int r = threadIdx.x >> 3;
  int c = (threadIdx.x & 7) * 4;
  int k0 = blockIdx.y * 32, n0 = blockIdx.x * 32;
  float4 v = *(const float4*)&W[(size_t)(k0 + r) * Nd + n0 + c];
  tile[r][c] = v.x; tile[r][c + 1] = v.y; tile[r][c + 2] = v.z; tile[r][c + 3] = v.w;
  __syncthreads();
  size_t o = (size_t)(n0 + r) * Kd + k0 + c;
  *(ushort4*)&hT[o] = make_ushort4(f2h(tile[c + 0][r]), f2h(tile[c + 1][r]),
                                   f2h(tile[c + 2][r]), f2h(tile[c + 3][r]));
}

// ---------- transpose V [8192][1024] f16 -> vT [1024][8192] f16 ----------
__global__ __launch_bounds__(256) void transpose_v_kernel(
    const unsigned short* __restrict__ Vs, unsigned short* __restrict__ vT) {
  __shared__ unsigned short tile[32][36];
  int r = threadIdx.x >> 3;
  int c = (threadIdx.x & 7) * 4;
  int col0 = blockIdx.x * 32;
  int row0 = blockIdx.y * 32;
  ushort4 v = *(const ushort4*)&Vs[(size_t)(row0 + r) * 1024 + col0 + c];
  tile[r][c] = v.x; tile[r][c + 1] = v.y; tile[r][c + 2] = v.z; tile[r][c + 3] = v.w;
  __syncthreads();
  ushort4 o = make_ushort4(tile[c + 0][r], tile[c + 1][r],
                           tile[c + 2][r], tile[c + 3][r]);
  *(ushort4*)&vT[(size_t)(col0 + r) * 8192 + row0 + c] = o;
}

// =====================================================================
// qkv_kernel: fused QKV projection, 2-term f16 NT GEMM, 128x384 tile,
// BK=32, QUAD-buffer 160KB, 3-ahead FIFO, counted VM(10).
// Stage distributed across phases ({0,1}@p0, {2}@p1, {3}@p2, {4}@p3 ->
// buf (t+3)%4). Boundary: VM(10) if t+3 staged (2 tiles+ in flight),
// VM(5) if only t+2, VM(0) at tail. WAR distance = 3 barriers (safer
// than R16 tri). Same fragment geometry/epilogue as R15/R16 (proven).
// Grid (8,64)=512 = 2 balanced rounds; staged 640MB.
// =====================================================================
__global__ __launch_bounds__(512, 2) void qkv_kernel(
    const unsigned short* __restrict__ Ah, const unsigned short* __restrict__ Al,
    const unsigned short* __restrict__ WT, const float* __restrict__ bq,
    const float* __restrict__ bk, const float* __restrict__ bv,
    unsigned short* __restrict__ qh, unsigned short* __restrict__ kh,
    unsigned short* __restrict__ vS) {
  __shared__ __align__(16) char smem[4 * 40 * 1024];
  constexpr int lda = 1024, ldb = 1024, K = 1024;
  const int t = threadIdx.x, wid = t >> 6, lane = t & 63;
  const int waveM = wid >> 2, waveN = wid & 3;
  const int lr0 = lane & 15, lk0 = (lane >> 4) * 8;
  const int m0 = blockIdx.y * 128, n0 = blockIdx.x * 384;

  const unsigned short* slot_src[5];
#pragma unroll
  for (int s = 0; s < 5; ++s) {
    int si = 5 * wid + s;
    const unsigned short* p;
    if (si < 8)       p = Ah + (size_t)(m0 + si * 16 + lr0) * lda + lk0;
    else if (si < 16) p = Al + (size_t)(m0 + (si - 8) * 16 + lr0) * lda + lk0;
    else              p = WT + (size_t)(n0 + (si - 16) * 16 + lr0) * ldb + lk0;
    slot_src[s] = p;
  }

  const int NTILES = K >> 5;  // 32
  f32x4 acc[4][6] = {};

  // prologue: stage tiles 0,1,2 (15 loads/wave); wait t0 (drop to 10)
#pragma unroll
  for (int tt = 0; tt < 3; ++tt)
#pragma unroll
    for (int s = 0; s < 5; ++s)
      GLOAD16(slot_src[s] + (size_t)tt * 32,
              smem + tt * 40960 + (5 * wid + s) * 1024);
  VM(10);
  BARSYNC;
  __builtin_amdgcn_sched_barrier(0);

  for (int tile = 0; tile < NTILES; ++tile) {
    const int cur = tile & 3, nxt = (tile + 3) & 3;
    const bool do_stage = (tile + 3) < NTILES;
    const bool t2f = (tile + 2) < NTILES;  // t+2 still in flight at boundary
    const char* cb = smem + cur * 40960;
    char* nb = smem + nxt * 40960;
    half8 bf[6];
#pragma unroll
    for (int p = 0; p < 4; ++p) {
      const int mg = waveM * 4 + p;
      half8 ahf = *(const half8*)(cb + mg * 1024 + lane * 16);
      half8 alf = *(const half8*)(cb + (8 + mg) * 1024 + lane * 16);
      if (p == 0) {
#pragma unroll
        for (int j = 0; j < 6; ++j) {
          int ng = waveN * 6 + j;
          bf[j] = *(const half8*)(cb + (16 + ng) * 1024 + lane * 16);
        }
      }
      if (do_stage) {
        if (p == 0) {
          GLOAD16(slot_src[0] + (size_t)(tile + 3) * 32, nb + (5 * wid + 0) * 1024);
          GLOAD16(slot_src[1] + (size_t)(tile + 3) * 32, nb + (5 * wid + 1) * 1024);
        } else {
          const int slot = p + 1;  // p=1->2, p=2->3, p=3->4
          GLOAD16(slot_src[slot] + (size_t)(tile + 3) * 32,
                  nb + (5 * wid + slot) * 1024);
        }
      }
      __builtin_amdgcn_s_setprio(1);
#pragma unroll
      for (int j = 0; j < 6; ++j) {
        f32x4 c = acc[p][j];
        c = __builtin_amdgcn_mfma_f32_16x16x32_f16(ahf, bf[j], c, 0, 0, 0);
        c = __builtin_amdgcn_mfma_f32_16x16x32_f16(alf, bf[j], c, 0, 0, 0);
        acc[p][j] = c;
      }
      __builtin_amdgcn_s_setprio(0);
      if (p < 3) __builtin_amdgcn_s_barrier();
    }
    if (tile + 1 < NTILES) {
      if (do_stage) VM(10);
      else if (t2f) VM(5);
      else VM(0);
      BARSYNC;
      __builtin_amdgcn_sched_barrier(0);
    }
  }

  const int or0 = (lane >> 4) * 4;
#pragma unroll
  for (int mm = 0; mm < 4; ++mm)
#pragma unroll
    for (int j = 0; j < 6; ++j)
#pragma unroll
      for (int r = 0; r < 4; ++r) {
        int row = m0 + waveM * 64 + mm * 16 + or0 + r;
        int gc = n0 + waveN * 96 + j * 16 + lr0;
        int slab = gc >> 10;
        int col = gc & 1023;
        float x = acc[mm][j][r];
        if (slab == 0) {
          qh[(size_t)row * 1024 + col] = f2h(x + bq[col]);
        } else if (slab == 1) {
          kh[(size_t)row * 1024 + col] = f2h(x + bk[col]);
        } else {
          vS[(size_t)row * 1024 + col] = f2h(x + bv[col]);
        }
      }
}

// =====================================================================
// g8q: 8-phase 256x256 BK=64 1-term f16 NT GEMM (QK^T), m201 ledger.
// (R14-proven, unchanged.)
// =====================================================================
#define ST8(h, T, bufb)                                                   \
  do {                                                                    \
    const unsigned short* _s = ssrc[h] + (size_t)(T) * 64;                \
    char* _d = smem + (bufb) * 65536 + sdst[h];                           \
    GLOAD16(_s, _d);                                                      \
    GLOAD16(_s + 32, _d + 1024);                                          \
  } while (0)

#define RDA(bufb, qr)                                                     \
  _Pragma("unroll") for (int _i = 0; _i < 4; ++_i)                        \
  _Pragma("unroll") for (int _kk = 0; _kk < 2; ++_kk)                     \
      areg[_i][_kk] = *(const half8*)(smem + (bufb) * 65536 +             \
          ((waveM * 8 + (qr) * 4 + _i) * 2 + _kk) * 1024 + lane * 16);

#define RDB(bufb, qc)                                                     \
  _Pragma("unroll") for (int _j = 0; _j < 2; ++_j)                        \
  _Pragma("unroll") for (int _kk = 0; _kk < 2; ++_kk)                     \
      breg[_j][_kk] = *(const half8*)(smem + (bufb) * 65536 + 32768 +     \
          ((waveN * 4 + (qc) * 2 + _j) * 2 + _kk) * 1024 + lane * 16);

#define MM16(qr, qc)                                                      \
  __builtin_amdgcn_s_setprio(1);                                          \
  _Pragma("unroll") for (int _i = 0; _i < 4; ++_i)                        \
  _Pragma("unroll") for (int _j = 0; _j < 2; ++_j)                        \
  _Pragma("unroll") for (int _kk = 0; _kk < 2; ++_kk)                     \
      acc[(qr) * 4 + _i][(qc) * 2 + _j] =                                 \
          __builtin_amdgcn_mfma_f32_16x16x32_f16(                         \
              areg[_i][_kk], breg[_j][_kk],                               \
              acc[(qr) * 4 + _i][(qc) * 2 + _j], 0, 0, 0);                \
  __builtin_amdgcn_s_setprio(0);

__global__ __launch_bounds__(512, 2) void g8q_kernel(
    const unsigned short* __restrict__ Abase, size_t Astr, int lda,
    const unsigned short* __restrict__ Bbase, size_t Bstr, int ldb,
    float* __restrict__ outF, size_t Ostr, int ldo, int K) {
  __shared__ __align__(16) char smem[131072];
  const int t = threadIdx.x, wid = t >> 6, lane = t & 63;
  const int waveM = wid >> 2, waveN = wid & 3;
  const int lr0 = lane & 15, lk0 = (lane >> 4) * 8;
  const int m0 = blockIdx.y * 256, n0 = blockIdx.x * 256;
  const unsigned short* A = Abase + (size_t)blockIdx.z * Astr;
  const unsigned short* B = Bbase + (size_t)blockIdx.z * Bstr;
  float* out = outF + (size_t)blockIdx.z * Ostr;

  const int rgA0 = (wid & 3) + ((wid >> 2) << 3);   // {0-3,8-11}
  const int rgA1 = rgA0 + 4;                        // {4-7,12-15}
  const int cgB0 = (wid & 1) + ((wid >> 1) << 2);   // {0,1,4,5,8,9,12,13}
  const int cgB1 = cgB0 + 2;                        // {2,3,6,7,10,11,14,15}
  const unsigned short* ssrc[4];
  int sdst[4];
  ssrc[0] = A + (size_t)(m0 + rgA0 * 16 + lr0) * lda + lk0;
  ssrc[1] = A + (size_t)(m0 + rgA1 * 16 + lr0) * lda + lk0;
  ssrc[2] = B + (size_t)(n0 + cgB0 * 16 + lr0) * ldb + lk0;
  ssrc[3] = B + (size_t)(n0 + cgB1 * 16 + lr0) * ldb + lk0;
  sdst[0] = (rgA0 * 2) * 1024;
  sdst[1] = (rgA1 * 2) * 1024;
  sdst[2] = 32768 + (cgB0 * 2) * 1024;
  sdst[3] = 32768 + (cgB1 * 2) * 1024;

  const int NT = K >> 6, NT2 = NT >> 1;
  f32x4 acc[8][4] = {};
  half8 areg[4][2], breg[2][2];

  ST8(0, 0, 0); ST8(2, 0, 0); ST8(1, 0, 0); ST8(3, 0, 0);
  ST8(2, 1, 1); ST8(1, 1, 1); ST8(3, 1, 1);
  VM(6);
  BARSYNC;
  __builtin_amdgcn_sched_barrier(0);

#pragma unroll 1
  for (int it = 0; it < NT2; ++it) {
    const int tt = 2 * it;
    const bool s2 = (tt + 2) < NT;
    const bool s3 = (tt + 3) < NT;
    RDA(0, 0) RDB(0, 0)
    ST8(0, tt + 1, 1);
    BARSYNC; LGKM0; MM16(0, 0) BARSYNC;
    RDA(0, 1)
    if (s2) ST8(2, tt + 2, 0);
    BARSYNC; LGKM0; MM16(1, 0) BARSYNC;
    RDB(0, 1)
    if (s2) ST8(1, tt + 2, 0);
    BARSYNC; LGKM0; MM16(1, 1) BARSYNC;
    RDA(0, 0)
    if (s2) ST8(3, tt + 2, 0);
    BARSYNC; LGKM0; MM16(0, 1)
    if (s2) { VM(6); } else { VM(0); }
    BARSYNC;
    RDA(1, 0) RDB(1, 0)
    if (s2) ST8(0, tt + 2, 0);
    BARSYNC; LGKM0; MM16(0, 0) BARSYNC;
    RDA(1, 1)
    if (s3) ST8(2, tt + 3, 1);
    BARSYNC; LGKM0; MM16(1, 0) BARSYNC;
    RDB(1, 1)
    if (s3) ST8(1, tt + 3, 1);
    BARSYNC; LGKM0; MM16(1, 1) BARSYNC;
    RDA(1, 0)
    if (s3) ST8(3, tt + 3, 1);
    BARSYNC; LGKM0; MM16(0, 1)
    if (s3) { VM(6); }
    BARSYNC;
  }

  const int or0 = (lane >> 4) * 4;
#pragma unroll
  for (int mm = 0; mm < 8; ++mm)
#pragma unroll
    for (int cg = 0; cg < 4; ++cg)
#pragma unroll
      for (int r = 0; r < 4; ++r)
        out[(size_t)(m0 + waveM * 128 + mm * 16 + or0 + r) * ldo +
            (n0 + waveN * 64 + cg * 16 + lr0)] = acc[mm][cg][r];
}

// =====================================================================
// g1: 1-term f16 NT GEMM (PV), 256x128, BK=64, tri-144KB, 6 slots/wave,
// VM(6). fp32 out. (R6/R10-proven, unchanged.)
// =====================================================================
__global__ __launch_bounds__(512, 2) void g1_kernel(
    const unsigned short* __restrict__ Abase, size_t Astr, int lda,
    const unsigned short* __restrict__ Bbase, size_t Bstr, int ldb,
    float* __restrict__ outF, size_t Ostr, int ldo, int K) {
  __shared__ __align__(16) char smem[3 * 48 * 1024];
  const int t = threadIdx.x, wid = t >> 6, lane = t & 63;
  const int waveM = wid >> 2, waveN = wid & 3;
  const int lr0 = lane & 15, lk0 = (lane >> 4) * 8;
  const int m0 = blockIdx.y * 256, n0 = blockIdx.x * 128;
  const unsigned short* A = Abase + (size_t)blockIdx.z * Astr;
  const unsigned short* B = Bbase + (size_t)blockIdx.z * Bstr;
  float* out = outF + (size_t)blockIdx.z * Ostr;

  const unsigned short* slot_src[6];
#pragma unroll
  for (int s = 0; s < 6; ++s) {
    int si = 6 * wid + s;
    const unsigned short* p;
    if (si < 16)      p = A + (size_t)(m0 + si * 16 + lr0) * lda + lk0;
    else if (si < 32) p = A + (size_t)(m0 + (si - 16) * 16 + lr0) * lda + 32 + lk0;
    else if (si < 40) p = B + (size_t)(n0 + (si - 32) * 16 + lr0) * ldb + lk0;
    else              p = B + (size_t)(n0 + (si - 40) * 16 + lr0) * ldb + 32 + lk0;
    slot_src[s] = p;
  }

  const int NTILES = K >> 6;
  f32x4 acc[8][2] = {};

#pragma unroll
  for (int tt = 0; tt < 2; ++tt)
#pragma unroll
    for (int s = 0; s < 6; ++s)
      GLOAD16(slot_src[s] + (size_t)tt * 64,
              smem + tt * 49152 + (6 * wid + s) * 1024);
  VM(6);
  BARSYNC;
  __builtin_amdgcn_sched_barrier(0);

  for (int tile = 0; tile < NTILES; ++tile) {
    const int cur = tile % 3, nxt = (tile + 2) % 3;
    const bool do_stage = (tile + 2) < NTILES;
    const char* cb = smem + cur * 49152;
    char* nb = smem + nxt * 49152;
    half8 blo[2], bhi[2];
#pragma unroll
    for (int p = 0; p < 4; ++p) {
      half8 alo[2], ahi[2];
#pragma unroll
      for (int i = 0; i < 2; ++i) {
        int mg = waveM * 8 + 2 * p + i;
        alo[i] = *(const half8*)(cb + mg * 1024 + lane * 16);
        ahi[i] = *(const half8*)(cb + (16 + mg) * 1024 + lane * 16);
      }
      if (p == 0) {
#pragma unroll
        for (int j = 0; j < 2; ++j) {
          int ng = waveN * 2 + j;
          blo[j] = *(const half8*)(cb + (32 + ng) * 1024 + lane * 16);
          bhi[j] = *(const half8*)(cb + (40 + ng) * 1024 + lane * 16);
        }
      }
      if (do_stage && p < 3) {
#pragma unroll
        for (int s = 0; s < 2; ++s) {
          int slot = 2 * p + s;
          GLOAD16(slot_src[slot] + (size_t)(tile + 2) * 64,
                  nb + (6 * wid + slot) * 1024);
        }
      }
      __builtin_amdgcn_s_setprio(1);
#pragma unroll
      for (int i = 0; i < 2; ++i)
#pragma unroll
        for (int j = 0; j < 2; ++j) {
          f32x4 c = acc[2 * p + i][j];
          c = __builtin_amdgcn_mfma_f32_16x16x32_f16(alo[i], blo[j], c, 0, 0, 0);
          c = __builtin_amdgcn_mfma_f32_16x16x32_f16(ahi[i], bhi[j], c, 0, 0, 0);
          acc[2 * p + i][j] = c;
        }
      __builtin_amdgcn_s_setprio(0);
    }
    if (tile + 1 < NTILES) {
      LGKM0;
      if (do_stage) VM(6); else VM(0);
      BARSYNC;
      __builtin_amdgcn_sched_barrier(0);
    }
  }

  const int or0 = (lane >> 4) * 4;
#pragma unroll
  for (int mm = 0; mm < 8; ++mm)
#pragma unroll
    for (int j = 0; j < 2; ++j)
#pragma unroll
      for (int r = 0; r < 4; ++r)
        out[(size_t)(m0 + waveM * 128 + mm * 16 + or0 + r) * ldo +
            (n0 + waveN * 32 + j * 16 + lr0)] = acc[mm][j][r];
}

// ---------- row softmax: fp32 [4096] -> f16 probs (in-place, pld stride) ----
__global__ __launch_bounds__(256) void softmax_rows_kernel(
    const float* Sm, unsigned short* P, int ncol, int pld) {
  const int t = threadIdx.x;
  const float* srow = Sm + (size_t)blockIdx.x * ncol;
  float4 v[4];
  float m = -3.4e38f;
#pragma unroll
  for (int i = 0; i < 4; ++i) {
    v[i] = ((const float4*)srow)[t + 256 * i];
    m = fmaxf(m, fmaxf(fmaxf(v[i].x, v[i].y), fmaxf(v[i].z, v[i].w)));
  }
#pragma unroll
  for (int off = 32; off >= 1; off >>= 1) m = fmaxf(m, __shfl_down(m, off));
  __shared__ float redm[4];
  if ((t & 63) == 0) redm[t >> 6] = m;
  __syncthreads();
  m = fmaxf(fmaxf(redm[0], redm[1]), fmaxf(redm[2], redm[3]));
  float s = 0.f;
#pragma unroll
  for (int i = 0; i < 4; ++i) {
    v[i].x = __expf(v[i].x - m);
    v[i].y = __expf(v[i].y - m);
    v[i].z = __expf(v[i].z - m);
    v[i].w = __expf(v[i].w - m);
    s += v[i].x + v[i].y + v[i].z + v[i].w;
  }
#pragma unroll
  for (int off = 32; off >= 1; off >>= 1) s += __shfl_down(s, off);
  __shared__ float reds[4];
  if ((t & 63) == 0) reds[t >> 6] = s;
  __syncthreads();
  s = reds[0] + reds[1] + reds[2] + reds[3];
  float inv = 1.f / s;
  unsigned short* prow = P + (size_t)blockIdx.x * pld;
#pragma unroll
  for (int i = 0; i < 4; ++i) {
    ushort4 o = make_ushort4(f2h(v[i].x * inv), f2h(v[i].y * inv),
                             f2h(v[i].z * inv), f2h(v[i].w * inv));
    ((ushort4*)prow)[t + 256 * i] = o;
  }
}

extern "C" void kernel_launch(void* const* d_in, const int* in_sizes, int n_in,
                              void* d_out, int out_size, void* d_ws, size_t ws_size,
                              hipStream_t stream) {
  const float* hs = (const float*)d_in[0];
  const float* Wq = (const float*)d_in[1];
  const float* bq = (const float*)d_in[2];
  const float* Wk = (const float*)d_in[3];
  const float* bk = (const float*)d_in[4];
  const float* Wv = (const float*)d_in[5];
  const float* bv = (const float*)d_in[6];
  float* out = (float*)d_out;

  constexpr int Ss = 4096, Hh = 1024;
  constexpr int Mm = 8192;
  constexpr size_t TOK = (size_t)Ss * Hh;
  char* ws = (char*)d_ws;
  const size_t MB = 1024 * 1024;

  unsigned short* qh = (unsigned short*)(ws + 0 * MB);
  unsigned short* kh = (unsigned short*)(ws + 16 * MB);
  unsigned short* vT = (unsigned short*)(ws + 32 * MB);  // [1024][8192]
  char* rb = ws + 48 * MB;
  unsigned short* hs_h = (unsigned short*)(rb + 0 * MB);
  unsigned short* hs_l = (unsigned short*)(rb + 16 * MB);
  unsigned short* WT = (unsigned short*)(rb + 32 * MB);   // [3072][1024]
  unsigned short* vS = (unsigned short*)(rb + 38 * MB);   // [8192][1024] staging
  float* Sf = (float*)rb;

  const bool big = ws_size >= (size_t)176 * MB;

  // 1) splits; W -> [3072][1024] f16 (q | k | v)
  split_pair_f16_kernel<<<dim3(Mm * Hh / 2048), 256, 0, stream>>>(hs, hs_h, hs_l);
  transpose_f16_kernel<<<dim3(32, 32), 256, 0, stream>>>(Wq, WT, Hh, Hh);
  transpose_f16_kernel<<<dim3(32, 32), 256, 0, stream>>>(
      Wk, WT + (size_t)1024 * 1024, Hh, Hh);
  transpose_f16_kernel<<<dim3(32, 32), 256, 0, stream>>>(
      Wv, WT + (size_t)2048 * 1024, Hh, Hh);

  // 2) fused QKV projection (128x384 2-term, quad-buffer VM(10))
  qkv_kernel<<<dim3(8, 64), 512, 0, stream>>>(
      hs_h, hs_l, WT, bq, bk, bv, qh, kh, vS);

  // 2b) transpose V staging [8192][1024] -> vT [1024][8192]
  transpose_v_kernel<<<dim3(32, 256), 256, 0, stream>>>(vS, vT);

  if (big) {
    // 3) QK^T both batches (8-phase 256x256 BK=64) -> S fp32 slabs
    g8q_kernel<<<dim3(16, 16, 2), 512, 0, stream>>>(
        qh, TOK, Hh, kh, TOK, Hh, Sf, (size_t)Ss * Ss, Ss, Hh);
    // 4) softmax 8192 rows, fp32 -> f16 in-place strided (pld 8192)
    softmax_rows_kernel<<<dim3(2 * Ss), 256, 0, stream>>>(
        Sf, (unsigned short*)Sf, Ss, 2 * Ss);
    // 5) PV both batches (256x128 1-term, grid 256)
    g1_kernel<<<dim3(8, 16, 2), 512, 0, stream>>>(
        (const unsigned short*)Sf, (size_t)Ss * 2 * Ss, 2 * Ss,
        vT, (size_t)Ss, Mm, out, TOK, Hh, Ss);
  } else {
    float* Sb = (float*)rb;
    unsigned short* Pb = (unsigned short*)(rb + 64 * MB);
    for (int b = 0; b < 2; ++b) {
      g8q_kernel<<<dim3(16, 16, 1), 512, 0, stream>>>(
          qh + b * TOK, 0, Hh, kh + b * TOK, 0, Hh, Sb, 0, Ss, Hh);
      softmax_rows_kernel<<<dim3(Ss), 256, 0, stream>>>(Sb, Pb, Ss, Ss);
      g1_kernel<<<dim3(8, 16, 1), 512, 0, stream>>>(
          Pb, 0, Ss, vT + (size_t)b * Ss, 0, Mm, out + b * TOK, 0, Hh, Ss);
    }
  }
}

// Round 19
// 359.850 us; speedup vs baseline: 1.2049x; 1.0072x over previous
//
#include <hip/hip_runtime.h>
#include <stdint.h>

typedef __attribute__((ext_vector_type(8))) short short8;
typedef __attribute__((ext_vector_type(8))) _Float16 half8;
typedef __attribute__((ext_vector_type(4))) float f32x4;

__device__ __forceinline__ unsigned short f2h(float x) {
  _Float16 h = (_Float16)x;
  return __builtin_bit_cast(unsigned short, h);
}
__device__ __forceinline__ float h2f(unsigned short u) {
  return (float)__builtin_bit_cast(_Float16, u);
}

#define GLOAD16(gsrc, ldst)                                              \
  __builtin_amdgcn_global_load_lds(                                      \
      (const __attribute__((address_space(1))) void*)(gsrc),             \
      (__attribute__((address_space(3))) void*)(ldst), 16, 0, 0)

#define VM(N) asm volatile("s_waitcnt vmcnt(" #N ")" ::: "memory")
#define BARSYNC __builtin_amdgcn_s_barrier()
#define LGKM0                                                \
  do {                                                       \
    asm volatile("s_waitcnt lgkmcnt(0)" ::: "memory");       \
    __builtin_amdgcn_sched_barrier(0);                       \
  } while (0)

// ---------- split fp32 -> (hi, lo) f16, 8 elems/thread ----------
__global__ __launch_bounds__(256) void split_pair_f16_kernel(
    const float* __restrict__ in, unsigned short* __restrict__ h,
    unsigned short* __restrict__ l) {
  size_t i = (size_t)blockIdx.x * 256 + threadIdx.x;
  float4 a = ((const float4*)in)[2 * i];
  float4 b = ((const float4*)in)[2 * i + 1];
  ushort4 h0 = make_ushort4(f2h(a.x), f2h(a.y), f2h(a.z), f2h(a.w));
  ushort4 h1 = make_ushort4(f2h(b.x), f2h(b.y), f2h(b.z), f2h(b.w));
  ((ushort4*)h)[2 * i] = h0;
  ((ushort4*)h)[2 * i + 1] = h1;
  ((ushort4*)l)[2 * i] = make_ushort4(
      f2h(a.x - h2f(h0.x)), f2h(a.y - h2f(h0.y)),
      f2h(a.z - h2f(h0.z)), f2h(a.w - h2f(h0.w)));
  ((ushort4*)l)[2 * i + 1] = make_ushort4(
      f2h(b.x - h2f(h1.x)), f2h(b.y - h2f(h1.y)),
      f2h(b.z - h2f(h1.z)), f2h(b.w - h2f(h1.w)));
}

// ---------- transpose Wq/Wk/Wv [K][N] fp32 -> f16 [N][K], z selects ----
__global__ __launch_bounds__(256) void transpose_f16x3_kernel(
    const float* __restrict__ Wq, const float* __restrict__ Wk,
    const float* __restrict__ Wv, unsigned short* __restrict__ hT) {
  __shared__ float tile[32][33];
  const float* W = blockIdx.z == 0 ? Wq : blockIdx.z == 1 ? Wk : Wv;
  unsigned short* dst = hT + (size_t)blockIdx.z * 1024 * 1024;
  int r = threadIdx.x >> 3;
  int c = (threadIdx.x & 7) * 4;
  int k0 = blockIdx.y * 32, n0 = blockIdx.x * 32;
  float4 v = *(const float4*)&W[(size_t)(k0 + r) * 1024 + n0 + c];
  tile[r][c] = v.x; tile[r][c + 1] = v.y; tile[r][c + 2] = v.z; tile[r][c + 3] = v.w;
  __syncthreads();
  size_t o = (size_t)(n0 + r) * 1024 + k0 + c;
  *(ushort4*)&dst[o] = make_ushort4(f2h(tile[c + 0][r]), f2h(tile[c + 1][r]),
                                    f2h(tile[c + 2][r]), f2h(tile[c + 3][r]));
}

// ---------- transpose V [8192][1024] f16 -> vT [1024][8192] f16 ----------
__global__ __launch_bounds__(256) void transpose_v_kernel(
    const unsigned short* __restrict__ Vs, unsigned short* __restrict__ vT) {
  __shared__ unsigned short tile[32][36];
  int r = threadIdx.x >> 3;
  int c = (threadIdx.x & 7) * 4;
  int col0 = blockIdx.x * 32;
  int row0 = blockIdx.y * 32;
  ushort4 v = *(const ushort4*)&Vs[(size_t)(row0 + r) * 1024 + col0 + c];
  tile[r][c] = v.x; tile[r][c + 1] = v.y; tile[r][c + 2] = v.z; tile[r][c + 3] = v.w;
  __syncthreads();
  ushort4 o = make_ushort4(tile[c + 0][r], tile[c + 1][r],
                           tile[c + 2][r], tile[c + 3][r]);
  *(ushort4*)&vT[(size_t)(col0 + r) * 8192 + row0 + c] = o;
}

// =====================================================================
// qkv_kernel: fused QKV projection, 2-term f16 NT GEMM, 128x384 tile,
// BK=32, quad-buffer 160KB, 3-ahead FIFO, counted VM(10). (R17, frozen.)
// =====================================================================
__global__ __launch_bounds__(512, 2) void qkv_kernel(
    const unsigned short* __restrict__ Ah, const unsigned short* __restrict__ Al,
    const unsigned short* __restrict__ WT, const float* __restrict__ bq,
    const float* __restrict__ bk, const float* __restrict__ bv,
    unsigned short* __restrict__ qh, unsigned short* __restrict__ kh,
    unsigned short* __restrict__ vS) {
  __shared__ __align__(16) char smem[4 * 40 * 1024];
  constexpr int lda = 1024, ldb = 1024, K = 1024;
  const int t = threadIdx.x, wid = t >> 6, lane = t & 63;
  const int waveM = wid >> 2, waveN = wid & 3;
  const int lr0 = lane & 15, lk0 = (lane >> 4) * 8;
  const int m0 = blockIdx.y * 128, n0 = blockIdx.x * 384;

  const unsigned short* slot_src[5];
#pragma unroll
  for (int s = 0; s < 5; ++s) {
    int si = 5 * wid + s;
    const unsigned short* p;
    if (si < 8)       p = Ah + (size_t)(m0 + si * 16 + lr0) * lda + lk0;
    else if (si < 16) p = Al + (size_t)(m0 + (si - 8) * 16 + lr0) * lda + lk0;
    else              p = WT + (size_t)(n0 + (si - 16) * 16 + lr0) * ldb + lk0;
    slot_src[s] = p;
  }

  const int NTILES = K >> 5;
  f32x4 acc[4][6] = {};

#pragma unroll
  for (int tt = 0; tt < 3; ++tt)
#pragma unroll
    for (int s = 0; s < 5; ++s)
      GLOAD16(slot_src[s] + (size_t)tt * 32,
              smem + tt * 40960 + (5 * wid + s) * 1024);
  VM(10);
  BARSYNC;
  __builtin_amdgcn_sched_barrier(0);

  for (int tile = 0; tile < NTILES; ++tile) {
    const int cur = tile & 3, nxt = (tile + 3) & 3;
    const bool do_stage = (tile + 3) < NTILES;
    const bool t2f = (tile + 2) < NTILES;
    const char* cb = smem + cur * 40960;
    char* nb = smem + nxt * 40960;
    half8 bf[6];
#pragma unroll
    for (int p = 0; p < 4; ++p) {
      const int mg = waveM * 4 + p;
      half8 ahf = *(const half8*)(cb + mg * 1024 + lane * 16);
      half8 alf = *(const half8*)(cb + (8 + mg) * 1024 + lane * 16);
      if (p == 0) {
#pragma unroll
        for (int j = 0; j < 6; ++j) {
          int ng = waveN * 6 + j;
          bf[j] = *(const half8*)(cb + (16 + ng) * 1024 + lane * 16);
        }
      }
      if (do_stage) {
        if (p == 0) {
          GLOAD16(slot_src[0] + (size_t)(tile + 3) * 32, nb + (5 * wid + 0) * 1024);
          GLOAD16(slot_src[1] + (size_t)(tile + 3) * 32, nb + (5 * wid + 1) * 1024);
        } else {
          const int slot = p + 1;
          GLOAD16(slot_src[slot] + (size_t)(tile + 3) * 32,
                  nb + (5 * wid + slot) * 1024);
        }
      }
      __builtin_amdgcn_s_setprio(1);
#pragma unroll
      for (int j = 0; j < 6; ++j) {
        f32x4 c = acc[p][j];
        c = __builtin_amdgcn_mfma_f32_16x16x32_f16(ahf, bf[j], c, 0, 0, 0);
        c = __builtin_amdgcn_mfma_f32_16x16x32_f16(alf, bf[j], c, 0, 0, 0);
        acc[p][j] = c;
      }
      __builtin_amdgcn_s_setprio(0);
      if (p < 3) __builtin_amdgcn_s_barrier();
    }
    if (tile + 1 < NTILES) {
      if (do_stage) VM(10);
      else if (t2f) VM(5);
      else VM(0);
      BARSYNC;
      __builtin_amdgcn_sched_barrier(0);
    }
  }

  const int or0 = (lane >> 4) * 4;
#pragma unroll
  for (int mm = 0; mm < 4; ++mm)
#pragma unroll
    for (int j = 0; j < 6; ++j)
#pragma unroll
      for (int r = 0; r < 4; ++r) {
        int row = m0 + waveM * 64 + mm * 16 + or0 + r;
        int gc = n0 + waveN * 96 + j * 16 + lr0;
        int slab = gc >> 10;
        int col = gc & 1023;
        float x = acc[mm][j][r];
        if (slab == 0) {
          qh[(size_t)row * 1024 + col] = f2h(x + bq[col]);
        } else if (slab == 1) {
          kh[(size_t)row * 1024 + col] = f2h(x + bk[col]);
        } else {
          vS[(size_t)row * 1024 + col] = f2h(x + bv[col]);
        }
      }
}

// =====================================================================
// g8q: 8-phase 256x256 BK=64 1-term f16 NT GEMM (QK^T), m201 ledger.
// (R14-proven, unchanged.)
// =====================================================================
#define ST8(h, T, bufb)                                                   \
  do {                                                                    \
    const unsigned short* _s = ssrc[h] + (size_t)(T) * 64;                \
    char* _d = smem + (bufb) * 65536 + sdst[h];                           \
    GLOAD16(_s, _d);                                                      \
    GLOAD16(_s + 32, _d + 1024);                                          \
  } while (0)

#define RDA(bufb, qr)                                                     \
  _Pragma("unroll") for (int _i = 0; _i < 4; ++_i)                        \
  _Pragma("unroll") for (int _kk = 0; _kk < 2; ++_kk)                     \
      areg[_i][_kk] = *(const half8*)(smem + (bufb) * 65536 +             \
          ((waveM * 8 + (qr) * 4 + _i) * 2 + _kk) * 1024 + lane * 16);

#define RDB(bufb, qc)                                                     \
  _Pragma("unroll") for (int _j = 0; _j < 2; ++_j)                        \
  _Pragma("unroll") for (int _kk = 0; _kk < 2; ++_kk)                     \
      breg[_j][_kk] = *(const half8*)(smem + (bufb) * 65536 + 32768 +     \
          ((waveN * 4 + (qc) * 2 + _j) * 2 + _kk) * 1024 + lane * 16);

#define MM16(qr, qc)                                                      \
  __builtin_amdgcn_s_setprio(1);                                          \
  _Pragma("unroll") for (int _i = 0; _i < 4; ++_i)                        \
  _Pragma("unroll") for (int _j = 0; _j < 2; ++_j)                        \
  _Pragma("unroll") for (int _kk = 0; _kk < 2; ++_kk)                     \
      acc[(qr) * 4 + _i][(qc) * 2 + _j] =                                 \
          __builtin_amdgcn_mfma_f32_16x16x32_f16(                         \
              areg[_i][_kk], breg[_j][_kk],                               \
              acc[(qr) * 4 + _i][(qc) * 2 + _j], 0, 0, 0);                \
  __builtin_amdgcn_s_setprio(0);

__global__ __launch_bounds__(512, 2) void g8q_kernel(
    const unsigned short* __restrict__ Abase, size_t Astr, int lda,
    const unsigned short* __restrict__ Bbase, size_t Bstr, int ldb,
    float* __restrict__ outF, size_t Ostr, int ldo, int K) {
  __shared__ __align__(16) char smem[131072];
  const int t = threadIdx.x, wid = t >> 6, lane = t & 63;
  const int waveM = wid >> 2, waveN = wid & 3;
  const int lr0 = lane & 15, lk0 = (lane >> 4) * 8;
  const int m0 = blockIdx.y * 256, n0 = blockIdx.x * 256;
  const unsigned short* A = Abase + (size_t)blockIdx.z * Astr;
  const unsigned short* B = Bbase + (size_t)blockIdx.z * Bstr;
  float* out = outF + (size_t)blockIdx.z * Ostr;

  const int rgA0 = (wid & 3) + ((wid >> 2) << 3);
  const int rgA1 = rgA0 + 4;
  const int cgB0 = (wid & 1) + ((wid >> 1) << 2);
  const int cgB1 = cgB0 + 2;
  const unsigned short* ssrc[4];
  int sdst[4];
  ssrc[0] = A + (size_t)(m0 + rgA0 * 16 + lr0) * lda + lk0;
  ssrc[1] = A + (size_t)(m0 + rgA1 * 16 + lr0) * lda + lk0;
  ssrc[2] = B + (size_t)(n0 + cgB0 * 16 + lr0) * ldb + lk0;
  ssrc[3] = B + (size_t)(n0 + cgB1 * 16 + lr0) * ldb + lk0;
  sdst[0] = (rgA0 * 2) * 1024;
  sdst[1] = (rgA1 * 2) * 1024;
  sdst[2] = 32768 + (cgB0 * 2) * 1024;
  sdst[3] = 32768 + (cgB1 * 2) * 1024;

  const int NT = K >> 6, NT2 = NT >> 1;
  f32x4 acc[8][4] = {};
  half8 areg[4][2], breg[2][2];

  ST8(0, 0, 0); ST8(2, 0, 0); ST8(1, 0, 0); ST8(3, 0, 0);
  ST8(2, 1, 1); ST8(1, 1, 1); ST8(3, 1, 1);
  VM(6);
  BARSYNC;
  __builtin_amdgcn_sched_barrier(0);

#pragma unroll 1
  for (int it = 0; it < NT2; ++it) {
    const int tt = 2 * it;
    const bool s2 = (tt + 2) < NT;
    const bool s3 = (tt + 3) < NT;
    RDA(0, 0) RDB(0, 0)
    ST8(0, tt + 1, 1);
    BARSYNC; LGKM0; MM16(0, 0) BARSYNC;
    RDA(0, 1)
    if (s2) ST8(2, tt + 2, 0);
    BARSYNC; LGKM0; MM16(1, 0) BARSYNC;
    RDB(0, 1)
    if (s2) ST8(1, tt + 2, 0);
    BARSYNC; LGKM0; MM16(1, 1) BARSYNC;
    RDA(0, 0)
    if (s2) ST8(3, tt + 2, 0);
    BARSYNC; LGKM0; MM16(0, 1)
    if (s2) { VM(6); } else { VM(0); }
    BARSYNC;
    RDA(1, 0) RDB(1, 0)
    if (s2) ST8(0, tt + 2, 0);
    BARSYNC; LGKM0; MM16(0, 0) BARSYNC;
    RDA(1, 1)
    if (s3) ST8(2, tt + 3, 1);
    BARSYNC; LGKM0; MM16(1, 0) BARSYNC;
    RDB(1, 1)
    if (s3) ST8(1, tt + 3, 1);
    BARSYNC; LGKM0; MM16(1, 1) BARSYNC;
    RDA(1, 0)
    if (s3) ST8(3, tt + 3, 1);
    BARSYNC; LGKM0; MM16(0, 1)
    if (s3) { VM(6); }
    BARSYNC;
  }

  const int or0 = (lane >> 4) * 4;
#pragma unroll
  for (int mm = 0; mm < 8; ++mm)
#pragma unroll
    for (int cg = 0; cg < 4; ++cg)
#pragma unroll
      for (int r = 0; r < 4; ++r)
        out[(size_t)(m0 + waveM * 128 + mm * 16 + or0 + r) * ldo +
            (n0 + waveN * 64 + cg * 16 + lr0)] = acc[mm][cg][r];
}

// =====================================================================
// g1t: 1-term f16 NT GEMM (PV), 128x256 tile, BK=64, tri-144KB,
// 6 slots/wave, VM(6) -- g1's proven ledger with swapped geometry to
// minimize staged bytes (A=P 8 rowgroups, B=vT 16 rowgroups).
// Slot-linear LDS: A k-lo rg at rg*1KB, A k-hi at (8+rg)*1KB,
// B k-lo ng at (16+ng)*1KB, B k-hi at (32+ng)*1KB. acc[4][4],
// 8 MFMA/phase (mg = waveM*4+p), B frags (8 regs) loaded at p==0.
// Grid (4, 32, 2) = 256 blocks; staged 384MB (vs 544 at 256x128).
// K-accumulation order per output unchanged -> bit-identical results.
// =====================================================================
__global__ __launch_bounds__(512, 2) void g1t_kernel(
    const unsigned short* __restrict__ Abase, size_t Astr, int lda,
    const unsigned short* __restrict__ Bbase, size_t Bstr, int ldb,
    float* __restrict__ outF, size_t Ostr, int ldo, int K) {
  __shared__ __align__(16) char smem[3 * 48 * 1024];
  const int t = threadIdx.x, wid = t >> 6, lane = t & 63;
  const int waveM = wid >> 2, waveN = wid & 3;
  const int lr0 = lane & 15, lk0 = (lane >> 4) * 8;
  const int m0 = blockIdx.y * 128, n0 = blockIdx.x * 256;
  const unsigned short* A = Abase + (size_t)blockIdx.z * Astr;
  const unsigned short* B = Bbase + (size_t)blockIdx.z * Bstr;
  float* out = outF + (size_t)blockIdx.z * Ostr;

  const unsigned short* slot_src[6];
#pragma unroll
  for (int s = 0; s < 6; ++s) {
    int si = 6 * wid + s;
    const unsigned short* p;
    if (si < 8)       p = A + (size_t)(m0 + si * 16 + lr0) * lda + lk0;
    else if (si < 16) p = A + (size_t)(m0 + (si - 8) * 16 + lr0) * lda + 32 + lk0;
    else if (si < 32) p = B + (size_t)(n0 + (si - 16) * 16 + lr0) * ldb + lk0;
    else              p = B + (size_t)(n0 + (si - 32) * 16 + lr0) * ldb + 32 + lk0;
    slot_src[s] = p;
  }

  const int NTILES = K >> 6;
  f32x4 acc[4][4] = {};

#pragma unroll
  for (int tt = 0; tt < 2; ++tt)
#pragma unroll
    for (int s = 0; s < 6; ++s)
      GLOAD16(slot_src[s] + (size_t)tt * 64,
              smem + tt * 49152 + (6 * wid + s) * 1024);
  VM(6);
  BARSYNC;
  __builtin_amdgcn_sched_barrier(0);

  for (int tile = 0; tile < NTILES; ++tile) {
    const int cur = tile % 3, nxt = (tile + 2) % 3;
    const bool do_stage = (tile + 2) < NTILES;
    const char* cb = smem + cur * 49152;
    char* nb = smem + nxt * 49152;
    half8 blo[4], bhi[4];
#pragma unroll
    for (int p = 0; p < 4; ++p) {
      const int mg = waveM * 4 + p;
      half8 alo = *(const half8*)(cb + mg * 1024 + lane * 16);
      half8 ahi = *(const half8*)(cb + (8 + mg) * 1024 + lane * 16);
      if (p == 0) {
#pragma unroll
        for (int j = 0; j < 4; ++j) {
          int ng = waveN * 4 + j;
          blo[j] = *(const half8*)(cb + (16 + ng) * 1024 + lane * 16);
          bhi[j] = *(const half8*)(cb + (32 + ng) * 1024 + lane * 16);
        }
      }
      if (do_stage && p < 3) {
#pragma unroll
        for (int s = 0; s < 2; ++s) {
          int slot = 2 * p + s;
          GLOAD16(slot_src[slot] + (size_t)(tile + 2) * 64,
                  nb + (6 * wid + slot) * 1024);
        }
      }
      __builtin_amdgcn_s_setprio(1);
#pragma unroll
      for (int j = 0; j < 4; ++j) {
        f32x4 c = acc[p][j];
        c = __builtin_amdgcn_mfma_f32_16x16x32_f16(alo, blo[j], c, 0, 0, 0);
        c = __builtin_amdgcn_mfma_f32_16x16x32_f16(ahi, bhi[j], c, 0, 0, 0);
        acc[p][j] = c;
      }
      __builtin_amdgcn_s_setprio(0);
    }
    if (tile + 1 < NTILES) {
      LGKM0;
      if (do_stage) VM(6); else VM(0);
      BARSYNC;
      __builtin_amdgcn_sched_barrier(0);
    }
  }

  const int or0 = (lane >> 4) * 4;
#pragma unroll
  for (int mm = 0; mm < 4; ++mm)
#pragma unroll
    for (int j = 0; j < 4; ++j)
#pragma unroll
      for (int r = 0; r < 4; ++r)
        out[(size_t)(m0 + waveM * 64 + mm * 16 + or0 + r) * ldo +
            (n0 + waveN * 64 + j * 16 + lr0)] = acc[mm][j][r];
}

// ---------- row softmax: fp32 [4096] -> f16 probs (in-place, pld stride) ----
__global__ __launch_bounds__(256) void softmax_rows_kernel(
    const float* Sm, unsigned short* P, int ncol, int pld) {
  const int t = threadIdx.x;
  const float* srow = Sm + (size_t)blockIdx.x * ncol;
  float4 v[4];
  float m = -3.4e38f;
#pragma unroll
  for (int i = 0; i < 4; ++i) {
    v[i] = ((const float4*)srow)[t + 256 * i];
    m = fmaxf(m, fmaxf(fmaxf(v[i].x, v[i].y), fmaxf(v[i].z, v[i].w)));
  }
#pragma unroll
  for (int off = 32; off >= 1; off >>= 1) m = fmaxf(m, __shfl_down(m, off));
  __shared__ float redm[4];
  if ((t & 63) == 0) redm[t >> 6] = m;
  __syncthreads();
  m = fmaxf(fmaxf(redm[0], redm[1]), fmaxf(redm[2], redm[3]));
  float s = 0.f;
#pragma unroll
  for (int i = 0; i < 4; ++i) {
    v[i].x = __expf(v[i].x - m);
    v[i].y = __expf(v[i].y - m);
    v[i].z = __expf(v[i].z - m);
    v[i].w = __expf(v[i].w - m);
    s += v[i].x + v[i].y + v[i].z + v[i].w;
  }
#pragma unroll
  for (int off = 32; off >= 1; off >>= 1) s += __shfl_down(s, off);
  __shared__ float reds[4];
  if ((t & 63) == 0) reds[t >> 6] = s;
  __syncthreads();
  s = reds[0] + reds[1] + reds[2] + reds[3];
  float inv = 1.f / s;
  unsigned short* prow = P + (size_t)blockIdx.x * pld;
#pragma unroll
  for (int i = 0; i < 4; ++i) {
    ushort4 o = make_ushort4(f2h(v[i].x * inv), f2h(v[i].y * inv),
                             f2h(v[i].z * inv), f2h(v[i].w * inv));
    ((ushort4*)prow)[t + 256 * i] = o;
  }
}

extern "C" void kernel_launch(void* const* d_in, const int* in_sizes, int n_in,
                              void* d_out, int out_size, void* d_ws, size_t ws_size,
                              hipStream_t stream) {
  const float* hs = (const float*)d_in[0];
  const float* Wq = (const float*)d_in[1];
  const float* bq = (const float*)d_in[2];
  const float* Wk = (const float*)d_in[3];
  const float* bk = (const float*)d_in[4];
  const float* Wv = (const float*)d_in[5];
  const float* bv = (const float*)d_in[6];
  float* out = (float*)d_out;

  constexpr int Ss = 4096, Hh = 1024;
  constexpr int Mm = 8192;
  constexpr size_t TOK = (size_t)Ss * Hh;
  char* ws = (char*)d_ws;
  const size_t MB = 1024 * 1024;

  unsigned short* qh = (unsigned short*)(ws + 0 * MB);
  unsigned short* kh = (unsigned short*)(ws + 16 * MB);
  unsigned short* vT = (unsigned short*)(ws + 32 * MB);  // [1024][8192]
  char* rb = ws + 48 * MB;
  unsigned short* hs_h = (unsigned short*)(rb + 0 * MB);
  unsigned short* hs_l = (unsigned short*)(rb + 16 * MB);
  unsigned short* WT = (unsigned short*)(rb + 32 * MB);   // [3072][1024]
  unsigned short* vS = (unsigned short*)(rb + 38 * MB);   // [8192][1024] staging
  float* Sf = (float*)rb;

  const bool big = ws_size >= (size_t)176 * MB;

  // 1) splits; W -> [3072][1024] f16 (q | k | v), single z=3 launch
  split_pair_f16_kernel<<<dim3(Mm * Hh / 2048), 256, 0, stream>>>(hs, hs_h, hs_l);
  transpose_f16x3_kernel<<<dim3(32, 32, 3), 256, 0, stream>>>(Wq, Wk, Wv, WT);

  // 2) fused QKV projection (128x384 2-term, quad-buffer VM(10))
  qkv_kernel<<<dim3(8, 64), 512, 0, stream>>>(
      hs_h, hs_l, WT, bq, bk, bv, qh, kh, vS);

  // 2b) transpose V staging [8192][1024] -> vT [1024][8192]
  transpose_v_kernel<<<dim3(32, 256), 256, 0, stream>>>(vS, vT);

  if (big) {
    // 3) QK^T both batches (8-phase 256x256 BK=64) -> S fp32 slabs
    g8q_kernel<<<dim3(16, 16, 2), 512, 0, stream>>>(
        qh, TOK, Hh, kh, TOK, Hh, Sf, (size_t)Ss * Ss, Ss, Hh);
    // 4) softmax 8192 rows, fp32 -> f16 in-place strided (pld 8192)
    softmax_rows_kernel<<<dim3(2 * Ss), 256, 0, stream>>>(
        Sf, (unsigned short*)Sf, Ss, 2 * Ss);
    // 5) PV both batches (128x256 1-term, grid 256, min staged bytes)
    g1t_kernel<<<dim3(4, 32, 2), 512, 0, stream>>>(
        (const unsigned short*)Sf, (size_t)Ss * 2 * Ss, 2 * Ss,
        vT, (size_t)Ss, Mm, out, TOK, Hh, Ss);
  } else {
    float* Sb = (float*)rb;
    unsigned short* Pb = (unsigned short*)(rb + 64 * MB);
    for (int b = 0; b < 2; ++b) {
      g8q_kernel<<<dim3(16, 16, 1), 512, 0, stream>>>(
          qh + b * TOK, 0, Hh, kh + b * TOK, 0, Hh, Sb, 0, Ss, Hh);
      softmax_rows_kernel<<<dim3(Ss), 256, 0, stream>>>(Sb, Pb, Ss, Ss);
      g1t_kernel<<<dim3(4, 32, 1), 512, 0, stream>>>(
          Pb, 0, Ss, vT + (size_t)b * Ss, 0, Mm, out + b * TOK, 0, Hh, Ss);
    }
  }
}